// Round 5
// baseline (300.595 us; speedup 1.0000x reference)
//
#include <hip/hip_runtime.h>
#include <stdint.h>

// PinConv pipeline, round 15:
//  - gather_agg FUSED into gemm2: each gemm2 block gathers its own 64 dst
//    rows (paired-edge, 32-lane halves, bn1 affine in-register) into an LDS
//    tile Ag[2][64*SA] that serves directly as the A-hi (K=128..255) MFMA
//    operand. Deletes the aggb intermediate (12.8MB W + 12.8MB R), one
//    dispatch, and one serialization boundary. Bit-identical math.
//  - 7 dispatches, no device-scope fences (round-12 lesson).
//  - B matrices pre-cast to bf16 once (round-13 win).

#define BN_EPS 1e-5f
#define NSLOT 32

typedef __attribute__((ext_vector_type(8))) short bf16x8;
typedef __attribute__((ext_vector_type(4))) float f32x4;

static __device__ __forceinline__ unsigned short f2bf(float f) {
    uint32_t u = __builtin_bit_cast(uint32_t, f);
    u += 0x7fffu + ((u >> 16) & 1u);          // round-to-nearest-even
    return (unsigned short)(u >> 16);
}
static __device__ __forceinline__ float bf_lo(uint32_t u) {
    return __builtin_bit_cast(float, u << 16);
}
static __device__ __forceinline__ float bf_hi(uint32_t u) {
    return __builtin_bit_cast(float, u & 0xffff0000u);
}

static __device__ __forceinline__ void cast_blk(
    const float* __restrict__ src, unsigned short* __restrict__ dst,
    int n, int blk)
{
    int i = (blk * 256 + threadIdx.x) * 4;
    if (i + 3 < n) {
        float4 v = *(const float4*)(src + i);
        ushort4 o;
        o.x = f2bf(v.x); o.y = f2bf(v.y); o.z = f2bf(v.z); o.w = f2bf(v.w);
        *(ushort4*)(dst + i) = o;
    } else {
        for (int j = i; j < n; ++j) dst[j] = f2bf(src[j]);
    }
}

// ---------------------------------------------------------------------------
// Fused: blocks [0,CB) cast feat; [CB,CB+HB) coarse-histogram dst into
// 512-wide buckets; [CB+HB,..) cast Q_w / W_w to bf16. No fences.
__global__ __launch_bounds__(256) void k_pre(
    const float* __restrict__ feat, unsigned short* __restrict__ featb, int nf,
    const int* __restrict__ dst, int* __restrict__ ccnt, int E, int CB, int HB,
    const float* __restrict__ Qw, unsigned short* __restrict__ Qwb,
    const float* __restrict__ Ww, unsigned short* __restrict__ Wwb)
{
    int b = (int)blockIdx.x;
    if (b < CB) { cast_blk(feat, featb, nf, b); return; }
    b -= CB;
    if (b >= HB) {
        b -= HB;
        if (b < 16) cast_blk(Qw, Qwb, 128 * 128, b);
        else        cast_blk(Ww, Wwb, 128 * 256, b - 16);
        return;
    }
    __shared__ int hcnt[128];
    const int tid = threadIdx.x;
    if (tid < 128) hcnt[tid] = 0;
    __syncthreads();
    const int base_e = b * 2048;
#pragma unroll
    for (int j = 0; j < 8; ++j) {
        int e = base_e + j * 256 + tid;
        if (e < E) atomicAdd(&hcnt[dst[e] >> 9], 1);
    }
    __syncthreads();
    if (tid < 128 && hcnt[tid] > 0) atomicAdd(&ccnt[tid], hcnt[tid]);
}

// ---------------------------------------------------------------------------
// Single block: exclusive scan of 128 bucket counts -> coffs[129], gcur,
// and offs[N] = E.
__global__ __launch_bounds__(128) void k_coffs(
    const int* __restrict__ ccnt, int* __restrict__ coffs,
    int* __restrict__ gcur, int* __restrict__ offs, int N, int E)
{
    __shared__ int w0sum;
    const int t = threadIdx.x;
    const int lane = t & 63, wv = t >> 6;
    int v = ccnt[t];
    int incl = v;
#pragma unroll
    for (int o = 1; o < 64; o <<= 1) {
        int u = __shfl_up(incl, o, 64);
        if (lane >= o) incl += u;
    }
    if (wv == 0 && lane == 63) w0sum = incl;
    __syncthreads();
    int excl = incl - v + (wv ? w0sum : 0);
    coffs[t] = excl;
    gcur[t]  = excl;
    if (t == 127) { coffs[128] = excl + v; offs[N] = E; }
}

// ---------------------------------------------------------------------------
// GEMM1 body (LDS-staged): Y = relu(A @ B^T + bias) -> bf16; K=128.
// B bf16 pre-converted -> staging is pure uint4 copy. Col sum/sumsq ->
// striped fp64 slots.
static __device__ __forceinline__ void gemm1_body(
    int bid,
    const unsigned short* __restrict__ A,
    const unsigned short* __restrict__ Bb,
    const float* __restrict__ bias,
    unsigned short* __restrict__ Y,
    double* __restrict__ sum, double* __restrict__ sumsq, int N)
{
    constexpr int SA = 72;
    __shared__ unsigned short As[64 * SA];
    __shared__ unsigned short Bs[128 * SA];
    __shared__ float bsum_s[128], bsq_s[128];

    const int tid  = threadIdx.x;
    const int lane = tid & 63;
    const int wv   = tid >> 6;
    const int wr   = wv >> 1;
    const int wc   = wv & 1;
    const int m15  = lane & 15;
    const int quad = lane >> 4;
    const int r0   = bid * 64;

    if (tid < 128) { bsum_s[tid] = 0.f; bsq_s[tid] = 0.f; }

    f32x4 acc[2][4];
#pragma unroll
    for (int rt = 0; rt < 2; ++rt)
#pragma unroll
        for (int ct = 0; ct < 4; ++ct)
            acc[rt][ct] = (f32x4){0.f, 0.f, 0.f, 0.f};

    for (int kc = 0; kc < 128; kc += 64) {
#pragma unroll
        for (int i = 0; i < 2; ++i) {
            int idx = i * 256 + tid;
            int row = idx >> 3, seg = idx & 7;
            int gr  = r0 + row; if (gr >= N) gr = N - 1;
            uint4 v = *(const uint4*)(A + (size_t)gr * 128 + kc + seg * 8);
            *(uint4*)(As + row * SA + seg * 8) = v;
        }
#pragma unroll
        for (int i = 0; i < 4; ++i) {
            int idx = i * 256 + tid;
            int row = idx >> 3, seg = idx & 7;
            uint4 v = *(const uint4*)(Bb + (size_t)row * 128 + kc + seg * 8);
            *(uint4*)(Bs + row * SA + seg * 8) = v;
        }
        __syncthreads();

#pragma unroll
        for (int ks = 0; ks < 64; ks += 32) {
            bf16x8 af[2], bfr[4];
#pragma unroll
            for (int rt = 0; rt < 2; ++rt)
                af[rt] = *(const bf16x8*)(As + (wr * 32 + rt * 16 + m15) * SA + ks + quad * 8);
#pragma unroll
            for (int ct = 0; ct < 4; ++ct)
                bfr[ct] = *(const bf16x8*)(Bs + (wc * 64 + ct * 16 + m15) * SA + ks + quad * 8);
#pragma unroll
            for (int rt = 0; rt < 2; ++rt)
#pragma unroll
                for (int ct = 0; ct < 4; ++ct)
                    acc[rt][ct] = __builtin_amdgcn_mfma_f32_16x16x32_bf16(
                        af[rt], bfr[ct], acc[rt][ct], 0, 0, 0);
        }
        __syncthreads();
    }

#pragma unroll
    for (int ct = 0; ct < 4; ++ct) {
        int col = wc * 64 + ct * 16 + m15;
        float bz = bias[col];
        float s = 0.f, q = 0.f;
#pragma unroll
        for (int rt = 0; rt < 2; ++rt) {
#pragma unroll
            for (int reg = 0; reg < 4; ++reg) {
                int row = r0 + wr * 32 + rt * 16 + quad * 4 + reg;
                float vv = fmaxf(acc[rt][ct][reg] + bz, 0.f);
                if (row < N) {
                    Y[(size_t)row * 128 + col] = f2bf(vv);
                } else {
                    vv = 0.f;
                }
                s += vv; q = fmaf(vv, vv, q);
            }
        }
        s += __shfl_xor(s, 16, 64); s += __shfl_xor(s, 32, 64);
        q += __shfl_xor(q, 16, 64); q += __shfl_xor(q, 32, 64);
        if (quad == 0) {
            atomicAdd(&bsum_s[col], s);
            atomicAdd(&bsq_s[col], q);
        }
    }
    __syncthreads();
    if (tid < 128) {
        const int slot = (bid & (NSLOT - 1)) * 128;
        atomicAdd(&sum[slot + tid],   (double)bsum_s[tid]);
        atomicAdd(&sumsq[slot + tid], (double)bsq_s[tid]);
    }
}

// ---------------------------------------------------------------------------
// bn coef body: reduce 32 slots -> bn affine coefs a[128], b[128]. t in [0,128).
static __device__ __forceinline__ void bn_coef_body(
    int t, const double* __restrict__ sum, const double* __restrict__ sumsq,
    const float* __restrict__ gamma, const float* __restrict__ beta,
    float* __restrict__ a, float* __restrict__ b, double invN)
{
    double ms = 0.0, qs = 0.0;
#pragma unroll
    for (int s = 0; s < NSLOT; ++s) {
        ms += sum[s * 128 + t];
        qs += sumsq[s * 128 + t];
    }
    float mean = (float)(ms * invN);
    float var  = (float)(qs * invN) - mean * mean;
    float sc = rsqrtf(var + BN_EPS) * gamma[t];
    a[t] = sc;
    b[t] = fmaf(-mean, sc, beta[t]);
}

__global__ __launch_bounds__(128) void bn_coef(
    const double* __restrict__ sum, const double* __restrict__ sumsq,
    const float* __restrict__ gamma, const float* __restrict__ beta,
    float* __restrict__ a, float* __restrict__ b, double invN)
{
    bn_coef_body(threadIdx.x, sum, sumsq, gamma, beta, a, b, invN);
}

// ---------------------------------------------------------------------------
// bin body: bin edges into coarse buckets of 512 dsts (int4 records).
static __device__ __forceinline__ void bin_body(
    int bid,
    const int* __restrict__ src, const int* __restrict__ dst,
    const float* __restrict__ w, int* __restrict__ gcur,
    int4* __restrict__ tmp, int E)
{
    __shared__ int hcnt[128];
    __shared__ int hbase[128];
    const int tid = threadIdx.x;
    if (tid < 128) hcnt[tid] = 0;
    __syncthreads();

    int d8[8], s8[8], slot8[8];
    float w8[8];
#pragma unroll
    for (int j = 0; j < 8; ++j) {
        int e = bid * 2048 + j * 256 + tid;
        if (e < E) {
            d8[j] = dst[e]; s8[j] = src[e]; w8[j] = w[e];
            slot8[j] = atomicAdd(&hcnt[d8[j] >> 9], 1);
        } else d8[j] = -1;
    }
    __syncthreads();
    if (tid < 128 && hcnt[tid] > 0)
        hbase[tid] = atomicAdd(&gcur[tid], hcnt[tid]);
    __syncthreads();
#pragma unroll
    for (int j = 0; j < 8; ++j) {
        if (d8[j] >= 0) {
            int pos = hbase[d8[j] >> 9] + slot8[j];
            tmp[pos] = make_int4(s8[j], __float_as_int(w8[j]), d8[j], 0);
        }
    }
}

// fatB: blocks [0,HB) bin edges; blocks [HB,HB+GB) run gemm1 -> y1b bf16.
__global__ __launch_bounds__(256) void k_bin_gemm(
    const int* __restrict__ src, const int* __restrict__ dst,
    const float* __restrict__ w, int* __restrict__ gcur,
    int4* __restrict__ tmp, int E, int HB,
    const unsigned short* __restrict__ featb,
    const unsigned short* __restrict__ Qwb, const float* __restrict__ Qb,
    unsigned short* __restrict__ y1b,
    double* __restrict__ sum, double* __restrict__ sumsq, int N)
{
    if ((int)blockIdx.x < HB)
        bin_body(blockIdx.x, src, dst, w, gcur, tmp, E);
    else
        gemm1_body(blockIdx.x - HB, featb, Qwb, Qb, y1b, sum, sumsq, N);
}

// ---------------------------------------------------------------------------
// refine body: per bucket — count per-dst in LDS, scan (+coffs base), write
// offs slice, scatter records to epack in exact dst order.
static __device__ __forceinline__ void refine_body(
    int b,
    const int4* __restrict__ tmp, const int* __restrict__ coffs,
    int* __restrict__ offs, int2* __restrict__ epack, int N)
{
    __shared__ int hist[512];
    __shared__ int wpre[4];
    const int d0   = b << 9;
    const int dlim = min(512, N - d0);
    const int tid  = threadIdx.x;
    const int lane = tid & 63, wv = tid >> 6;
    const int start = coffs[b];
    const int end   = coffs[b + 1];

    hist[tid] = 0; hist[tid + 256] = 0;
    __syncthreads();

    for (int p = start + tid; p < end; p += 256)
        atomicAdd(&hist[tmp[p].z - d0], 1);
    __syncthreads();

    int v0 = hist[2 * tid], v1 = hist[2 * tid + 1];
    int s = v0 + v1;
    int incl = s;
#pragma unroll
    for (int o = 1; o < 64; o <<= 1) {
        int t = __shfl_up(incl, o, 64);
        if (lane >= o) incl += t;
    }
    if (lane == 63) wpre[wv] = incl;
    __syncthreads();
    if (tid == 0) {
        int r = 0;
#pragma unroll
        for (int i = 0; i < 4; ++i) { int t = wpre[i]; wpre[i] = r; r += t; }
    }
    __syncthreads();
    int e0 = start + wpre[wv] + incl - s;
    if (2 * tid < dlim)     offs[d0 + 2 * tid]     = e0;
    if (2 * tid + 1 < dlim) offs[d0 + 2 * tid + 1] = e0 + v0;
    hist[2 * tid]     = e0;
    hist[2 * tid + 1] = e0 + v0;
    __syncthreads();

    for (int p = start + tid; p < end; p += 256) {
        int4 rec = tmp[p];
        int pos = atomicAdd(&hist[rec.z - d0], 1);
        epack[pos] = make_int2(rec.x, rec.y);
    }
}

// fat: block 0 = bn_coef1 reduce; blocks [1,NB] = refine buckets.
__global__ __launch_bounds__(256) void k_bnref(
    const double* __restrict__ sum, const double* __restrict__ sumsq,
    const float* __restrict__ gamma, const float* __restrict__ beta,
    float* __restrict__ a, float* __restrict__ b, double invN,
    const int4* __restrict__ tmp, const int* __restrict__ coffs,
    int* __restrict__ offs, int2* __restrict__ epack, int N)
{
    if (blockIdx.x == 0) {
        if (threadIdx.x < 128)
            bn_coef_body(threadIdx.x, sum, sumsq, gamma, beta, a, b, invN);
        return;
    }
    refine_body((int)blockIdx.x - 1, tmp, coffs, offs, epack, N);
}

// ---------------------------------------------------------------------------
// gemm2 with fused gather: per block, gather agg rows for its 64-row tile
// into LDS (Ag, bn1 affine applied, bf16) then K=256 GEMM with A-lo staged
// from featb and A-hi fragments read from Ag. Output y2 f32 + stats2.
__global__ __launch_bounds__(256) void gemm2_fused(
    const unsigned short* __restrict__ featb,
    const unsigned short* __restrict__ y1b,
    const int* __restrict__ offs, const int2* __restrict__ epack,
    const float* __restrict__ a1, const float* __restrict__ b1,
    const unsigned short* __restrict__ Bb,
    const float* __restrict__ bias,
    float* __restrict__ Y,
    double* __restrict__ sum, double* __restrict__ sumsq, int N)
{
    constexpr int SA = 72;
    __shared__ unsigned short As[64 * SA];
    __shared__ unsigned short Bs[128 * SA];
    __shared__ unsigned short Ag[2][64 * SA];   // A-hi: agg tile, chunked by 64 k
    __shared__ float bsum_s[128], bsq_s[128];

    const int tid  = threadIdx.x;
    const int lane = tid & 63;
    const int wv   = tid >> 6;
    const int wr   = wv >> 1;
    const int wc   = wv & 1;
    const int m15  = lane & 15;
    const int quad = lane >> 4;
    const int r0   = (int)blockIdx.x * 64;

    if (tid < 128) { bsum_s[tid] = 0.f; bsq_s[tid] = 0.f; }

    // ---------------- gather phase: wave wv owns local rows wv+4*i ----------
    const int li = lane & 31;      // owns columns 4*li .. 4*li+3
    const int hf = lane >> 5;      // edge-pair half
    const int c  = 4 * li;
    const float4 av = *(const float4*)(a1 + c);
    const float4 bv = *(const float4*)(b1 + c);
#pragma unroll 1
    for (int i = 0; i < 16; ++i) {
        const int lr = wv + 4 * i;
        const int r  = r0 + lr;
        float ac0 = 0.f, ac1 = 0.f, ac2 = 0.f, ac3 = 0.f, den = 0.f;
        if (r < N) {
            int p = offs[r];
            const int end = offs[r + 1];
            for (; p + 3 < end; p += 4) {
                int2 ea = epack[p + hf];
                int2 eb = epack[p + 2 + hf];
                uint2 ua = *(const uint2*)(y1b + (size_t)ea.x * 128 + c);
                uint2 ub = *(const uint2*)(y1b + (size_t)eb.x * 128 + c);
                float wa = __int_as_float(ea.y), wb = __int_as_float(eb.y);
                ac0 = fmaf(wa, bf_lo(ua.x), ac0); ac1 = fmaf(wa, bf_hi(ua.x), ac1);
                ac2 = fmaf(wa, bf_lo(ua.y), ac2); ac3 = fmaf(wa, bf_hi(ua.y), ac3);
                ac0 = fmaf(wb, bf_lo(ub.x), ac0); ac1 = fmaf(wb, bf_hi(ub.x), ac1);
                ac2 = fmaf(wb, bf_lo(ub.y), ac2); ac3 = fmaf(wb, bf_hi(ub.y), ac3);
                den += wa + wb;
            }
            for (; p + 1 < end; p += 2) {
                int2 ea = epack[p + hf];
                uint2 ua = *(const uint2*)(y1b + (size_t)ea.x * 128 + c);
                float wa = __int_as_float(ea.y);
                ac0 = fmaf(wa, bf_lo(ua.x), ac0); ac1 = fmaf(wa, bf_hi(ua.x), ac1);
                ac2 = fmaf(wa, bf_lo(ua.y), ac2); ac3 = fmaf(wa, bf_hi(ua.y), ac3);
                den += wa;
            }
            if (p < end && hf == 0) {   // odd tail edge: half 0 only
                int2 ea = epack[p];
                uint2 ua = *(const uint2*)(y1b + (size_t)ea.x * 128 + c);
                float wa = __int_as_float(ea.y);
                ac0 = fmaf(wa, bf_lo(ua.x), ac0); ac1 = fmaf(wa, bf_hi(ua.x), ac1);
                ac2 = fmaf(wa, bf_lo(ua.y), ac2); ac3 = fmaf(wa, bf_hi(ua.y), ac3);
                den += wa;
            }
        }
        ac0 += __shfl_xor(ac0, 32, 64);
        ac1 += __shfl_xor(ac1, 32, 64);
        ac2 += __shfl_xor(ac2, 32, 64);
        ac3 += __shfl_xor(ac3, 32, 64);
        den += __shfl_xor(den, 32, 64);
        if (hf == 0) {
            float m0 = 0.f, m1 = 0.f, m2 = 0.f, m3 = 0.f;
            if (den != 0.f) {
                float inv = 1.f / den;
                m0 = ac0 * inv; m1 = ac1 * inv; m2 = ac2 * inv; m3 = ac3 * inv;
            } else if (r < N) {
                uint2 u = *(const uint2*)(y1b + (size_t)r * 128 + c);
                m0 = bf_lo(u.x); m1 = bf_hi(u.x); m2 = bf_lo(u.y); m3 = bf_hi(u.y);
            }
            ushort4 o;
            o.x = f2bf(fmaf(av.x, m0, bv.x));
            o.y = f2bf(fmaf(av.y, m1, bv.y));
            o.z = f2bf(fmaf(av.z, m2, bv.z));
            o.w = f2bf(fmaf(av.w, m3, bv.w));
            *(ushort4*)(Ag[li >> 4] + lr * SA + (c & 63)) = o;
        }
    }
    __syncthreads();

    // ---------------- K=256 GEMM loop ----------------
    f32x4 acc[2][4];
#pragma unroll
    for (int rt = 0; rt < 2; ++rt)
#pragma unroll
        for (int ct = 0; ct < 4; ++ct)
            acc[rt][ct] = (f32x4){0.f, 0.f, 0.f, 0.f};

    for (int kc = 0; kc < 256; kc += 64) {
        if (kc < 128) {
#pragma unroll
            for (int i = 0; i < 2; ++i) {
                int idx = i * 256 + tid;
                int row = idx >> 3, seg = idx & 7;
                int gr  = r0 + row; if (gr >= N) gr = N - 1;
                uint4 v = *(const uint4*)(featb + (size_t)gr * 128 + kc + seg * 8);
                *(uint4*)(As + row * SA + seg * 8) = v;
            }
        }
#pragma unroll
        for (int i = 0; i < 4; ++i) {
            int idx = i * 256 + tid;
            int row = idx >> 3, seg = idx & 7;
            uint4 v = *(const uint4*)(Bb + (size_t)row * 256 + kc + seg * 8);
            *(uint4*)(Bs + row * SA + seg * 8) = v;
        }
        __syncthreads();

        const unsigned short* Ap = (kc < 128) ? As : Ag[(kc >> 6) & 1];
#pragma unroll
        for (int ks = 0; ks < 64; ks += 32) {
            bf16x8 af[2], bfr[4];
#pragma unroll
            for (int rt = 0; rt < 2; ++rt)
                af[rt] = *(const bf16x8*)(Ap + (wr * 32 + rt * 16 + m15) * SA + ks + quad * 8);
#pragma unroll
            for (int ct = 0; ct < 4; ++ct)
                bfr[ct] = *(const bf16x8*)(Bs + (wc * 64 + ct * 16 + m15) * SA + ks + quad * 8);
#pragma unroll
            for (int rt = 0; rt < 2; ++rt)
#pragma unroll
                for (int ct = 0; ct < 4; ++ct)
                    acc[rt][ct] = __builtin_amdgcn_mfma_f32_16x16x32_bf16(
                        af[rt], bfr[ct], acc[rt][ct], 0, 0, 0);
        }
        __syncthreads();
    }

    // ---------------- epilogue: relu + store f32 + col stats ----------------
#pragma unroll
    for (int ct = 0; ct < 4; ++ct) {
        int col = wc * 64 + ct * 16 + m15;
        float bz = bias[col];
        float s = 0.f, q = 0.f;
#pragma unroll
        for (int rt = 0; rt < 2; ++rt) {
#pragma unroll
            for (int reg = 0; reg < 4; ++reg) {
                int row = r0 + wr * 32 + rt * 16 + quad * 4 + reg;
                float vv = fmaxf(acc[rt][ct][reg] + bz, 0.f);
                if (row < N) {
                    Y[(size_t)row * 128 + col] = vv;
                } else {
                    vv = 0.f;
                }
                s += vv; q = fmaf(vv, vv, q);
            }
        }
        s += __shfl_xor(s, 16, 64); s += __shfl_xor(s, 32, 64);
        q += __shfl_xor(q, 16, 64); q += __shfl_xor(q, 32, 64);
        if (quad == 0) {
            atomicAdd(&bsum_s[col], s);
            atomicAdd(&bsq_s[col], q);
        }
    }
    __syncthreads();
    if (tid < 128) {
        const int slot = ((int)blockIdx.x & (NSLOT - 1)) * 128;
        atomicAdd(&sum[slot + tid],   (double)bsum_s[tid]);
        atomicAdd(&sumsq[slot + tid], (double)bsq_s[tid]);
    }
}

// ---------------------------------------------------------------------------
// bn2 affine (precomputed coefs) + row L2 normalize.
__global__ __launch_bounds__(256) void finalize(
    const float* __restrict__ Y2,
    const float* __restrict__ a, const float* __restrict__ b,
    float* __restrict__ out, int N)
{
    __shared__ float sa[128], sb[128];
    const int t = threadIdx.x;
    if (t < 128) { sa[t] = a[t]; sb[t] = b[t]; }
    __syncthreads();
    const int row  = (int)((blockIdx.x * 256u + t) >> 6);
    const int lane = t & 63;
    if (row >= N) return;
    const size_t base = (size_t)row * 128;
    float v0 = fmaf(sa[lane],      Y2[base + lane],      sb[lane]);
    float v1 = fmaf(sa[lane + 64], Y2[base + lane + 64], sb[lane + 64]);
    float ss = fmaf(v0, v0, v1 * v1);
#pragma unroll
    for (int o = 32; o; o >>= 1) ss += __shfl_xor(ss, o, 64);
    float nrm = sqrtf(ss);
    float inv = (nrm == 0.f) ? 1.f : 1.f / nrm;
    out[base + lane]      = v0 * inv;
    out[base + lane + 64] = v1 * inv;
}

// ---------------------------------------------------------------------------
extern "C" void kernel_launch(void* const* d_in, const int* in_sizes, int n_in,
                              void* d_out, int out_size, void* d_ws, size_t ws_size,
                              hipStream_t stream)
{
    const float* feat   = (const float*)d_in[0];
    const float* w      = (const float*)d_in[1];
    const float* Q_w    = (const float*)d_in[2];
    const float* Q_b    = (const float*)d_in[3];
    const float* W_w    = (const float*)d_in[4];
    const float* W_b    = (const float*)d_in[5];
    const float* gamma2 = (const float*)d_in[6];
    const float* beta2  = (const float*)d_in[7];
    const int*   src    = (const int*)d_in[8];
    const int*   dst    = (const int*)d_in[9];

    const int N = in_sizes[0] / 128;   // 50000
    const int E = in_sizes[1];         // 800000

    // workspace layout
    float*          y2    = (float*)d_ws;                            // N*128 f32
    unsigned short* featb = (unsigned short*)(y2 + (size_t)N * 128); // N*128 bf16
    unsigned short* y1b   = featb + (size_t)N * 128;                 // N*128 bf16
    int4*  tmp    = (int4*)(y1b + (size_t)N * 128);                  // E (16B aligned)
    int2*  epack  = (int2*)(tmp + E);                                // E
    int*   offs   = (int*)(epack + E);                               // N+1
    int*   coffs  = offs + (N + 1);                                  // 129
    int*   gcur   = coffs + 129;                                     // 128
    float* coefs  = (float*)(gcur + 128);                            // 512
    float* a1 = coefs, *b1 = coefs + 128, *a2 = coefs + 256, *b2 = coefs + 384;
    uintptr_t qp = ((uintptr_t)(coefs + 512) + 15) & ~(uintptr_t)15;
    unsigned short* Qwb = (unsigned short*)qp;                       // 128*128 bf16
    unsigned short* Wwb = Qwb + 128 * 128;                           // 128*256 bf16
    uintptr_t sp = ((uintptr_t)(Wwb + 128 * 256) + 15) & ~(uintptr_t)15;
    double* stats = (double*)sp;                                     // 4*NSLOT*128 <- zeroed
    double* sum1   = stats;
    double* sumsq1 = stats + NSLOT * 128;
    double* sum2   = stats + 2 * NSLOT * 128;
    double* sumsq2 = stats + 3 * NSLOT * 128;
    int*   ccnt   = (int*)(stats + 4 * NSLOT * 128);                 // 128 <- zeroed

    hipMemsetAsync(stats, 0,
                   4 * NSLOT * 128 * sizeof(double) + 128 * sizeof(int),
                   stream);

    const double invN = 1.0 / (double)N;
    const int GB = (N + 63) / 64;               // gemm blocks (782)
    const int NB = (N + 511) >> 9;              // coarse buckets (98)
    const int CB = (N * 128 / 4 + 255) / 256;   // feat cast blocks
    const int HB = (E + 2047) / 2048;           // histogram/bin blocks
    const int QB = 16;                          // Q_w cast blocks
    const int WB = 32;                          // W_w cast blocks

    k_pre<<<CB + HB + QB + WB, 256, 0, stream>>>(
        feat, featb, N * 128, dst, ccnt, E, CB, HB,
        Q_w, Qwb, W_w, Wwb);
    k_coffs<<<1, 128, 0, stream>>>(ccnt, coffs, gcur, offs, N, E);

    // fatB: bin || gemm1 -> y1b bf16 + stats1
    k_bin_gemm<<<HB + GB, 256, 0, stream>>>(
        src, dst, w, gcur, tmp, E, HB,
        featb, Qwb, Q_b, y1b, sum1, sumsq1, N);

    // fat: bn_coef1 (block 0) || refine (blocks 1..NB)
    k_bnref<<<NB + 1, 256, 0, stream>>>(
        sum1, sumsq1, gamma2, beta2, a1, b1, invN,
        tmp, coffs, offs, epack, N);

    // gemm2 with fused per-tile gather (reads y1b via epack/offs)
    gemm2_fused<<<GB, 256, 0, stream>>>(
        featb, y1b, offs, epack, a1, b1, Wwb, W_b,
        y2, sum2, sumsq2, N);

    bn_coef<<<1, 128, 0, stream>>>(sum2, sumsq2, gamma2, beta2, a2, b2, invN);
    finalize<<<(N * 64 + 255) / 256, 256, 0, stream>>>(
        y2, a2, b2, (float*)d_out, N);
}

// Round 6
// 234.494 us; speedup vs baseline: 1.2819x; 1.2819x over previous
//
#include <hip/hip_runtime.h>
#include <stdint.h>

// PinConv pipeline, round 16:
//  - REVERT round-15 gather fusion (regression: gather lost its 50k-wave TLP
//    inside the GEMM grid; occupancy 17.8%, 132us). Back to standalone
//    gather_agg (round-14 structure, 227.7us best).
//  - GEMM tiles 64x128 -> 128x128 (both gemm1 and gemm2): halves per-output
//    staging + barriers, doubles MFMA per K-step per wave (32), halves block
//    count. LDS ~38KB -> 4 blocks/CU.
//  - bn_coef2 folded into finalize (grid-strided, per-block redundant coef
//    reduce into LDS): 7 dispatches, no device-scope fences.

#define BN_EPS 1e-5f
#define NSLOT 32

typedef __attribute__((ext_vector_type(8))) short bf16x8;
typedef __attribute__((ext_vector_type(4))) float f32x4;

static __device__ __forceinline__ unsigned short f2bf(float f) {
    uint32_t u = __builtin_bit_cast(uint32_t, f);
    u += 0x7fffu + ((u >> 16) & 1u);          // round-to-nearest-even
    return (unsigned short)(u >> 16);
}
static __device__ __forceinline__ float bf_lo(uint32_t u) {
    return __builtin_bit_cast(float, u << 16);
}
static __device__ __forceinline__ float bf_hi(uint32_t u) {
    return __builtin_bit_cast(float, u & 0xffff0000u);
}

static __device__ __forceinline__ void cast_blk(
    const float* __restrict__ src, unsigned short* __restrict__ dst,
    int n, int blk)
{
    int i = (blk * 256 + threadIdx.x) * 4;
    if (i + 3 < n) {
        float4 v = *(const float4*)(src + i);
        ushort4 o;
        o.x = f2bf(v.x); o.y = f2bf(v.y); o.z = f2bf(v.z); o.w = f2bf(v.w);
        *(ushort4*)(dst + i) = o;
    } else {
        for (int j = i; j < n; ++j) dst[j] = f2bf(src[j]);
    }
}

// ---------------------------------------------------------------------------
// Fused: blocks [0,CB) cast feat; [CB,CB+HB) coarse-histogram dst into
// 512-wide buckets; [CB+HB,..) cast Q_w / W_w to bf16. No fences.
__global__ __launch_bounds__(256) void k_pre(
    const float* __restrict__ feat, unsigned short* __restrict__ featb, int nf,
    const int* __restrict__ dst, int* __restrict__ ccnt, int E, int CB, int HB,
    const float* __restrict__ Qw, unsigned short* __restrict__ Qwb,
    const float* __restrict__ Ww, unsigned short* __restrict__ Wwb)
{
    int b = (int)blockIdx.x;
    if (b < CB) { cast_blk(feat, featb, nf, b); return; }
    b -= CB;
    if (b >= HB) {
        b -= HB;
        if (b < 16) cast_blk(Qw, Qwb, 128 * 128, b);
        else        cast_blk(Ww, Wwb, 128 * 256, b - 16);
        return;
    }
    __shared__ int hcnt[128];
    const int tid = threadIdx.x;
    if (tid < 128) hcnt[tid] = 0;
    __syncthreads();
    const int base_e = b * 2048;
#pragma unroll
    for (int j = 0; j < 8; ++j) {
        int e = base_e + j * 256 + tid;
        if (e < E) atomicAdd(&hcnt[dst[e] >> 9], 1);
    }
    __syncthreads();
    if (tid < 128 && hcnt[tid] > 0) atomicAdd(&ccnt[tid], hcnt[tid]);
}

// ---------------------------------------------------------------------------
// Single block: exclusive scan of 128 bucket counts -> coffs[129], gcur,
// and offs[N] = E.
__global__ __launch_bounds__(128) void k_coffs(
    const int* __restrict__ ccnt, int* __restrict__ coffs,
    int* __restrict__ gcur, int* __restrict__ offs, int N, int E)
{
    __shared__ int w0sum;
    const int t = threadIdx.x;
    const int lane = t & 63, wv = t >> 6;
    int v = ccnt[t];
    int incl = v;
#pragma unroll
    for (int o = 1; o < 64; o <<= 1) {
        int u = __shfl_up(incl, o, 64);
        if (lane >= o) incl += u;
    }
    if (wv == 0 && lane == 63) w0sum = incl;
    __syncthreads();
    int excl = incl - v + (wv ? w0sum : 0);
    coffs[t] = excl;
    gcur[t]  = excl;
    if (t == 127) { coffs[128] = excl + v; offs[N] = E; }
}

// ---------------------------------------------------------------------------
// GEMM body (LDS-staged, 128x128 tile, 4 waves in 2x2): Y = relu(A@B^T+bias).
// A rows bf16 from A_lo (k<128) / A_hi (k>=128); B bf16 [128][K] pre-cast ->
// staging is pure uint4 copy. Output f32 or bf16. Col sum/sumsq -> striped
// fp64 slots. No fences.
template<int K, bool OUT_BF16>
static __device__ __forceinline__ void gemm_body(
    int bid,
    const unsigned short* __restrict__ A_lo,
    const unsigned short* __restrict__ A_hi,
    const unsigned short* __restrict__ Bb,
    const float* __restrict__ bias,
    void* __restrict__ Yv,
    double* __restrict__ sum, double* __restrict__ sumsq, int N)
{
    constexpr int SA = 72;
    __shared__ unsigned short As[128 * SA];
    __shared__ unsigned short Bs[128 * SA];
    __shared__ float bsum_s[128], bsq_s[128];

    const int tid  = threadIdx.x;
    const int lane = tid & 63;
    const int wv   = tid >> 6;
    const int wr   = wv >> 1;
    const int wc   = wv & 1;
    const int m15  = lane & 15;
    const int quad = lane >> 4;
    const int r0   = bid * 128;

    if (tid < 128) { bsum_s[tid] = 0.f; bsq_s[tid] = 0.f; }

    f32x4 acc[4][4];
#pragma unroll
    for (int rt = 0; rt < 4; ++rt)
#pragma unroll
        for (int ct = 0; ct < 4; ++ct)
            acc[rt][ct] = (f32x4){0.f, 0.f, 0.f, 0.f};

    for (int kc = 0; kc < K; kc += 64) {
        const unsigned short* Ap = (kc < 128) ? A_lo : A_hi;
        const int koff = kc & 127;
        // A tile: 128 rows x 64 bf16 -> 4 x 256 x 16B
#pragma unroll
        for (int i = 0; i < 4; ++i) {
            int idx = i * 256 + tid;
            int row = idx >> 3, seg = idx & 7;
            int gr  = r0 + row; if (gr >= N) gr = N - 1;
            uint4 v = *(const uint4*)(Ap + (size_t)gr * 128 + koff + seg * 8);
            *(uint4*)(As + row * SA + seg * 8) = v;
        }
        // B tile: 128 rows x 64 bf16 -> 4 x 256 x 16B (pure copy)
#pragma unroll
        for (int i = 0; i < 4; ++i) {
            int idx = i * 256 + tid;
            int row = idx >> 3, seg = idx & 7;
            uint4 v = *(const uint4*)(Bb + (size_t)row * K + kc + seg * 8);
            *(uint4*)(Bs + row * SA + seg * 8) = v;
        }
        __syncthreads();

#pragma unroll
        for (int ks = 0; ks < 64; ks += 32) {
            bf16x8 af[4], bfr[4];
#pragma unroll
            for (int rt = 0; rt < 4; ++rt)
                af[rt] = *(const bf16x8*)(As + (wr * 64 + rt * 16 + m15) * SA + ks + quad * 8);
#pragma unroll
            for (int ct = 0; ct < 4; ++ct)
                bfr[ct] = *(const bf16x8*)(Bs + (wc * 64 + ct * 16 + m15) * SA + ks + quad * 8);
#pragma unroll
            for (int rt = 0; rt < 4; ++rt)
#pragma unroll
                for (int ct = 0; ct < 4; ++ct)
                    acc[rt][ct] = __builtin_amdgcn_mfma_f32_16x16x32_bf16(
                        af[rt], bfr[ct], acc[rt][ct], 0, 0, 0);
        }
        __syncthreads();
    }

#pragma unroll
    for (int ct = 0; ct < 4; ++ct) {
        int col = wc * 64 + ct * 16 + m15;
        float bz = bias[col];
        float s = 0.f, q = 0.f;
#pragma unroll
        for (int rt = 0; rt < 4; ++rt) {
#pragma unroll
            for (int reg = 0; reg < 4; ++reg) {
                int row = r0 + wr * 64 + rt * 16 + quad * 4 + reg;
                float vv = fmaxf(acc[rt][ct][reg] + bz, 0.f);
                if (row < N) {
                    if constexpr (OUT_BF16)
                        ((unsigned short*)Yv)[(size_t)row * 128 + col] = f2bf(vv);
                    else
                        ((float*)Yv)[(size_t)row * 128 + col] = vv;
                } else {
                    vv = 0.f;
                }
                s += vv; q = fmaf(vv, vv, q);
            }
        }
        s += __shfl_xor(s, 16, 64); s += __shfl_xor(s, 32, 64);
        q += __shfl_xor(q, 16, 64); q += __shfl_xor(q, 32, 64);
        if (quad == 0) {
            atomicAdd(&bsum_s[col], s);
            atomicAdd(&bsq_s[col], q);
        }
    }
    __syncthreads();
    if (tid < 128) {
        const int slot = (bid & (NSLOT - 1)) * 128;
        atomicAdd(&sum[slot + tid],   (double)bsum_s[tid]);
        atomicAdd(&sumsq[slot + tid], (double)bsq_s[tid]);
    }
}

// ---------------------------------------------------------------------------
// bn coef body: reduce 32 slots -> bn affine coefs. t in [0,128).
static __device__ __forceinline__ void bn_coef_body(
    int t, const double* __restrict__ sum, const double* __restrict__ sumsq,
    const float* __restrict__ gamma, const float* __restrict__ beta,
    float* __restrict__ a, float* __restrict__ b, double invN)
{
    double ms = 0.0, qs = 0.0;
#pragma unroll
    for (int s = 0; s < NSLOT; ++s) {
        ms += sum[s * 128 + t];
        qs += sumsq[s * 128 + t];
    }
    float mean = (float)(ms * invN);
    float var  = (float)(qs * invN) - mean * mean;
    float sc = rsqrtf(var + BN_EPS) * gamma[t];
    a[t] = sc;
    b[t] = fmaf(-mean, sc, beta[t]);
}

// ---------------------------------------------------------------------------
// bin body: bin edges into coarse buckets of 512 dsts (int4 records).
static __device__ __forceinline__ void bin_body(
    int bid,
    const int* __restrict__ src, const int* __restrict__ dst,
    const float* __restrict__ w, int* __restrict__ gcur,
    int4* __restrict__ tmp, int E)
{
    __shared__ int hcnt[128];
    __shared__ int hbase[128];
    const int tid = threadIdx.x;
    if (tid < 128) hcnt[tid] = 0;
    __syncthreads();

    int d8[8], s8[8], slot8[8];
    float w8[8];
#pragma unroll
    for (int j = 0; j < 8; ++j) {
        int e = bid * 2048 + j * 256 + tid;
        if (e < E) {
            d8[j] = dst[e]; s8[j] = src[e]; w8[j] = w[e];
            slot8[j] = atomicAdd(&hcnt[d8[j] >> 9], 1);
        } else d8[j] = -1;
    }
    __syncthreads();
    if (tid < 128 && hcnt[tid] > 0)
        hbase[tid] = atomicAdd(&gcur[tid], hcnt[tid]);
    __syncthreads();
#pragma unroll
    for (int j = 0; j < 8; ++j) {
        if (d8[j] >= 0) {
            int pos = hbase[d8[j] >> 9] + slot8[j];
            tmp[pos] = make_int4(s8[j], __float_as_int(w8[j]), d8[j], 0);
        }
    }
}

// fatB: blocks [0,HB) bin edges; blocks [HB,HB+GB) run gemm1 -> y1b bf16.
__global__ __launch_bounds__(256) void k_bin_gemm(
    const int* __restrict__ src, const int* __restrict__ dst,
    const float* __restrict__ w, int* __restrict__ gcur,
    int4* __restrict__ tmp, int E, int HB,
    const unsigned short* __restrict__ featb,
    const unsigned short* __restrict__ Qwb, const float* __restrict__ Qb,
    unsigned short* __restrict__ y1b,
    double* __restrict__ sum, double* __restrict__ sumsq, int N)
{
    if ((int)blockIdx.x < HB)
        bin_body(blockIdx.x, src, dst, w, gcur, tmp, E);
    else
        gemm_body<128, true>(blockIdx.x - HB, featb, featb, Qwb, Qb, y1b,
                             sum, sumsq, N);
}

// ---------------------------------------------------------------------------
// refine body: per bucket — count per-dst in LDS, scan (+coffs base), write
// offs slice, scatter records to epack in exact dst order.
static __device__ __forceinline__ void refine_body(
    int b,
    const int4* __restrict__ tmp, const int* __restrict__ coffs,
    int* __restrict__ offs, int2* __restrict__ epack, int N)
{
    __shared__ int hist[512];
    __shared__ int wpre[4];
    const int d0   = b << 9;
    const int dlim = min(512, N - d0);
    const int tid  = threadIdx.x;
    const int lane = tid & 63, wv = tid >> 6;
    const int start = coffs[b];
    const int end   = coffs[b + 1];

    hist[tid] = 0; hist[tid + 256] = 0;
    __syncthreads();

    for (int p = start + tid; p < end; p += 256)
        atomicAdd(&hist[tmp[p].z - d0], 1);
    __syncthreads();

    int v0 = hist[2 * tid], v1 = hist[2 * tid + 1];
    int s = v0 + v1;
    int incl = s;
#pragma unroll
    for (int o = 1; o < 64; o <<= 1) {
        int t = __shfl_up(incl, o, 64);
        if (lane >= o) incl += t;
    }
    if (lane == 63) wpre[wv] = incl;
    __syncthreads();
    if (tid == 0) {
        int r = 0;
#pragma unroll
        for (int i = 0; i < 4; ++i) { int t = wpre[i]; wpre[i] = r; r += t; }
    }
    __syncthreads();
    int e0 = start + wpre[wv] + incl - s;
    if (2 * tid < dlim)     offs[d0 + 2 * tid]     = e0;
    if (2 * tid + 1 < dlim) offs[d0 + 2 * tid + 1] = e0 + v0;
    hist[2 * tid]     = e0;
    hist[2 * tid + 1] = e0 + v0;
    __syncthreads();

    for (int p = start + tid; p < end; p += 256) {
        int4 rec = tmp[p];
        int pos = atomicAdd(&hist[rec.z - d0], 1);
        epack[pos] = make_int2(rec.x, rec.y);
    }
}

// fat: block 0 = bn_coef1 reduce; blocks [1,NB] = refine buckets.
__global__ __launch_bounds__(256) void k_bnref(
    const double* __restrict__ sum, const double* __restrict__ sumsq,
    const float* __restrict__ gamma, const float* __restrict__ beta,
    float* __restrict__ a, float* __restrict__ b, double invN,
    const int4* __restrict__ tmp, const int* __restrict__ coffs,
    int* __restrict__ offs, int2* __restrict__ epack, int N)
{
    if (blockIdx.x == 0) {
        if (threadIdx.x < 128)
            bn_coef_body(threadIdx.x, sum, sumsq, gamma, beta, a, b, invN);
        return;
    }
    refine_body((int)blockIdx.x - 1, tmp, coffs, offs, epack, N);
}

// ---------------------------------------------------------------------------
// One wave per dst row, 2 edges in flight (32-lane halves, 4 cols/lane).
// Reads raw relu y1b; applies bn affine (a,b) to the weighted mean (or to
// the own row when den==0). Writes agg bf16.
__global__ __launch_bounds__(256) void gather_agg(
    const unsigned short* __restrict__ y1b,
    const int* __restrict__ offs, const int2* __restrict__ epack,
    const float* __restrict__ a, const float* __restrict__ b,
    unsigned short* __restrict__ aggb, int N)
{
    const int r    = (int)((blockIdx.x * 256u + threadIdx.x) >> 6);
    const int lane = threadIdx.x & 63;
    const int li   = lane & 31;     // owns columns 4*li .. 4*li+3
    const int hf   = lane >> 5;     // 0: even edge of pair, 1: odd
    if (r >= N) return;
    int p = offs[r];
    const int end = offs[r + 1];
    float ac0 = 0.f, ac1 = 0.f, ac2 = 0.f, ac3 = 0.f, den = 0.f;
    for (; p + 3 < end; p += 4) {
        int2 ea = epack[p + hf];
        int2 eb = epack[p + 2 + hf];
        uint2 ua = *(const uint2*)(y1b + (size_t)ea.x * 128 + 4 * li);
        uint2 ub = *(const uint2*)(y1b + (size_t)eb.x * 128 + 4 * li);
        float wa = __int_as_float(ea.y), wb = __int_as_float(eb.y);
        ac0 = fmaf(wa, bf_lo(ua.x), ac0); ac1 = fmaf(wa, bf_hi(ua.x), ac1);
        ac2 = fmaf(wa, bf_lo(ua.y), ac2); ac3 = fmaf(wa, bf_hi(ua.y), ac3);
        ac0 = fmaf(wb, bf_lo(ub.x), ac0); ac1 = fmaf(wb, bf_hi(ub.x), ac1);
        ac2 = fmaf(wb, bf_lo(ub.y), ac2); ac3 = fmaf(wb, bf_hi(ub.y), ac3);
        den += wa + wb;
    }
    for (; p + 1 < end; p += 2) {
        int2 ea = epack[p + hf];
        uint2 ua = *(const uint2*)(y1b + (size_t)ea.x * 128 + 4 * li);
        float wa = __int_as_float(ea.y);
        ac0 = fmaf(wa, bf_lo(ua.x), ac0); ac1 = fmaf(wa, bf_hi(ua.x), ac1);
        ac2 = fmaf(wa, bf_lo(ua.y), ac2); ac3 = fmaf(wa, bf_hi(ua.y), ac3);
        den += wa;
    }
    if (p < end && hf == 0) {   // odd tail edge: half 0 only
        int2 ea = epack[p];
        uint2 ua = *(const uint2*)(y1b + (size_t)ea.x * 128 + 4 * li);
        float wa = __int_as_float(ea.y);
        ac0 = fmaf(wa, bf_lo(ua.x), ac0); ac1 = fmaf(wa, bf_hi(ua.x), ac1);
        ac2 = fmaf(wa, bf_lo(ua.y), ac2); ac3 = fmaf(wa, bf_hi(ua.y), ac3);
        den += wa;
    }
    ac0 += __shfl_xor(ac0, 32, 64);
    ac1 += __shfl_xor(ac1, 32, 64);
    ac2 += __shfl_xor(ac2, 32, 64);
    ac3 += __shfl_xor(ac3, 32, 64);
    den += __shfl_xor(den, 32, 64);
    if (hf) return;
    const int c = 4 * li;
    float4 av = *(const float4*)(a + c);
    float4 bv = *(const float4*)(b + c);
    float m0, m1, m2, m3;
    if (den != 0.f) {
        float inv = 1.f / den;
        m0 = ac0 * inv; m1 = ac1 * inv; m2 = ac2 * inv; m3 = ac3 * inv;
    } else {
        uint2 u = *(const uint2*)(y1b + (size_t)r * 128 + c);
        m0 = bf_lo(u.x); m1 = bf_hi(u.x); m2 = bf_lo(u.y); m3 = bf_hi(u.y);
    }
    ushort4 o;
    o.x = f2bf(fmaf(av.x, m0, bv.x));
    o.y = f2bf(fmaf(av.y, m1, bv.y));
    o.z = f2bf(fmaf(av.z, m2, bv.z));
    o.w = f2bf(fmaf(av.w, m3, bv.w));
    *(ushort4*)(aggb + (size_t)r * 128 + c) = o;
}

// ---------------------------------------------------------------------------
// gemm2 standalone (K=256, A = [featb|aggb]) -> y2 f32 + stats2.
__global__ __launch_bounds__(256) void gemm_bn2(
    const unsigned short* __restrict__ A_lo,
    const unsigned short* __restrict__ A_hi,
    const unsigned short* __restrict__ Bb,
    const float* __restrict__ bias,
    float* __restrict__ Y,
    double* __restrict__ sum, double* __restrict__ sumsq, int N)
{
    gemm_body<256, false>(blockIdx.x, A_lo, A_hi, Bb, bias, Y, sum, sumsq, N);
}

// ---------------------------------------------------------------------------
// finalize: per-block bn2 coef reduce (redundant, into LDS) + grid-strided
// bn2 affine + row L2 normalize.
__global__ __launch_bounds__(256) void finalize(
    const float* __restrict__ Y2,
    const double* __restrict__ sum, const double* __restrict__ sumsq,
    const float* __restrict__ gamma, const float* __restrict__ beta,
    double invN,
    float* __restrict__ out, int N)
{
    __shared__ float sa[128], sb[128];
    const int t = threadIdx.x;
    if (t < 128)
        bn_coef_body(t, sum, sumsq, gamma, beta, sa, sb, invN);
    __syncthreads();
    const int lane = t & 63;
    const int wstride = (int)gridDim.x * 4;
    for (int row = (int)blockIdx.x * 4 + (t >> 6); row < N; row += wstride) {
        const size_t base = (size_t)row * 128;
        float v0 = fmaf(sa[lane],      Y2[base + lane],      sb[lane]);
        float v1 = fmaf(sa[lane + 64], Y2[base + lane + 64], sb[lane + 64]);
        float ss = fmaf(v0, v0, v1 * v1);
#pragma unroll
        for (int o = 32; o; o >>= 1) ss += __shfl_xor(ss, o, 64);
        float nrm = sqrtf(ss);
        float inv = (nrm == 0.f) ? 1.f : 1.f / nrm;
        out[base + lane]      = v0 * inv;
        out[base + lane + 64] = v1 * inv;
    }
}

// ---------------------------------------------------------------------------
extern "C" void kernel_launch(void* const* d_in, const int* in_sizes, int n_in,
                              void* d_out, int out_size, void* d_ws, size_t ws_size,
                              hipStream_t stream)
{
    const float* feat   = (const float*)d_in[0];
    const float* w      = (const float*)d_in[1];
    const float* Q_w    = (const float*)d_in[2];
    const float* Q_b    = (const float*)d_in[3];
    const float* W_w    = (const float*)d_in[4];
    const float* W_b    = (const float*)d_in[5];
    const float* gamma2 = (const float*)d_in[6];
    const float* beta2  = (const float*)d_in[7];
    const int*   src    = (const int*)d_in[8];
    const int*   dst    = (const int*)d_in[9];

    const int N = in_sizes[0] / 128;   // 50000
    const int E = in_sizes[1];         // 800000

    // workspace layout
    float*          y2    = (float*)d_ws;                            // N*128 f32
    unsigned short* featb = (unsigned short*)(y2 + (size_t)N * 128); // N*128 bf16
    unsigned short* aggb  = featb + (size_t)N * 128;                 // N*128 bf16
    unsigned short* y1b   = aggb + (size_t)N * 128;                  // N*128 bf16
    int4*  tmp    = (int4*)(y1b + (size_t)N * 128);                  // E (16B aligned)
    int2*  epack  = (int2*)(tmp + E);                                // E
    int*   offs   = (int*)(epack + E);                               // N+1
    int*   coffs  = offs + (N + 1);                                  // 129
    int*   gcur   = coffs + 129;                                     // 128
    float* coefs  = (float*)(gcur + 128);                            // 512
    float* a1 = coefs, *b1 = coefs + 128;
    uintptr_t qp = ((uintptr_t)(coefs + 512) + 15) & ~(uintptr_t)15;
    unsigned short* Qwb = (unsigned short*)qp;                       // 128*128 bf16
    unsigned short* Wwb = Qwb + 128 * 128;                           // 128*256 bf16
    uintptr_t sp = ((uintptr_t)(Wwb + 128 * 256) + 15) & ~(uintptr_t)15;
    double* stats = (double*)sp;                                     // 4*NSLOT*128 <- zeroed
    double* sum1   = stats;
    double* sumsq1 = stats + NSLOT * 128;
    double* sum2   = stats + 2 * NSLOT * 128;
    double* sumsq2 = stats + 3 * NSLOT * 128;
    int*   ccnt   = (int*)(stats + 4 * NSLOT * 128);                 // 128 <- zeroed

    hipMemsetAsync(stats, 0,
                   4 * NSLOT * 128 * sizeof(double) + 128 * sizeof(int),
                   stream);

    const double invN = 1.0 / (double)N;
    const int GB = (N + 127) / 128;             // gemm blocks (391)
    const int NB = (N + 511) >> 9;              // coarse buckets (98)
    const int CB = (N * 128 / 4 + 255) / 256;   // feat cast blocks
    const int HB = (E + 2047) / 2048;           // histogram/bin blocks
    const int QB = 16;                          // Q_w cast blocks
    const int WB = 32;                          // W_w cast blocks

    k_pre<<<CB + HB + QB + WB, 256, 0, stream>>>(
        feat, featb, N * 128, dst, ccnt, E, CB, HB,
        Q_w, Qwb, W_w, Wwb);
    k_coffs<<<1, 128, 0, stream>>>(ccnt, coffs, gcur, offs, N, E);

    // fatB: bin || gemm1 -> y1b bf16 + stats1
    k_bin_gemm<<<HB + GB, 256, 0, stream>>>(
        src, dst, w, gcur, tmp, E, HB,
        featb, Qwb, Q_b, y1b, sum1, sumsq1, N);

    // fat: bn_coef1 (block 0) || refine (blocks 1..NB)
    k_bnref<<<NB + 1, 256, 0, stream>>>(
        sum1, sumsq1, gamma2, beta2, a1, b1, invN,
        tmp, coffs, offs, epack, N);

    gather_agg<<<(N * 64 + 255) / 256, 256, 0, stream>>>(
        y1b, offs, epack, a1, b1, aggb, N);

    gemm_bn2<<<GB, 256, 0, stream>>>(
        featb, aggb, Wwb, W_b, y2, sum2, sumsq2, N);

    finalize<<<1024, 256, 0, stream>>>(
        y2, sum2, sumsq2, gamma2, beta2, invN, (float*)d_out, N);
}

// Round 7
// 225.824 us; speedup vs baseline: 1.3311x; 1.0384x over previous
//
#include <hip/hip_runtime.h>
#include <stdint.h>

// PinConv pipeline, round 17 (base = round 14/227.7us, best):
//  - REVERT round-16 changes (128^2 tile taxed co-resident bin blocks' LDS
//    occupancy; finalize's per-block redundant stats reduce added 64MB L2).
//  - k_coffs dispatch ELIMINATED: bin/refine blocks recompute the 128-bucket
//    exclusive scan redundantly in-LDS (512B read + wave scan); shared cursor
//    is zero-based gofs[128] (memset-zeroed). offs[N]=E moved to k_pre.
//    Serial chain 7 -> 6 dispatches.
//  - gather_agg: 8 edges in flight (was 4) for deeper MLP; latency-bound per
//    counters (HBM 29%, VALU 39%, occ 61%).

#define BN_EPS 1e-5f
#define NSLOT 32

typedef __attribute__((ext_vector_type(8))) short bf16x8;
typedef __attribute__((ext_vector_type(4))) float f32x4;

static __device__ __forceinline__ unsigned short f2bf(float f) {
    uint32_t u = __builtin_bit_cast(uint32_t, f);
    u += 0x7fffu + ((u >> 16) & 1u);          // round-to-nearest-even
    return (unsigned short)(u >> 16);
}
static __device__ __forceinline__ float bf_lo(uint32_t u) {
    return __builtin_bit_cast(float, u << 16);
}
static __device__ __forceinline__ float bf_hi(uint32_t u) {
    return __builtin_bit_cast(float, u & 0xffff0000u);
}

static __device__ __forceinline__ void cast_blk(
    const float* __restrict__ src, unsigned short* __restrict__ dst,
    int n, int blk)
{
    int i = (blk * 256 + threadIdx.x) * 4;
    if (i + 3 < n) {
        float4 v = *(const float4*)(src + i);
        ushort4 o;
        o.x = f2bf(v.x); o.y = f2bf(v.y); o.z = f2bf(v.z); o.w = f2bf(v.w);
        *(ushort4*)(dst + i) = o;
    } else {
        for (int j = i; j < n; ++j) dst[j] = f2bf(src[j]);
    }
}

// Redundant per-block exclusive scan of ccnt[128]. Threads 0..127 get
// excl (exclusive prefix) and v (own count); also mirrors into sc[] if given.
// Caller must __syncthreads() before first use of outputs beyond own lane.
static __device__ __forceinline__ void scan_ccnt(
    const int* __restrict__ ccnt, int* excl_out, int* v_out, int* w0s)
{
    const int t = threadIdx.x;
    int v = 0, incl = 0;
    if (t < 128) {
        v = ccnt[t];
        incl = v;
        const int lane = t & 63;
#pragma unroll
        for (int o = 1; o < 64; o <<= 1) {
            int u = __shfl_up(incl, o, 64);
            if (lane >= o) incl += u;
        }
        if (t == 63) *w0s = incl;
    }
    __syncthreads();
    int excl = 0;
    if (t < 128) excl = incl - v + ((t >> 6) ? *w0s : 0);
    *excl_out = excl;
    *v_out = v;
}

// ---------------------------------------------------------------------------
// Fused: blocks [0,CB) cast feat; [CB,CB+HB) coarse-histogram dst into
// 512-wide buckets; [CB+HB,..) cast Q_w / W_w to bf16. No fences.
__global__ __launch_bounds__(256) void k_pre(
    const float* __restrict__ feat, unsigned short* __restrict__ featb, int nf,
    const int* __restrict__ dst, int* __restrict__ ccnt, int E, int CB, int HB,
    const float* __restrict__ Qw, unsigned short* __restrict__ Qwb,
    const float* __restrict__ Ww, unsigned short* __restrict__ Wwb,
    int* __restrict__ offs, int N)
{
    int b = (int)blockIdx.x;
    if (b < CB) {
        if (b == 0 && threadIdx.x == 0) offs[N] = E;
        cast_blk(feat, featb, nf, b);
        return;
    }
    b -= CB;
    if (b >= HB) {
        b -= HB;
        if (b < 16) cast_blk(Qw, Qwb, 128 * 128, b);
        else        cast_blk(Ww, Wwb, 128 * 256, b - 16);
        return;
    }
    __shared__ int hcnt[128];
    const int tid = threadIdx.x;
    if (tid < 128) hcnt[tid] = 0;
    __syncthreads();
    const int base_e = b * 2048;
#pragma unroll
    for (int j = 0; j < 8; ++j) {
        int e = base_e + j * 256 + tid;
        if (e < E) atomicAdd(&hcnt[dst[e] >> 9], 1);
    }
    __syncthreads();
    if (tid < 128 && hcnt[tid] > 0) atomicAdd(&ccnt[tid], hcnt[tid]);
}

// ---------------------------------------------------------------------------
// GEMM body (LDS-staged, 64x128 tile): Y = relu(A @ B^T + bias); A rows bf16
// from A_lo/A_hi (K split at 128). B bf16 [128][K] pre-cast -> staging is a
// pure uint4 copy. Output f32 or bf16. Col sum/sumsq -> striped fp64 slots.
template<int K, bool OUT_BF16>
static __device__ __forceinline__ void gemm_body(
    int bid,
    const unsigned short* __restrict__ A_lo,
    const unsigned short* __restrict__ A_hi,
    const unsigned short* __restrict__ Bb,
    const float* __restrict__ bias,
    void* __restrict__ Yv,
    double* __restrict__ sum, double* __restrict__ sumsq, int N)
{
    constexpr int SA = 72;
    __shared__ unsigned short As[64 * SA];
    __shared__ unsigned short Bs[128 * SA];
    __shared__ float bsum_s[128], bsq_s[128];

    const int tid  = threadIdx.x;
    const int lane = tid & 63;
    const int wv   = tid >> 6;
    const int wr   = wv >> 1;
    const int wc   = wv & 1;
    const int m15  = lane & 15;
    const int quad = lane >> 4;
    const int r0   = bid * 64;

    if (tid < 128) { bsum_s[tid] = 0.f; bsq_s[tid] = 0.f; }

    f32x4 acc[2][4];
#pragma unroll
    for (int rt = 0; rt < 2; ++rt)
#pragma unroll
        for (int ct = 0; ct < 4; ++ct)
            acc[rt][ct] = (f32x4){0.f, 0.f, 0.f, 0.f};

    for (int kc = 0; kc < K; kc += 64) {
        const unsigned short* Ap = (kc < 128) ? A_lo : A_hi;
        const int koff = kc & 127;
#pragma unroll
        for (int i = 0; i < 2; ++i) {
            int idx = i * 256 + tid;
            int row = idx >> 3, seg = idx & 7;
            int gr  = r0 + row; if (gr >= N) gr = N - 1;
            uint4 v = *(const uint4*)(Ap + (size_t)gr * 128 + koff + seg * 8);
            *(uint4*)(As + row * SA + seg * 8) = v;
        }
#pragma unroll
        for (int i = 0; i < 4; ++i) {
            int idx = i * 256 + tid;
            int row = idx >> 3, seg = idx & 7;
            uint4 v = *(const uint4*)(Bb + (size_t)row * K + kc + seg * 8);
            *(uint4*)(Bs + row * SA + seg * 8) = v;
        }
        __syncthreads();

#pragma unroll
        for (int ks = 0; ks < 64; ks += 32) {
            bf16x8 af[2], bfr[4];
#pragma unroll
            for (int rt = 0; rt < 2; ++rt)
                af[rt] = *(const bf16x8*)(As + (wr * 32 + rt * 16 + m15) * SA + ks + quad * 8);
#pragma unroll
            for (int ct = 0; ct < 4; ++ct)
                bfr[ct] = *(const bf16x8*)(Bs + (wc * 64 + ct * 16 + m15) * SA + ks + quad * 8);
#pragma unroll
            for (int rt = 0; rt < 2; ++rt)
#pragma unroll
                for (int ct = 0; ct < 4; ++ct)
                    acc[rt][ct] = __builtin_amdgcn_mfma_f32_16x16x32_bf16(
                        af[rt], bfr[ct], acc[rt][ct], 0, 0, 0);
        }
        __syncthreads();
    }

#pragma unroll
    for (int ct = 0; ct < 4; ++ct) {
        int col = wc * 64 + ct * 16 + m15;
        float bz = bias[col];
        float s = 0.f, q = 0.f;
#pragma unroll
        for (int rt = 0; rt < 2; ++rt) {
#pragma unroll
            for (int reg = 0; reg < 4; ++reg) {
                int row = r0 + wr * 32 + rt * 16 + quad * 4 + reg;
                float vv = fmaxf(acc[rt][ct][reg] + bz, 0.f);
                if (row < N) {
                    if constexpr (OUT_BF16)
                        ((unsigned short*)Yv)[(size_t)row * 128 + col] = f2bf(vv);
                    else
                        ((float*)Yv)[(size_t)row * 128 + col] = vv;
                } else {
                    vv = 0.f;
                }
                s += vv; q = fmaf(vv, vv, q);
            }
        }
        s += __shfl_xor(s, 16, 64); s += __shfl_xor(s, 32, 64);
        q += __shfl_xor(q, 16, 64); q += __shfl_xor(q, 32, 64);
        if (quad == 0) {
            atomicAdd(&bsum_s[col], s);
            atomicAdd(&bsq_s[col], q);
        }
    }
    __syncthreads();
    if (tid < 128) {
        const int slot = (bid & (NSLOT - 1)) * 128;
        atomicAdd(&sum[slot + tid],   (double)bsum_s[tid]);
        atomicAdd(&sumsq[slot + tid], (double)bsq_s[tid]);
    }
}

// ---------------------------------------------------------------------------
// bn coef body: reduce 32 slots -> bn affine coefs. t in [0,128).
static __device__ __forceinline__ void bn_coef_body(
    int t, const double* __restrict__ sum, const double* __restrict__ sumsq,
    const float* __restrict__ gamma, const float* __restrict__ beta,
    float* __restrict__ a, float* __restrict__ b, double invN)
{
    double ms = 0.0, qs = 0.0;
#pragma unroll
    for (int s = 0; s < NSLOT; ++s) {
        ms += sum[s * 128 + t];
        qs += sumsq[s * 128 + t];
    }
    float mean = (float)(ms * invN);
    float var  = (float)(qs * invN) - mean * mean;
    float sc = rsqrtf(var + BN_EPS) * gamma[t];
    a[t] = sc;
    b[t] = fmaf(-mean, sc, beta[t]);
}

__global__ __launch_bounds__(128) void bn_coef(
    const double* __restrict__ sum, const double* __restrict__ sumsq,
    const float* __restrict__ gamma, const float* __restrict__ beta,
    float* __restrict__ a, float* __restrict__ b, double invN)
{
    bn_coef_body(threadIdx.x, sum, sumsq, gamma, beta, a, b, invN);
}

// ---------------------------------------------------------------------------
// bin body: bin edges into coarse buckets of 512 dsts (int4 records).
// Bucket bases come from a redundant in-block scan of ccnt; the running
// cursor is zero-based gofs[128].
static __device__ __forceinline__ void bin_body(
    int bid,
    const int* __restrict__ src, const int* __restrict__ dst,
    const float* __restrict__ w,
    const int* __restrict__ ccnt, int* __restrict__ gofs,
    int4* __restrict__ tmp, int E)
{
    __shared__ int hcnt[128];
    __shared__ int hbase[128];
    __shared__ int w0s;
    const int tid = threadIdx.x;
    if (tid < 128) hcnt[tid] = 0;
    __syncthreads();

    int d8[8], s8[8], slot8[8];
    float w8[8];
#pragma unroll
    for (int j = 0; j < 8; ++j) {
        int e = bid * 2048 + j * 256 + tid;
        if (e < E) {
            d8[j] = dst[e]; s8[j] = src[e]; w8[j] = w[e];
            slot8[j] = atomicAdd(&hcnt[d8[j] >> 9], 1);
        } else d8[j] = -1;
    }
    __syncthreads();
    int excl, vcnt;
    scan_ccnt(ccnt, &excl, &vcnt, &w0s);
    if (tid < 128 && hcnt[tid] > 0)
        hbase[tid] = excl + atomicAdd(&gofs[tid], hcnt[tid]);
    __syncthreads();
#pragma unroll
    for (int j = 0; j < 8; ++j) {
        if (d8[j] >= 0) {
            int pos = hbase[d8[j] >> 9] + slot8[j];
            tmp[pos] = make_int4(s8[j], __float_as_int(w8[j]), d8[j], 0);
        }
    }
}

// fatB: blocks [0,HB) bin edges; blocks [HB,HB+GB) run gemm1 -> y1b bf16.
__global__ __launch_bounds__(256) void k_bin_gemm(
    const int* __restrict__ src, const int* __restrict__ dst,
    const float* __restrict__ w,
    const int* __restrict__ ccnt, int* __restrict__ gofs,
    int4* __restrict__ tmp, int E, int HB,
    const unsigned short* __restrict__ featb,
    const unsigned short* __restrict__ Qwb, const float* __restrict__ Qb,
    unsigned short* __restrict__ y1b,
    double* __restrict__ sum, double* __restrict__ sumsq, int N)
{
    if ((int)blockIdx.x < HB)
        bin_body(blockIdx.x, src, dst, w, ccnt, gofs, tmp, E);
    else
        gemm_body<128, true>(blockIdx.x - HB, featb, featb, Qwb, Qb, y1b,
                             sum, sumsq, N);
}

// ---------------------------------------------------------------------------
// refine body: per bucket — bases from redundant ccnt scan; count per-dst in
// LDS, scan (+bucket base), write offs slice, scatter to epack in dst order.
static __device__ __forceinline__ void refine_body(
    int b,
    const int4* __restrict__ tmp, const int* __restrict__ ccnt,
    int* __restrict__ offs, int2* __restrict__ epack, int N)
{
    __shared__ int hist[512];
    __shared__ int wpre[4];
    __shared__ int w0s;
    __shared__ int sbounds[2];
    const int d0   = b << 9;
    const int dlim = min(512, N - d0);
    const int tid  = threadIdx.x;
    const int lane = tid & 63, wv = tid >> 6;

    hist[tid] = 0; hist[tid + 256] = 0;
    __syncthreads();
    int excl, vcnt;
    scan_ccnt(ccnt, &excl, &vcnt, &w0s);
    if (tid == b) { sbounds[0] = excl; sbounds[1] = excl + vcnt; }
    __syncthreads();
    const int start = sbounds[0];
    const int end   = sbounds[1];

    for (int p = start + tid; p < end; p += 256)
        atomicAdd(&hist[tmp[p].z - d0], 1);
    __syncthreads();

    int v0 = hist[2 * tid], v1 = hist[2 * tid + 1];
    int s = v0 + v1;
    int incl = s;
#pragma unroll
    for (int o = 1; o < 64; o <<= 1) {
        int t = __shfl_up(incl, o, 64);
        if (lane >= o) incl += t;
    }
    if (lane == 63) wpre[wv] = incl;
    __syncthreads();
    if (tid == 0) {
        int r = 0;
#pragma unroll
        for (int i = 0; i < 4; ++i) { int t = wpre[i]; wpre[i] = r; r += t; }
    }
    __syncthreads();
    int e0 = start + wpre[wv] + incl - s;
    if (2 * tid < dlim)     offs[d0 + 2 * tid]     = e0;
    if (2 * tid + 1 < dlim) offs[d0 + 2 * tid + 1] = e0 + v0;
    hist[2 * tid]     = e0;
    hist[2 * tid + 1] = e0 + v0;
    __syncthreads();

    for (int p = start + tid; p < end; p += 256) {
        int4 rec = tmp[p];
        int pos = atomicAdd(&hist[rec.z - d0], 1);
        epack[pos] = make_int2(rec.x, rec.y);
    }
}

// fat: block 0 = bn_coef1 reduce; blocks [1,NB] = refine buckets.
__global__ __launch_bounds__(256) void k_bnref(
    const double* __restrict__ sum, const double* __restrict__ sumsq,
    const float* __restrict__ gamma, const float* __restrict__ beta,
    float* __restrict__ a, float* __restrict__ b, double invN,
    const int4* __restrict__ tmp, const int* __restrict__ ccnt,
    int* __restrict__ offs, int2* __restrict__ epack, int N)
{
    if (blockIdx.x == 0) {
        if (threadIdx.x < 128)
            bn_coef_body(threadIdx.x, sum, sumsq, gamma, beta, a, b, invN);
        return;
    }
    refine_body((int)blockIdx.x - 1, tmp, ccnt, offs, epack, N);
}

// ---------------------------------------------------------------------------
// One wave per dst row, 8 edges in flight (32-lane halves x 4 pair-groups,
// 4 cols/lane). Reads raw relu y1b; applies bn affine (a,b) to the weighted
// mean (or own row when den==0). Writes agg bf16.
__global__ __launch_bounds__(256) void gather_agg(
    const unsigned short* __restrict__ y1b,
    const int* __restrict__ offs, const int2* __restrict__ epack,
    const float* __restrict__ a, const float* __restrict__ b,
    unsigned short* __restrict__ aggb, int N)
{
    const int r    = (int)((blockIdx.x * 256u + threadIdx.x) >> 6);
    const int lane = threadIdx.x & 63;
    const int li   = lane & 31;     // owns columns 4*li .. 4*li+3
    const int hf   = lane >> 5;     // 0: even edge of pair, 1: odd
    if (r >= N) return;
    int p = offs[r];
    const int end = offs[r + 1];
    const int c = 4 * li;
    float ac0 = 0.f, ac1 = 0.f, ac2 = 0.f, ac3 = 0.f, den = 0.f;
    for (; p + 7 < end; p += 8) {
        int2 e0 = epack[p + hf];
        int2 e1 = epack[p + 2 + hf];
        int2 e2 = epack[p + 4 + hf];
        int2 e3 = epack[p + 6 + hf];
        uint2 u0 = *(const uint2*)(y1b + (size_t)e0.x * 128 + c);
        uint2 u1 = *(const uint2*)(y1b + (size_t)e1.x * 128 + c);
        uint2 u2 = *(const uint2*)(y1b + (size_t)e2.x * 128 + c);
        uint2 u3 = *(const uint2*)(y1b + (size_t)e3.x * 128 + c);
        float w0 = __int_as_float(e0.y), w1 = __int_as_float(e1.y);
        float w2 = __int_as_float(e2.y), w3 = __int_as_float(e3.y);
        ac0 = fmaf(w0, bf_lo(u0.x), ac0); ac1 = fmaf(w0, bf_hi(u0.x), ac1);
        ac2 = fmaf(w0, bf_lo(u0.y), ac2); ac3 = fmaf(w0, bf_hi(u0.y), ac3);
        ac0 = fmaf(w1, bf_lo(u1.x), ac0); ac1 = fmaf(w1, bf_hi(u1.x), ac1);
        ac2 = fmaf(w1, bf_lo(u1.y), ac2); ac3 = fmaf(w1, bf_hi(u1.y), ac3);
        ac0 = fmaf(w2, bf_lo(u2.x), ac0); ac1 = fmaf(w2, bf_hi(u2.x), ac1);
        ac2 = fmaf(w2, bf_lo(u2.y), ac2); ac3 = fmaf(w2, bf_hi(u2.y), ac3);
        ac0 = fmaf(w3, bf_lo(u3.x), ac0); ac1 = fmaf(w3, bf_hi(u3.x), ac1);
        ac2 = fmaf(w3, bf_lo(u3.y), ac2); ac3 = fmaf(w3, bf_hi(u3.y), ac3);
        den += (w0 + w1) + (w2 + w3);
    }
    for (; p + 3 < end; p += 4) {
        int2 ea = epack[p + hf];
        int2 eb = epack[p + 2 + hf];
        uint2 ua = *(const uint2*)(y1b + (size_t)ea.x * 128 + c);
        uint2 ub = *(const uint2*)(y1b + (size_t)eb.x * 128 + c);
        float wa = __int_as_float(ea.y), wb = __int_as_float(eb.y);
        ac0 = fmaf(wa, bf_lo(ua.x), ac0); ac1 = fmaf(wa, bf_hi(ua.x), ac1);
        ac2 = fmaf(wa, bf_lo(ua.y), ac2); ac3 = fmaf(wa, bf_hi(ua.y), ac3);
        ac0 = fmaf(wb, bf_lo(ub.x), ac0); ac1 = fmaf(wb, bf_hi(ub.x), ac1);
        ac2 = fmaf(wb, bf_lo(ub.y), ac2); ac3 = fmaf(wb, bf_hi(ub.y), ac3);
        den += wa + wb;
    }
    for (; p + 1 < end; p += 2) {
        int2 ea = epack[p + hf];
        uint2 ua = *(const uint2*)(y1b + (size_t)ea.x * 128 + c);
        float wa = __int_as_float(ea.y);
        ac0 = fmaf(wa, bf_lo(ua.x), ac0); ac1 = fmaf(wa, bf_hi(ua.x), ac1);
        ac2 = fmaf(wa, bf_lo(ua.y), ac2); ac3 = fmaf(wa, bf_hi(ua.y), ac3);
        den += wa;
    }
    if (p < end && hf == 0) {   // odd tail edge: half 0 only
        int2 ea = epack[p];
        uint2 ua = *(const uint2*)(y1b + (size_t)ea.x * 128 + c);
        float wa = __int_as_float(ea.y);
        ac0 = fmaf(wa, bf_lo(ua.x), ac0); ac1 = fmaf(wa, bf_hi(ua.x), ac1);
        ac2 = fmaf(wa, bf_lo(ua.y), ac2); ac3 = fmaf(wa, bf_hi(ua.y), ac3);
        den += wa;
    }
    ac0 += __shfl_xor(ac0, 32, 64);
    ac1 += __shfl_xor(ac1, 32, 64);
    ac2 += __shfl_xor(ac2, 32, 64);
    ac3 += __shfl_xor(ac3, 32, 64);
    den += __shfl_xor(den, 32, 64);
    if (hf) return;
    float4 av = *(const float4*)(a + c);
    float4 bv = *(const float4*)(b + c);
    float m0, m1, m2, m3;
    if (den != 0.f) {
        float inv = 1.f / den;
        m0 = ac0 * inv; m1 = ac1 * inv; m2 = ac2 * inv; m3 = ac3 * inv;
    } else {
        uint2 u = *(const uint2*)(y1b + (size_t)r * 128 + c);
        m0 = bf_lo(u.x); m1 = bf_hi(u.x); m2 = bf_lo(u.y); m3 = bf_hi(u.y);
    }
    ushort4 o;
    o.x = f2bf(fmaf(av.x, m0, bv.x));
    o.y = f2bf(fmaf(av.y, m1, bv.y));
    o.z = f2bf(fmaf(av.z, m2, bv.z));
    o.w = f2bf(fmaf(av.w, m3, bv.w));
    *(ushort4*)(aggb + (size_t)r * 128 + c) = o;
}

// ---------------------------------------------------------------------------
// gemm2 standalone (K=256, A = [featb|aggb]) -> y2 f32 + stats2.
__global__ __launch_bounds__(256) void gemm_bn2(
    const unsigned short* __restrict__ A_lo,
    const unsigned short* __restrict__ A_hi,
    const unsigned short* __restrict__ Bb,
    const float* __restrict__ bias,
    float* __restrict__ Y,
    double* __restrict__ sum, double* __restrict__ sumsq, int N)
{
    gemm_body<256, false>(blockIdx.x, A_lo, A_hi, Bb, bias, Y, sum, sumsq, N);
}

// ---------------------------------------------------------------------------
// bn2 affine (precomputed coefs) + row L2 normalize.
__global__ __launch_bounds__(256) void finalize(
    const float* __restrict__ Y2,
    const float* __restrict__ a, const float* __restrict__ b,
    float* __restrict__ out, int N)
{
    __shared__ float sa[128], sb[128];
    const int t = threadIdx.x;
    if (t < 128) { sa[t] = a[t]; sb[t] = b[t]; }
    __syncthreads();
    const int row  = (int)((blockIdx.x * 256u + t) >> 6);
    const int lane = t & 63;
    if (row >= N) return;
    const size_t base = (size_t)row * 128;
    float v0 = fmaf(sa[lane],      Y2[base + lane],      sb[lane]);
    float v1 = fmaf(sa[lane + 64], Y2[base + lane + 64], sb[lane + 64]);
    float ss = fmaf(v0, v0, v1 * v1);
#pragma unroll
    for (int o = 32; o; o >>= 1) ss += __shfl_xor(ss, o, 64);
    float nrm = sqrtf(ss);
    float inv = (nrm == 0.f) ? 1.f : 1.f / nrm;
    out[base + lane]      = v0 * inv;
    out[base + lane + 64] = v1 * inv;
}

// ---------------------------------------------------------------------------
extern "C" void kernel_launch(void* const* d_in, const int* in_sizes, int n_in,
                              void* d_out, int out_size, void* d_ws, size_t ws_size,
                              hipStream_t stream)
{
    const float* feat   = (const float*)d_in[0];
    const float* w      = (const float*)d_in[1];
    const float* Q_w    = (const float*)d_in[2];
    const float* Q_b    = (const float*)d_in[3];
    const float* W_w    = (const float*)d_in[4];
    const float* W_b    = (const float*)d_in[5];
    const float* gamma2 = (const float*)d_in[6];
    const float* beta2  = (const float*)d_in[7];
    const int*   src    = (const int*)d_in[8];
    const int*   dst    = (const int*)d_in[9];

    const int N = in_sizes[0] / 128;   // 50000
    const int E = in_sizes[1];         // 800000

    // workspace layout
    float*          y2    = (float*)d_ws;                            // N*128 f32
    unsigned short* featb = (unsigned short*)(y2 + (size_t)N * 128); // N*128 bf16
    unsigned short* aggb  = featb + (size_t)N * 128;                 // N*128 bf16
    unsigned short* y1b   = aggb + (size_t)N * 128;                  // N*128 bf16
    int4*  tmp    = (int4*)(y1b + (size_t)N * 128);                  // E (16B aligned)
    int2*  epack  = (int2*)(tmp + E);                                // E
    int*   offs   = (int*)(epack + E);                               // N+1
    float* coefs  = (float*)(offs + N + 1);                          // 512
    float* a1 = coefs, *b1 = coefs + 128, *a2 = coefs + 256, *b2 = coefs + 384;
    uintptr_t qp = ((uintptr_t)(coefs + 512) + 15) & ~(uintptr_t)15;
    unsigned short* Qwb = (unsigned short*)qp;                       // 128*128 bf16
    unsigned short* Wwb = Qwb + 128 * 128;                           // 128*256 bf16
    uintptr_t sp = ((uintptr_t)(Wwb + 128 * 256) + 15) & ~(uintptr_t)15;
    double* stats = (double*)sp;                                     // 4*NSLOT*128 <- zeroed
    double* sum1   = stats;
    double* sumsq1 = stats + NSLOT * 128;
    double* sum2   = stats + 2 * NSLOT * 128;
    double* sumsq2 = stats + 3 * NSLOT * 128;
    int*   ccnt   = (int*)(stats + 4 * NSLOT * 128);                 // 128 <- zeroed
    int*   gofs   = ccnt + 128;                                      // 128 <- zeroed

    hipMemsetAsync(stats, 0,
                   4 * NSLOT * 128 * sizeof(double) + 256 * sizeof(int),
                   stream);

    const double invN = 1.0 / (double)N;
    const int GB = (N + 63) / 64;               // gemm blocks (782)
    const int NB = (N + 511) >> 9;              // coarse buckets (98)
    const int CB = (N * 128 / 4 + 255) / 256;   // feat cast blocks
    const int HB = (E + 2047) / 2048;           // histogram/bin blocks
    const int QB = 16;                          // Q_w cast blocks
    const int WB = 32;                          // W_w cast blocks

    k_pre<<<CB + HB + QB + WB, 256, 0, stream>>>(
        feat, featb, N * 128, dst, ccnt, E, CB, HB,
        Q_w, Qwb, W_w, Wwb, offs, N);

    // fatB: bin || gemm1 -> y1b bf16 + stats1 (bases via in-block ccnt scan)
    k_bin_gemm<<<HB + GB, 256, 0, stream>>>(
        src, dst, w, ccnt, gofs, tmp, E, HB,
        featb, Qwb, Q_b, y1b, sum1, sumsq1, N);

    // fat: bn_coef1 (block 0) || refine (blocks 1..NB)
    k_bnref<<<NB + 1, 256, 0, stream>>>(
        sum1, sumsq1, gamma2, beta2, a1, b1, invN,
        tmp, ccnt, offs, epack, N);

    gather_agg<<<(N * 64 + 255) / 256, 256, 0, stream>>>(
        y1b, offs, epack, a1, b1, aggb, N);

    gemm_bn2<<<GB, 256, 0, stream>>>(
        featb, aggb, Wwb, W_b, y2, sum2, sumsq2, N);

    bn_coef<<<1, 128, 0, stream>>>(sum2, sumsq2, gamma2, beta2, a2, b2, invN);
    finalize<<<(N * 64 + 255) / 256, 256, 0, stream>>>(
        y2, a2, b2, (float*)d_out, N);
}

// Round 8
// 223.449 us; speedup vs baseline: 1.3453x; 1.0106x over previous
//
#include <hip/hip_runtime.h>
#include <stdint.h>

// PinConv pipeline, round 18 (base = round 17, 225.8us best):
//  - gemm_bn2 (standalone) tile 64x128 -> 128x128: halves block count,
//    doubles MFMA per staging barrier, halves B-staging traffic. Round-6's
//    128^2 regression was the FAT kernel (bin branch paid the LDS tax) +
//    bundled finalize change; gemm_bn2 has no co-resident branch.
//  - gemm1 inside fatB stays 64x128 (protects bin-branch occupancy).
//  - everything else identical to round 17.

#define BN_EPS 1e-5f
#define NSLOT 32

typedef __attribute__((ext_vector_type(8))) short bf16x8;
typedef __attribute__((ext_vector_type(4))) float f32x4;

static __device__ __forceinline__ unsigned short f2bf(float f) {
    uint32_t u = __builtin_bit_cast(uint32_t, f);
    u += 0x7fffu + ((u >> 16) & 1u);          // round-to-nearest-even
    return (unsigned short)(u >> 16);
}
static __device__ __forceinline__ float bf_lo(uint32_t u) {
    return __builtin_bit_cast(float, u << 16);
}
static __device__ __forceinline__ float bf_hi(uint32_t u) {
    return __builtin_bit_cast(float, u & 0xffff0000u);
}

static __device__ __forceinline__ void cast_blk(
    const float* __restrict__ src, unsigned short* __restrict__ dst,
    int n, int blk)
{
    int i = (blk * 256 + threadIdx.x) * 4;
    if (i + 3 < n) {
        float4 v = *(const float4*)(src + i);
        ushort4 o;
        o.x = f2bf(v.x); o.y = f2bf(v.y); o.z = f2bf(v.z); o.w = f2bf(v.w);
        *(ushort4*)(dst + i) = o;
    } else {
        for (int j = i; j < n; ++j) dst[j] = f2bf(src[j]);
    }
}

// Redundant per-block exclusive scan of ccnt[128].
static __device__ __forceinline__ void scan_ccnt(
    const int* __restrict__ ccnt, int* excl_out, int* v_out, int* w0s)
{
    const int t = threadIdx.x;
    int v = 0, incl = 0;
    if (t < 128) {
        v = ccnt[t];
        incl = v;
        const int lane = t & 63;
#pragma unroll
        for (int o = 1; o < 64; o <<= 1) {
            int u = __shfl_up(incl, o, 64);
            if (lane >= o) incl += u;
        }
        if (t == 63) *w0s = incl;
    }
    __syncthreads();
    int excl = 0;
    if (t < 128) excl = incl - v + ((t >> 6) ? *w0s : 0);
    *excl_out = excl;
    *v_out = v;
}

// ---------------------------------------------------------------------------
// Fused: blocks [0,CB) cast feat; [CB,CB+HB) coarse-histogram dst into
// 512-wide buckets; [CB+HB,..) cast Q_w / W_w to bf16. No fences.
__global__ __launch_bounds__(256) void k_pre(
    const float* __restrict__ feat, unsigned short* __restrict__ featb, int nf,
    const int* __restrict__ dst, int* __restrict__ ccnt, int E, int CB, int HB,
    const float* __restrict__ Qw, unsigned short* __restrict__ Qwb,
    const float* __restrict__ Ww, unsigned short* __restrict__ Wwb,
    int* __restrict__ offs, int N)
{
    int b = (int)blockIdx.x;
    if (b < CB) {
        if (b == 0 && threadIdx.x == 0) offs[N] = E;
        cast_blk(feat, featb, nf, b);
        return;
    }
    b -= CB;
    if (b >= HB) {
        b -= HB;
        if (b < 16) cast_blk(Qw, Qwb, 128 * 128, b);
        else        cast_blk(Ww, Wwb, 128 * 256, b - 16);
        return;
    }
    __shared__ int hcnt[128];
    const int tid = threadIdx.x;
    if (tid < 128) hcnt[tid] = 0;
    __syncthreads();
    const int base_e = b * 2048;
#pragma unroll
    for (int j = 0; j < 8; ++j) {
        int e = base_e + j * 256 + tid;
        if (e < E) atomicAdd(&hcnt[dst[e] >> 9], 1);
    }
    __syncthreads();
    if (tid < 128 && hcnt[tid] > 0) atomicAdd(&ccnt[tid], hcnt[tid]);
}

// ---------------------------------------------------------------------------
// GEMM body (LDS-staged, 64x128 tile): used by gemm1 inside fatB.
template<int K, bool OUT_BF16>
static __device__ __forceinline__ void gemm_body(
    int bid,
    const unsigned short* __restrict__ A_lo,
    const unsigned short* __restrict__ A_hi,
    const unsigned short* __restrict__ Bb,
    const float* __restrict__ bias,
    void* __restrict__ Yv,
    double* __restrict__ sum, double* __restrict__ sumsq, int N)
{
    constexpr int SA = 72;
    __shared__ unsigned short As[64 * SA];
    __shared__ unsigned short Bs[128 * SA];
    __shared__ float bsum_s[128], bsq_s[128];

    const int tid  = threadIdx.x;
    const int lane = tid & 63;
    const int wv   = tid >> 6;
    const int wr   = wv >> 1;
    const int wc   = wv & 1;
    const int m15  = lane & 15;
    const int quad = lane >> 4;
    const int r0   = bid * 64;

    if (tid < 128) { bsum_s[tid] = 0.f; bsq_s[tid] = 0.f; }

    f32x4 acc[2][4];
#pragma unroll
    for (int rt = 0; rt < 2; ++rt)
#pragma unroll
        for (int ct = 0; ct < 4; ++ct)
            acc[rt][ct] = (f32x4){0.f, 0.f, 0.f, 0.f};

    for (int kc = 0; kc < K; kc += 64) {
        const unsigned short* Ap = (kc < 128) ? A_lo : A_hi;
        const int koff = kc & 127;
#pragma unroll
        for (int i = 0; i < 2; ++i) {
            int idx = i * 256 + tid;
            int row = idx >> 3, seg = idx & 7;
            int gr  = r0 + row; if (gr >= N) gr = N - 1;
            uint4 v = *(const uint4*)(Ap + (size_t)gr * 128 + koff + seg * 8);
            *(uint4*)(As + row * SA + seg * 8) = v;
        }
#pragma unroll
        for (int i = 0; i < 4; ++i) {
            int idx = i * 256 + tid;
            int row = idx >> 3, seg = idx & 7;
            uint4 v = *(const uint4*)(Bb + (size_t)row * K + kc + seg * 8);
            *(uint4*)(Bs + row * SA + seg * 8) = v;
        }
        __syncthreads();

#pragma unroll
        for (int ks = 0; ks < 64; ks += 32) {
            bf16x8 af[2], bfr[4];
#pragma unroll
            for (int rt = 0; rt < 2; ++rt)
                af[rt] = *(const bf16x8*)(As + (wr * 32 + rt * 16 + m15) * SA + ks + quad * 8);
#pragma unroll
            for (int ct = 0; ct < 4; ++ct)
                bfr[ct] = *(const bf16x8*)(Bs + (wc * 64 + ct * 16 + m15) * SA + ks + quad * 8);
#pragma unroll
            for (int rt = 0; rt < 2; ++rt)
#pragma unroll
                for (int ct = 0; ct < 4; ++ct)
                    acc[rt][ct] = __builtin_amdgcn_mfma_f32_16x16x32_bf16(
                        af[rt], bfr[ct], acc[rt][ct], 0, 0, 0);
        }
        __syncthreads();
    }

#pragma unroll
    for (int ct = 0; ct < 4; ++ct) {
        int col = wc * 64 + ct * 16 + m15;
        float bz = bias[col];
        float s = 0.f, q = 0.f;
#pragma unroll
        for (int rt = 0; rt < 2; ++rt) {
#pragma unroll
            for (int reg = 0; reg < 4; ++reg) {
                int row = r0 + wr * 32 + rt * 16 + quad * 4 + reg;
                float vv = fmaxf(acc[rt][ct][reg] + bz, 0.f);
                if (row < N) {
                    if constexpr (OUT_BF16)
                        ((unsigned short*)Yv)[(size_t)row * 128 + col] = f2bf(vv);
                    else
                        ((float*)Yv)[(size_t)row * 128 + col] = vv;
                } else {
                    vv = 0.f;
                }
                s += vv; q = fmaf(vv, vv, q);
            }
        }
        s += __shfl_xor(s, 16, 64); s += __shfl_xor(s, 32, 64);
        q += __shfl_xor(q, 16, 64); q += __shfl_xor(q, 32, 64);
        if (quad == 0) {
            atomicAdd(&bsum_s[col], s);
            atomicAdd(&bsq_s[col], q);
        }
    }
    __syncthreads();
    if (tid < 128) {
        const int slot = (bid & (NSLOT - 1)) * 128;
        atomicAdd(&sum[slot + tid],   (double)bsum_s[tid]);
        atomicAdd(&sumsq[slot + tid], (double)bsq_s[tid]);
    }
}

// ---------------------------------------------------------------------------
// bn coef body: reduce 32 slots -> bn affine coefs. t in [0,128).
static __device__ __forceinline__ void bn_coef_body(
    int t, const double* __restrict__ sum, const double* __restrict__ sumsq,
    const float* __restrict__ gamma, const float* __restrict__ beta,
    float* __restrict__ a, float* __restrict__ b, double invN)
{
    double ms = 0.0, qs = 0.0;
#pragma unroll
    for (int s = 0; s < NSLOT; ++s) {
        ms += sum[s * 128 + t];
        qs += sumsq[s * 128 + t];
    }
    float mean = (float)(ms * invN);
    float var  = (float)(qs * invN) - mean * mean;
    float sc = rsqrtf(var + BN_EPS) * gamma[t];
    a[t] = sc;
    b[t] = fmaf(-mean, sc, beta[t]);
}

__global__ __launch_bounds__(128) void bn_coef(
    const double* __restrict__ sum, const double* __restrict__ sumsq,
    const float* __restrict__ gamma, const float* __restrict__ beta,
    float* __restrict__ a, float* __restrict__ b, double invN)
{
    bn_coef_body(threadIdx.x, sum, sumsq, gamma, beta, a, b, invN);
}

// ---------------------------------------------------------------------------
// bin body: bin edges into coarse buckets of 512 dsts (int4 records).
static __device__ __forceinline__ void bin_body(
    int bid,
    const int* __restrict__ src, const int* __restrict__ dst,
    const float* __restrict__ w,
    const int* __restrict__ ccnt, int* __restrict__ gofs,
    int4* __restrict__ tmp, int E)
{
    __shared__ int hcnt[128];
    __shared__ int hbase[128];
    __shared__ int w0s;
    const int tid = threadIdx.x;
    if (tid < 128) hcnt[tid] = 0;
    __syncthreads();

    int d8[8], s8[8], slot8[8];
    float w8[8];
#pragma unroll
    for (int j = 0; j < 8; ++j) {
        int e = bid * 2048 + j * 256 + tid;
        if (e < E) {
            d8[j] = dst[e]; s8[j] = src[e]; w8[j] = w[e];
            slot8[j] = atomicAdd(&hcnt[d8[j] >> 9], 1);
        } else d8[j] = -1;
    }
    __syncthreads();
    int excl, vcnt;
    scan_ccnt(ccnt, &excl, &vcnt, &w0s);
    if (tid < 128 && hcnt[tid] > 0)
        hbase[tid] = excl + atomicAdd(&gofs[tid], hcnt[tid]);
    __syncthreads();
#pragma unroll
    for (int j = 0; j < 8; ++j) {
        if (d8[j] >= 0) {
            int pos = hbase[d8[j] >> 9] + slot8[j];
            tmp[pos] = make_int4(s8[j], __float_as_int(w8[j]), d8[j], 0);
        }
    }
}

// fatB: blocks [0,HB) bin edges; blocks [HB,HB+GB) run gemm1 -> y1b bf16.
__global__ __launch_bounds__(256) void k_bin_gemm(
    const int* __restrict__ src, const int* __restrict__ dst,
    const float* __restrict__ w,
    const int* __restrict__ ccnt, int* __restrict__ gofs,
    int4* __restrict__ tmp, int E, int HB,
    const unsigned short* __restrict__ featb,
    const unsigned short* __restrict__ Qwb, const float* __restrict__ Qb,
    unsigned short* __restrict__ y1b,
    double* __restrict__ sum, double* __restrict__ sumsq, int N)
{
    if ((int)blockIdx.x < HB)
        bin_body(blockIdx.x, src, dst, w, ccnt, gofs, tmp, E);
    else
        gemm_body<128, true>(blockIdx.x - HB, featb, featb, Qwb, Qb, y1b,
                             sum, sumsq, N);
}

// ---------------------------------------------------------------------------
// refine body: per bucket — bases from redundant ccnt scan; count per-dst in
// LDS, scan (+bucket base), write offs slice, scatter to epack in dst order.
static __device__ __forceinline__ void refine_body(
    int b,
    const int4* __restrict__ tmp, const int* __restrict__ ccnt,
    int* __restrict__ offs, int2* __restrict__ epack, int N)
{
    __shared__ int hist[512];
    __shared__ int wpre[4];
    __shared__ int w0s;
    __shared__ int sbounds[2];
    const int d0   = b << 9;
    const int dlim = min(512, N - d0);
    const int tid  = threadIdx.x;
    const int lane = tid & 63, wv = tid >> 6;

    hist[tid] = 0; hist[tid + 256] = 0;
    __syncthreads();
    int excl, vcnt;
    scan_ccnt(ccnt, &excl, &vcnt, &w0s);
    if (tid == b) { sbounds[0] = excl; sbounds[1] = excl + vcnt; }
    __syncthreads();
    const int start = sbounds[0];
    const int end   = sbounds[1];

    for (int p = start + tid; p < end; p += 256)
        atomicAdd(&hist[tmp[p].z - d0], 1);
    __syncthreads();

    int v0 = hist[2 * tid], v1 = hist[2 * tid + 1];
    int s = v0 + v1;
    int incl = s;
#pragma unroll
    for (int o = 1; o < 64; o <<= 1) {
        int t = __shfl_up(incl, o, 64);
        if (lane >= o) incl += t;
    }
    if (lane == 63) wpre[wv] = incl;
    __syncthreads();
    if (tid == 0) {
        int r = 0;
#pragma unroll
        for (int i = 0; i < 4; ++i) { int t = wpre[i]; wpre[i] = r; r += t; }
    }
    __syncthreads();
    int e0 = start + wpre[wv] + incl - s;
    if (2 * tid < dlim)     offs[d0 + 2 * tid]     = e0;
    if (2 * tid + 1 < dlim) offs[d0 + 2 * tid + 1] = e0 + v0;
    hist[2 * tid]     = e0;
    hist[2 * tid + 1] = e0 + v0;
    __syncthreads();

    for (int p = start + tid; p < end; p += 256) {
        int4 rec = tmp[p];
        int pos = atomicAdd(&hist[rec.z - d0], 1);
        epack[pos] = make_int2(rec.x, rec.y);
    }
}

// fat: block 0 = bn_coef1 reduce; blocks [1,NB] = refine buckets.
__global__ __launch_bounds__(256) void k_bnref(
    const double* __restrict__ sum, const double* __restrict__ sumsq,
    const float* __restrict__ gamma, const float* __restrict__ beta,
    float* __restrict__ a, float* __restrict__ b, double invN,
    const int4* __restrict__ tmp, const int* __restrict__ ccnt,
    int* __restrict__ offs, int2* __restrict__ epack, int N)
{
    if (blockIdx.x == 0) {
        if (threadIdx.x < 128)
            bn_coef_body(threadIdx.x, sum, sumsq, gamma, beta, a, b, invN);
        return;
    }
    refine_body((int)blockIdx.x - 1, tmp, ccnt, offs, epack, N);
}

// ---------------------------------------------------------------------------
// One wave per dst row, 8 edges in flight (32-lane halves x 4 pair-groups,
// 4 cols/lane). Reads raw relu y1b; applies bn affine (a,b) to the weighted
// mean (or own row when den==0). Writes agg bf16.
__global__ __launch_bounds__(256) void gather_agg(
    const unsigned short* __restrict__ y1b,
    const int* __restrict__ offs, const int2* __restrict__ epack,
    const float* __restrict__ a, const float* __restrict__ b,
    unsigned short* __restrict__ aggb, int N)
{
    const int r    = (int)((blockIdx.x * 256u + threadIdx.x) >> 6);
    const int lane = threadIdx.x & 63;
    const int li   = lane & 31;     // owns columns 4*li .. 4*li+3
    const int hf   = lane >> 5;     // 0: even edge of pair, 1: odd
    if (r >= N) return;
    int p = offs[r];
    const int end = offs[r + 1];
    const int c = 4 * li;
    float ac0 = 0.f, ac1 = 0.f, ac2 = 0.f, ac3 = 0.f, den = 0.f;
    for (; p + 7 < end; p += 8) {
        int2 e0 = epack[p + hf];
        int2 e1 = epack[p + 2 + hf];
        int2 e2 = epack[p + 4 + hf];
        int2 e3 = epack[p + 6 + hf];
        uint2 u0 = *(const uint2*)(y1b + (size_t)e0.x * 128 + c);
        uint2 u1 = *(const uint2*)(y1b + (size_t)e1.x * 128 + c);
        uint2 u2 = *(const uint2*)(y1b + (size_t)e2.x * 128 + c);
        uint2 u3 = *(const uint2*)(y1b + (size_t)e3.x * 128 + c);
        float w0 = __int_as_float(e0.y), w1 = __int_as_float(e1.y);
        float w2 = __int_as_float(e2.y), w3 = __int_as_float(e3.y);
        ac0 = fmaf(w0, bf_lo(u0.x), ac0); ac1 = fmaf(w0, bf_hi(u0.x), ac1);
        ac2 = fmaf(w0, bf_lo(u0.y), ac2); ac3 = fmaf(w0, bf_hi(u0.y), ac3);
        ac0 = fmaf(w1, bf_lo(u1.x), ac0); ac1 = fmaf(w1, bf_hi(u1.x), ac1);
        ac2 = fmaf(w1, bf_lo(u1.y), ac2); ac3 = fmaf(w1, bf_hi(u1.y), ac3);
        ac0 = fmaf(w2, bf_lo(u2.x), ac0); ac1 = fmaf(w2, bf_hi(u2.x), ac1);
        ac2 = fmaf(w2, bf_lo(u2.y), ac2); ac3 = fmaf(w2, bf_hi(u2.y), ac3);
        ac0 = fmaf(w3, bf_lo(u3.x), ac0); ac1 = fmaf(w3, bf_hi(u3.x), ac1);
        ac2 = fmaf(w3, bf_lo(u3.y), ac2); ac3 = fmaf(w3, bf_hi(u3.y), ac3);
        den += (w0 + w1) + (w2 + w3);
    }
    for (; p + 3 < end; p += 4) {
        int2 ea = epack[p + hf];
        int2 eb = epack[p + 2 + hf];
        uint2 ua = *(const uint2*)(y1b + (size_t)ea.x * 128 + c);
        uint2 ub = *(const uint2*)(y1b + (size_t)eb.x * 128 + c);
        float wa = __int_as_float(ea.y), wb = __int_as_float(eb.y);
        ac0 = fmaf(wa, bf_lo(ua.x), ac0); ac1 = fmaf(wa, bf_hi(ua.x), ac1);
        ac2 = fmaf(wa, bf_lo(ua.y), ac2); ac3 = fmaf(wa, bf_hi(ua.y), ac3);
        ac0 = fmaf(wb, bf_lo(ub.x), ac0); ac1 = fmaf(wb, bf_hi(ub.x), ac1);
        ac2 = fmaf(wb, bf_lo(ub.y), ac2); ac3 = fmaf(wb, bf_hi(ub.y), ac3);
        den += wa + wb;
    }
    for (; p + 1 < end; p += 2) {
        int2 ea = epack[p + hf];
        uint2 ua = *(const uint2*)(y1b + (size_t)ea.x * 128 + c);
        float wa = __int_as_float(ea.y);
        ac0 = fmaf(wa, bf_lo(ua.x), ac0); ac1 = fmaf(wa, bf_hi(ua.x), ac1);
        ac2 = fmaf(wa, bf_lo(ua.y), ac2); ac3 = fmaf(wa, bf_hi(ua.y), ac3);
        den += wa;
    }
    if (p < end && hf == 0) {   // odd tail edge: half 0 only
        int2 ea = epack[p];
        uint2 ua = *(const uint2*)(y1b + (size_t)ea.x * 128 + c);
        float wa = __int_as_float(ea.y);
        ac0 = fmaf(wa, bf_lo(ua.x), ac0); ac1 = fmaf(wa, bf_hi(ua.x), ac1);
        ac2 = fmaf(wa, bf_lo(ua.y), ac2); ac3 = fmaf(wa, bf_hi(ua.y), ac3);
        den += wa;
    }
    ac0 += __shfl_xor(ac0, 32, 64);
    ac1 += __shfl_xor(ac1, 32, 64);
    ac2 += __shfl_xor(ac2, 32, 64);
    ac3 += __shfl_xor(ac3, 32, 64);
    den += __shfl_xor(den, 32, 64);
    if (hf) return;
    float4 av = *(const float4*)(a + c);
    float4 bv = *(const float4*)(b + c);
    float m0, m1, m2, m3;
    if (den != 0.f) {
        float inv = 1.f / den;
        m0 = ac0 * inv; m1 = ac1 * inv; m2 = ac2 * inv; m3 = ac3 * inv;
    } else {
        uint2 u = *(const uint2*)(y1b + (size_t)r * 128 + c);
        m0 = bf_lo(u.x); m1 = bf_hi(u.x); m2 = bf_lo(u.y); m3 = bf_hi(u.y);
    }
    ushort4 o;
    o.x = f2bf(fmaf(av.x, m0, bv.x));
    o.y = f2bf(fmaf(av.y, m1, bv.y));
    o.z = f2bf(fmaf(av.z, m2, bv.z));
    o.w = f2bf(fmaf(av.w, m3, bv.w));
    *(ushort4*)(aggb + (size_t)r * 128 + c) = o;
}

// ---------------------------------------------------------------------------
// gemm2 standalone (K=256, A = [featb|aggb], 128x128 tile) -> y2 f32 + stats2.
__global__ __launch_bounds__(256) void gemm_bn2(
    const unsigned short* __restrict__ A_lo,
    const unsigned short* __restrict__ A_hi,
    const unsigned short* __restrict__ Bb,
    const float* __restrict__ bias,
    float* __restrict__ Y,
    double* __restrict__ sum, double* __restrict__ sumsq, int N)
{
    constexpr int SA = 72;
    constexpr int K = 256;
    __shared__ unsigned short As[128 * SA];
    __shared__ unsigned short Bs[128 * SA];
    __shared__ float bsum_s[128], bsq_s[128];

    const int tid  = threadIdx.x;
    const int lane = tid & 63;
    const int wv   = tid >> 6;
    const int wr   = wv >> 1;
    const int wc   = wv & 1;
    const int m15  = lane & 15;
    const int quad = lane >> 4;
    const int r0   = (int)blockIdx.x * 128;

    if (tid < 128) { bsum_s[tid] = 0.f; bsq_s[tid] = 0.f; }

    f32x4 acc[4][4];
#pragma unroll
    for (int rt = 0; rt < 4; ++rt)
#pragma unroll
        for (int ct = 0; ct < 4; ++ct)
            acc[rt][ct] = (f32x4){0.f, 0.f, 0.f, 0.f};

    for (int kc = 0; kc < K; kc += 64) {
        const unsigned short* Ap = (kc < 128) ? A_lo : A_hi;
        const int koff = kc & 127;
        // A tile: 128 rows x 64 bf16 -> 4 x 256 x 16B
#pragma unroll
        for (int i = 0; i < 4; ++i) {
            int idx = i * 256 + tid;
            int row = idx >> 3, seg = idx & 7;
            int gr  = r0 + row; if (gr >= N) gr = N - 1;
            uint4 v = *(const uint4*)(Ap + (size_t)gr * 128 + koff + seg * 8);
            *(uint4*)(As + row * SA + seg * 8) = v;
        }
        // B tile: 128 rows x 64 bf16 -> 4 x 256 x 16B (pure copy)
#pragma unroll
        for (int i = 0; i < 4; ++i) {
            int idx = i * 256 + tid;
            int row = idx >> 3, seg = idx & 7;
            uint4 v = *(const uint4*)(Bb + (size_t)row * K + kc + seg * 8);
            *(uint4*)(Bs + row * SA + seg * 8) = v;
        }
        __syncthreads();

#pragma unroll
        for (int ks = 0; ks < 64; ks += 32) {
            bf16x8 af[4], bfr[4];
#pragma unroll
            for (int rt = 0; rt < 4; ++rt)
                af[rt] = *(const bf16x8*)(As + (wr * 64 + rt * 16 + m15) * SA + ks + quad * 8);
#pragma unroll
            for (int ct = 0; ct < 4; ++ct)
                bfr[ct] = *(const bf16x8*)(Bs + (wc * 64 + ct * 16 + m15) * SA + ks + quad * 8);
#pragma unroll
            for (int rt = 0; rt < 4; ++rt)
#pragma unroll
                for (int ct = 0; ct < 4; ++ct)
                    acc[rt][ct] = __builtin_amdgcn_mfma_f32_16x16x32_bf16(
                        af[rt], bfr[ct], acc[rt][ct], 0, 0, 0);
        }
        __syncthreads();
    }

#pragma unroll
    for (int ct = 0; ct < 4; ++ct) {
        int col = wc * 64 + ct * 16 + m15;
        float bz = bias[col];
        float s = 0.f, q = 0.f;
#pragma unroll
        for (int rt = 0; rt < 4; ++rt) {
#pragma unroll
            for (int reg = 0; reg < 4; ++reg) {
                int row = r0 + wr * 64 + rt * 16 + quad * 4 + reg;
                float vv = fmaxf(acc[rt][ct][reg] + bz, 0.f);
                if (row < N) {
                    Y[(size_t)row * 128 + col] = vv;
                } else {
                    vv = 0.f;
                }
                s += vv; q = fmaf(vv, vv, q);
            }
        }
        s += __shfl_xor(s, 16, 64); s += __shfl_xor(s, 32, 64);
        q += __shfl_xor(q, 16, 64); q += __shfl_xor(q, 32, 64);
        if (quad == 0) {
            atomicAdd(&bsum_s[col], s);
            atomicAdd(&bsq_s[col], q);
        }
    }
    __syncthreads();
    if (tid < 128) {
        const int slot = ((int)blockIdx.x & (NSLOT - 1)) * 128;
        atomicAdd(&sum[slot + tid],   (double)bsum_s[tid]);
        atomicAdd(&sumsq[slot + tid], (double)bsq_s[tid]);
    }
}

// ---------------------------------------------------------------------------
// bn2 affine (precomputed coefs) + row L2 normalize.
__global__ __launch_bounds__(256) void finalize(
    const float* __restrict__ Y2,
    const float* __restrict__ a, const float* __restrict__ b,
    float* __restrict__ out, int N)
{
    __shared__ float sa[128], sb[128];
    const int t = threadIdx.x;
    if (t < 128) { sa[t] = a[t]; sb[t] = b[t]; }
    __syncthreads();
    const int row  = (int)((blockIdx.x * 256u + t) >> 6);
    const int lane = t & 63;
    if (row >= N) return;
    const size_t base = (size_t)row * 128;
    float v0 = fmaf(sa[lane],      Y2[base + lane],      sb[lane]);
    float v1 = fmaf(sa[lane + 64], Y2[base + lane + 64], sb[lane + 64]);
    float ss = fmaf(v0, v0, v1 * v1);
#pragma unroll
    for (int o = 32; o; o >>= 1) ss += __shfl_xor(ss, o, 64);
    float nrm = sqrtf(ss);
    float inv = (nrm == 0.f) ? 1.f : 1.f / nrm;
    out[base + lane]      = v0 * inv;
    out[base + lane + 64] = v1 * inv;
}

// ---------------------------------------------------------------------------
extern "C" void kernel_launch(void* const* d_in, const int* in_sizes, int n_in,
                              void* d_out, int out_size, void* d_ws, size_t ws_size,
                              hipStream_t stream)
{
    const float* feat   = (const float*)d_in[0];
    const float* w      = (const float*)d_in[1];
    const float* Q_w    = (const float*)d_in[2];
    const float* Q_b    = (const float*)d_in[3];
    const float* W_w    = (const float*)d_in[4];
    const float* W_b    = (const float*)d_in[5];
    const float* gamma2 = (const float*)d_in[6];
    const float* beta2  = (const float*)d_in[7];
    const int*   src    = (const int*)d_in[8];
    const int*   dst    = (const int*)d_in[9];

    const int N = in_sizes[0] / 128;   // 50000
    const int E = in_sizes[1];         // 800000

    // workspace layout
    float*          y2    = (float*)d_ws;                            // N*128 f32
    unsigned short* featb = (unsigned short*)(y2 + (size_t)N * 128); // N*128 bf16
    unsigned short* aggb  = featb + (size_t)N * 128;                 // N*128 bf16
    unsigned short* y1b   = aggb + (size_t)N * 128;                  // N*128 bf16
    int4*  tmp    = (int4*)(y1b + (size_t)N * 128);                  // E (16B aligned)
    int2*  epack  = (int2*)(tmp + E);                                // E
    int*   offs   = (int*)(epack + E);                               // N+1
    float* coefs  = (float*)(offs + N + 1);                          // 512
    float* a1 = coefs, *b1 = coefs + 128, *a2 = coefs + 256, *b2 = coefs + 384;
    uintptr_t qp = ((uintptr_t)(coefs + 512) + 15) & ~(uintptr_t)15;
    unsigned short* Qwb = (unsigned short*)qp;                       // 128*128 bf16
    unsigned short* Wwb = Qwb + 128 * 128;                           // 128*256 bf16
    uintptr_t sp = ((uintptr_t)(Wwb + 128 * 256) + 15) & ~(uintptr_t)15;
    double* stats = (double*)sp;                                     // 4*NSLOT*128 <- zeroed
    double* sum1   = stats;
    double* sumsq1 = stats + NSLOT * 128;
    double* sum2   = stats + 2 * NSLOT * 128;
    double* sumsq2 = stats + 3 * NSLOT * 128;
    int*   ccnt   = (int*)(stats + 4 * NSLOT * 128);                 // 128 <- zeroed
    int*   gofs   = ccnt + 128;                                      // 128 <- zeroed

    hipMemsetAsync(stats, 0,
                   4 * NSLOT * 128 * sizeof(double) + 256 * sizeof(int),
                   stream);

    const double invN = 1.0 / (double)N;
    const int GB  = (N + 63) / 64;              // gemm1 blocks (782)
    const int GB2 = (N + 127) / 128;            // gemm2 blocks (391)
    const int NB = (N + 511) >> 9;              // coarse buckets (98)
    const int CB = (N * 128 / 4 + 255) / 256;   // feat cast blocks
    const int HB = (E + 2047) / 2048;           // histogram/bin blocks
    const int QB = 16;                          // Q_w cast blocks
    const int WB = 32;                          // W_w cast blocks

    k_pre<<<CB + HB + QB + WB, 256, 0, stream>>>(
        feat, featb, N * 128, dst, ccnt, E, CB, HB,
        Q_w, Qwb, W_w, Wwb, offs, N);

    // fatB: bin || gemm1 -> y1b bf16 + stats1 (bases via in-block ccnt scan)
    k_bin_gemm<<<HB + GB, 256, 0, stream>>>(
        src, dst, w, ccnt, gofs, tmp, E, HB,
        featb, Qwb, Q_b, y1b, sum1, sumsq1, N);

    // fat: bn_coef1 (block 0) || refine (blocks 1..NB)
    k_bnref<<<NB + 1, 256, 0, stream>>>(
        sum1, sumsq1, gamma2, beta2, a1, b1, invN,
        tmp, ccnt, offs, epack, N);

    gather_agg<<<(N * 64 + 255) / 256, 256, 0, stream>>>(
        y1b, offs, epack, a1, b1, aggb, N);

    gemm_bn2<<<GB2, 256, 0, stream>>>(
        featb, aggb, Wwb, W_b, y2, sum2, sumsq2, N);

    bn_coef<<<1, 128, 0, stream>>>(sum2, sumsq2, gamma2, beta2, a2, b2, invN);
    finalize<<<(N * 64 + 255) / 256, 256, 0, stream>>>(
        y2, a2, b2, (float*)d_out, N);
}

// Round 9
// 222.540 us; speedup vs baseline: 1.3507x; 1.0041x over previous
//
#include <hip/hip_runtime.h>
#include <stdint.h>

// PinConv pipeline, round 19 (base = round 18, 223.4us best):
//  - gather_agg restructured: 16 lanes/edge x uint4 (16B) loads, 4 edges in
//    flight per load round (8 with 2-deep unroll). Halves load-instr count
//    and per-lane VALU per edge; doubles MLP. Cross-group combine = xor-16 +
//    xor-32 butterfly once per row. Single isolated change.
//  - everything else identical to round 18 (128^2 gemm2 tile, 64x128 gemm1
//    in fatB, no k_coffs, no fences, pre-cast bf16 B).

#define BN_EPS 1e-5f
#define NSLOT 32

typedef __attribute__((ext_vector_type(8))) short bf16x8;
typedef __attribute__((ext_vector_type(4))) float f32x4;

static __device__ __forceinline__ unsigned short f2bf(float f) {
    uint32_t u = __builtin_bit_cast(uint32_t, f);
    u += 0x7fffu + ((u >> 16) & 1u);          // round-to-nearest-even
    return (unsigned short)(u >> 16);
}
static __device__ __forceinline__ float bf_lo(uint32_t u) {
    return __builtin_bit_cast(float, u << 16);
}
static __device__ __forceinline__ float bf_hi(uint32_t u) {
    return __builtin_bit_cast(float, u & 0xffff0000u);
}

static __device__ __forceinline__ void cast_blk(
    const float* __restrict__ src, unsigned short* __restrict__ dst,
    int n, int blk)
{
    int i = (blk * 256 + threadIdx.x) * 4;
    if (i + 3 < n) {
        float4 v = *(const float4*)(src + i);
        ushort4 o;
        o.x = f2bf(v.x); o.y = f2bf(v.y); o.z = f2bf(v.z); o.w = f2bf(v.w);
        *(ushort4*)(dst + i) = o;
    } else {
        for (int j = i; j < n; ++j) dst[j] = f2bf(src[j]);
    }
}

// Redundant per-block exclusive scan of ccnt[128].
static __device__ __forceinline__ void scan_ccnt(
    const int* __restrict__ ccnt, int* excl_out, int* v_out, int* w0s)
{
    const int t = threadIdx.x;
    int v = 0, incl = 0;
    if (t < 128) {
        v = ccnt[t];
        incl = v;
        const int lane = t & 63;
#pragma unroll
        for (int o = 1; o < 64; o <<= 1) {
            int u = __shfl_up(incl, o, 64);
            if (lane >= o) incl += u;
        }
        if (t == 63) *w0s = incl;
    }
    __syncthreads();
    int excl = 0;
    if (t < 128) excl = incl - v + ((t >> 6) ? *w0s : 0);
    *excl_out = excl;
    *v_out = v;
}

// ---------------------------------------------------------------------------
// Fused: blocks [0,CB) cast feat; [CB,CB+HB) coarse-histogram dst into
// 512-wide buckets; [CB+HB,..) cast Q_w / W_w to bf16. No fences.
__global__ __launch_bounds__(256) void k_pre(
    const float* __restrict__ feat, unsigned short* __restrict__ featb, int nf,
    const int* __restrict__ dst, int* __restrict__ ccnt, int E, int CB, int HB,
    const float* __restrict__ Qw, unsigned short* __restrict__ Qwb,
    const float* __restrict__ Ww, unsigned short* __restrict__ Wwb,
    int* __restrict__ offs, int N)
{
    int b = (int)blockIdx.x;
    if (b < CB) {
        if (b == 0 && threadIdx.x == 0) offs[N] = E;
        cast_blk(feat, featb, nf, b);
        return;
    }
    b -= CB;
    if (b >= HB) {
        b -= HB;
        if (b < 16) cast_blk(Qw, Qwb, 128 * 128, b);
        else        cast_blk(Ww, Wwb, 128 * 256, b - 16);
        return;
    }
    __shared__ int hcnt[128];
    const int tid = threadIdx.x;
    if (tid < 128) hcnt[tid] = 0;
    __syncthreads();
    const int base_e = b * 2048;
#pragma unroll
    for (int j = 0; j < 8; ++j) {
        int e = base_e + j * 256 + tid;
        if (e < E) atomicAdd(&hcnt[dst[e] >> 9], 1);
    }
    __syncthreads();
    if (tid < 128 && hcnt[tid] > 0) atomicAdd(&ccnt[tid], hcnt[tid]);
}

// ---------------------------------------------------------------------------
// GEMM body (LDS-staged, 64x128 tile): used by gemm1 inside fatB.
template<int K, bool OUT_BF16>
static __device__ __forceinline__ void gemm_body(
    int bid,
    const unsigned short* __restrict__ A_lo,
    const unsigned short* __restrict__ A_hi,
    const unsigned short* __restrict__ Bb,
    const float* __restrict__ bias,
    void* __restrict__ Yv,
    double* __restrict__ sum, double* __restrict__ sumsq, int N)
{
    constexpr int SA = 72;
    __shared__ unsigned short As[64 * SA];
    __shared__ unsigned short Bs[128 * SA];
    __shared__ float bsum_s[128], bsq_s[128];

    const int tid  = threadIdx.x;
    const int lane = tid & 63;
    const int wv   = tid >> 6;
    const int wr   = wv >> 1;
    const int wc   = wv & 1;
    const int m15  = lane & 15;
    const int quad = lane >> 4;
    const int r0   = bid * 64;

    if (tid < 128) { bsum_s[tid] = 0.f; bsq_s[tid] = 0.f; }

    f32x4 acc[2][4];
#pragma unroll
    for (int rt = 0; rt < 2; ++rt)
#pragma unroll
        for (int ct = 0; ct < 4; ++ct)
            acc[rt][ct] = (f32x4){0.f, 0.f, 0.f, 0.f};

    for (int kc = 0; kc < K; kc += 64) {
        const unsigned short* Ap = (kc < 128) ? A_lo : A_hi;
        const int koff = kc & 127;
#pragma unroll
        for (int i = 0; i < 2; ++i) {
            int idx = i * 256 + tid;
            int row = idx >> 3, seg = idx & 7;
            int gr  = r0 + row; if (gr >= N) gr = N - 1;
            uint4 v = *(const uint4*)(Ap + (size_t)gr * 128 + koff + seg * 8);
            *(uint4*)(As + row * SA + seg * 8) = v;
        }
#pragma unroll
        for (int i = 0; i < 4; ++i) {
            int idx = i * 256 + tid;
            int row = idx >> 3, seg = idx & 7;
            uint4 v = *(const uint4*)(Bb + (size_t)row * K + kc + seg * 8);
            *(uint4*)(Bs + row * SA + seg * 8) = v;
        }
        __syncthreads();

#pragma unroll
        for (int ks = 0; ks < 64; ks += 32) {
            bf16x8 af[2], bfr[4];
#pragma unroll
            for (int rt = 0; rt < 2; ++rt)
                af[rt] = *(const bf16x8*)(As + (wr * 32 + rt * 16 + m15) * SA + ks + quad * 8);
#pragma unroll
            for (int ct = 0; ct < 4; ++ct)
                bfr[ct] = *(const bf16x8*)(Bs + (wc * 64 + ct * 16 + m15) * SA + ks + quad * 8);
#pragma unroll
            for (int rt = 0; rt < 2; ++rt)
#pragma unroll
                for (int ct = 0; ct < 4; ++ct)
                    acc[rt][ct] = __builtin_amdgcn_mfma_f32_16x16x32_bf16(
                        af[rt], bfr[ct], acc[rt][ct], 0, 0, 0);
        }
        __syncthreads();
    }

#pragma unroll
    for (int ct = 0; ct < 4; ++ct) {
        int col = wc * 64 + ct * 16 + m15;
        float bz = bias[col];
        float s = 0.f, q = 0.f;
#pragma unroll
        for (int rt = 0; rt < 2; ++rt) {
#pragma unroll
            for (int reg = 0; reg < 4; ++reg) {
                int row = r0 + wr * 32 + rt * 16 + quad * 4 + reg;
                float vv = fmaxf(acc[rt][ct][reg] + bz, 0.f);
                if (row < N) {
                    if constexpr (OUT_BF16)
                        ((unsigned short*)Yv)[(size_t)row * 128 + col] = f2bf(vv);
                    else
                        ((float*)Yv)[(size_t)row * 128 + col] = vv;
                } else {
                    vv = 0.f;
                }
                s += vv; q = fmaf(vv, vv, q);
            }
        }
        s += __shfl_xor(s, 16, 64); s += __shfl_xor(s, 32, 64);
        q += __shfl_xor(q, 16, 64); q += __shfl_xor(q, 32, 64);
        if (quad == 0) {
            atomicAdd(&bsum_s[col], s);
            atomicAdd(&bsq_s[col], q);
        }
    }
    __syncthreads();
    if (tid < 128) {
        const int slot = (bid & (NSLOT - 1)) * 128;
        atomicAdd(&sum[slot + tid],   (double)bsum_s[tid]);
        atomicAdd(&sumsq[slot + tid], (double)bsq_s[tid]);
    }
}

// ---------------------------------------------------------------------------
// bn coef body: reduce 32 slots -> bn affine coefs. t in [0,128).
static __device__ __forceinline__ void bn_coef_body(
    int t, const double* __restrict__ sum, const double* __restrict__ sumsq,
    const float* __restrict__ gamma, const float* __restrict__ beta,
    float* __restrict__ a, float* __restrict__ b, double invN)
{
    double ms = 0.0, qs = 0.0;
#pragma unroll
    for (int s = 0; s < NSLOT; ++s) {
        ms += sum[s * 128 + t];
        qs += sumsq[s * 128 + t];
    }
    float mean = (float)(ms * invN);
    float var  = (float)(qs * invN) - mean * mean;
    float sc = rsqrtf(var + BN_EPS) * gamma[t];
    a[t] = sc;
    b[t] = fmaf(-mean, sc, beta[t]);
}

__global__ __launch_bounds__(128) void bn_coef(
    const double* __restrict__ sum, const double* __restrict__ sumsq,
    const float* __restrict__ gamma, const float* __restrict__ beta,
    float* __restrict__ a, float* __restrict__ b, double invN)
{
    bn_coef_body(threadIdx.x, sum, sumsq, gamma, beta, a, b, invN);
}

// ---------------------------------------------------------------------------
// bin body: bin edges into coarse buckets of 512 dsts (int4 records).
static __device__ __forceinline__ void bin_body(
    int bid,
    const int* __restrict__ src, const int* __restrict__ dst,
    const float* __restrict__ w,
    const int* __restrict__ ccnt, int* __restrict__ gofs,
    int4* __restrict__ tmp, int E)
{
    __shared__ int hcnt[128];
    __shared__ int hbase[128];
    __shared__ int w0s;
    const int tid = threadIdx.x;
    if (tid < 128) hcnt[tid] = 0;
    __syncthreads();

    int d8[8], s8[8], slot8[8];
    float w8[8];
#pragma unroll
    for (int j = 0; j < 8; ++j) {
        int e = bid * 2048 + j * 256 + tid;
        if (e < E) {
            d8[j] = dst[e]; s8[j] = src[e]; w8[j] = w[e];
            slot8[j] = atomicAdd(&hcnt[d8[j] >> 9], 1);
        } else d8[j] = -1;
    }
    __syncthreads();
    int excl, vcnt;
    scan_ccnt(ccnt, &excl, &vcnt, &w0s);
    if (tid < 128 && hcnt[tid] > 0)
        hbase[tid] = excl + atomicAdd(&gofs[tid], hcnt[tid]);
    __syncthreads();
#pragma unroll
    for (int j = 0; j < 8; ++j) {
        if (d8[j] >= 0) {
            int pos = hbase[d8[j] >> 9] + slot8[j];
            tmp[pos] = make_int4(s8[j], __float_as_int(w8[j]), d8[j], 0);
        }
    }
}

// fatB: blocks [0,HB) bin edges; blocks [HB,HB+GB) run gemm1 -> y1b bf16.
__global__ __launch_bounds__(256) void k_bin_gemm(
    const int* __restrict__ src, const int* __restrict__ dst,
    const float* __restrict__ w,
    const int* __restrict__ ccnt, int* __restrict__ gofs,
    int4* __restrict__ tmp, int E, int HB,
    const unsigned short* __restrict__ featb,
    const unsigned short* __restrict__ Qwb, const float* __restrict__ Qb,
    unsigned short* __restrict__ y1b,
    double* __restrict__ sum, double* __restrict__ sumsq, int N)
{
    if ((int)blockIdx.x < HB)
        bin_body(blockIdx.x, src, dst, w, ccnt, gofs, tmp, E);
    else
        gemm_body<128, true>(blockIdx.x - HB, featb, featb, Qwb, Qb, y1b,
                             sum, sumsq, N);
}

// ---------------------------------------------------------------------------
// refine body: per bucket — bases from redundant ccnt scan; count per-dst in
// LDS, scan (+bucket base), write offs slice, scatter to epack in dst order.
static __device__ __forceinline__ void refine_body(
    int b,
    const int4* __restrict__ tmp, const int* __restrict__ ccnt,
    int* __restrict__ offs, int2* __restrict__ epack, int N)
{
    __shared__ int hist[512];
    __shared__ int wpre[4];
    __shared__ int w0s;
    __shared__ int sbounds[2];
    const int d0   = b << 9;
    const int dlim = min(512, N - d0);
    const int tid  = threadIdx.x;
    const int lane = tid & 63, wv = tid >> 6;

    hist[tid] = 0; hist[tid + 256] = 0;
    __syncthreads();
    int excl, vcnt;
    scan_ccnt(ccnt, &excl, &vcnt, &w0s);
    if (tid == b) { sbounds[0] = excl; sbounds[1] = excl + vcnt; }
    __syncthreads();
    const int start = sbounds[0];
    const int end   = sbounds[1];

    for (int p = start + tid; p < end; p += 256)
        atomicAdd(&hist[tmp[p].z - d0], 1);
    __syncthreads();

    int v0 = hist[2 * tid], v1 = hist[2 * tid + 1];
    int s = v0 + v1;
    int incl = s;
#pragma unroll
    for (int o = 1; o < 64; o <<= 1) {
        int t = __shfl_up(incl, o, 64);
        if (lane >= o) incl += t;
    }
    if (lane == 63) wpre[wv] = incl;
    __syncthreads();
    if (tid == 0) {
        int r = 0;
#pragma unroll
        for (int i = 0; i < 4; ++i) { int t = wpre[i]; wpre[i] = r; r += t; }
    }
    __syncthreads();
    int e0 = start + wpre[wv] + incl - s;
    if (2 * tid < dlim)     offs[d0 + 2 * tid]     = e0;
    if (2 * tid + 1 < dlim) offs[d0 + 2 * tid + 1] = e0 + v0;
    hist[2 * tid]     = e0;
    hist[2 * tid + 1] = e0 + v0;
    __syncthreads();

    for (int p = start + tid; p < end; p += 256) {
        int4 rec = tmp[p];
        int pos = atomicAdd(&hist[rec.z - d0], 1);
        epack[pos] = make_int2(rec.x, rec.y);
    }
}

// fat: block 0 = bn_coef1 reduce; blocks [1,NB] = refine buckets.
__global__ __launch_bounds__(256) void k_bnref(
    const double* __restrict__ sum, const double* __restrict__ sumsq,
    const float* __restrict__ gamma, const float* __restrict__ beta,
    float* __restrict__ a, float* __restrict__ b, double invN,
    const int4* __restrict__ tmp, const int* __restrict__ ccnt,
    int* __restrict__ offs, int2* __restrict__ epack, int N)
{
    if (blockIdx.x == 0) {
        if (threadIdx.x < 128)
            bn_coef_body(threadIdx.x, sum, sumsq, gamma, beta, a, b, invN);
        return;
    }
    refine_body((int)blockIdx.x - 1, tmp, ccnt, offs, epack, N);
}

// ---------------------------------------------------------------------------
// One wave per dst row; 16 lanes/edge, uint4 (16B) loads, 4 edges per load
// round (8 with 2-deep unroll). Reads raw relu y1b; applies bn affine (a,b)
// to the weighted mean (or own row when den==0). Writes agg bf16.
__global__ __launch_bounds__(256) void gather_agg(
    const unsigned short* __restrict__ y1b,
    const int* __restrict__ offs, const int2* __restrict__ epack,
    const float* __restrict__ a, const float* __restrict__ b,
    unsigned short* __restrict__ aggb, int N)
{
    const int r    = (int)((blockIdx.x * 256u + threadIdx.x) >> 6);
    const int lane = threadIdx.x & 63;
    const int li   = lane & 15;     // owns columns 8*li .. 8*li+7
    const int hf   = lane >> 4;     // edge slot in quad (0..3)
    if (r >= N) return;
    int p = offs[r];
    const int end = offs[r + 1];
    const int c = 8 * li;
    float ac0 = 0.f, ac1 = 0.f, ac2 = 0.f, ac3 = 0.f;
    float ac4 = 0.f, ac5 = 0.f, ac6 = 0.f, ac7 = 0.f;
    float den = 0.f;
    for (; p + 7 < end; p += 8) {
        int2 e0 = epack[p + hf];
        int2 e1 = epack[p + 4 + hf];
        uint4 u0 = *(const uint4*)(y1b + (size_t)e0.x * 128 + c);
        uint4 u1 = *(const uint4*)(y1b + (size_t)e1.x * 128 + c);
        float w0 = __int_as_float(e0.y), w1 = __int_as_float(e1.y);
        ac0 = fmaf(w0, bf_lo(u0.x), ac0); ac1 = fmaf(w0, bf_hi(u0.x), ac1);
        ac2 = fmaf(w0, bf_lo(u0.y), ac2); ac3 = fmaf(w0, bf_hi(u0.y), ac3);
        ac4 = fmaf(w0, bf_lo(u0.z), ac4); ac5 = fmaf(w0, bf_hi(u0.z), ac5);
        ac6 = fmaf(w0, bf_lo(u0.w), ac6); ac7 = fmaf(w0, bf_hi(u0.w), ac7);
        ac0 = fmaf(w1, bf_lo(u1.x), ac0); ac1 = fmaf(w1, bf_hi(u1.x), ac1);
        ac2 = fmaf(w1, bf_lo(u1.y), ac2); ac3 = fmaf(w1, bf_hi(u1.y), ac3);
        ac4 = fmaf(w1, bf_lo(u1.z), ac4); ac5 = fmaf(w1, bf_hi(u1.z), ac5);
        ac6 = fmaf(w1, bf_lo(u1.w), ac6); ac7 = fmaf(w1, bf_hi(u1.w), ac7);
        den += w0 + w1;
    }
    for (; p < end; p += 4) {
        if (p + hf < end) {
            int2 e0 = epack[p + hf];
            uint4 u0 = *(const uint4*)(y1b + (size_t)e0.x * 128 + c);
            float w0 = __int_as_float(e0.y);
            ac0 = fmaf(w0, bf_lo(u0.x), ac0); ac1 = fmaf(w0, bf_hi(u0.x), ac1);
            ac2 = fmaf(w0, bf_lo(u0.y), ac2); ac3 = fmaf(w0, bf_hi(u0.y), ac3);
            ac4 = fmaf(w0, bf_lo(u0.z), ac4); ac5 = fmaf(w0, bf_hi(u0.z), ac5);
            ac6 = fmaf(w0, bf_lo(u0.w), ac6); ac7 = fmaf(w0, bf_hi(u0.w), ac7);
            den += w0;
        }
    }
    // sum the 4 edge-groups (lane bits 4,5); li (lane&15) invariant
    ac0 += __shfl_xor(ac0, 16, 64); ac0 += __shfl_xor(ac0, 32, 64);
    ac1 += __shfl_xor(ac1, 16, 64); ac1 += __shfl_xor(ac1, 32, 64);
    ac2 += __shfl_xor(ac2, 16, 64); ac2 += __shfl_xor(ac2, 32, 64);
    ac3 += __shfl_xor(ac3, 16, 64); ac3 += __shfl_xor(ac3, 32, 64);
    ac4 += __shfl_xor(ac4, 16, 64); ac4 += __shfl_xor(ac4, 32, 64);
    ac5 += __shfl_xor(ac5, 16, 64); ac5 += __shfl_xor(ac5, 32, 64);
    ac6 += __shfl_xor(ac6, 16, 64); ac6 += __shfl_xor(ac6, 32, 64);
    ac7 += __shfl_xor(ac7, 16, 64); ac7 += __shfl_xor(ac7, 32, 64);
    den += __shfl_xor(den, 16, 64); den += __shfl_xor(den, 32, 64);
    if (hf) return;
    float4 av0 = *(const float4*)(a + c);
    float4 av1 = *(const float4*)(a + c + 4);
    float4 bv0 = *(const float4*)(b + c);
    float4 bv1 = *(const float4*)(b + c + 4);
    float m0, m1, m2, m3, m4, m5, m6, m7;
    if (den != 0.f) {
        float inv = 1.f / den;
        m0 = ac0 * inv; m1 = ac1 * inv; m2 = ac2 * inv; m3 = ac3 * inv;
        m4 = ac4 * inv; m5 = ac5 * inv; m6 = ac6 * inv; m7 = ac7 * inv;
    } else {
        uint4 u = *(const uint4*)(y1b + (size_t)r * 128 + c);
        m0 = bf_lo(u.x); m1 = bf_hi(u.x); m2 = bf_lo(u.y); m3 = bf_hi(u.y);
        m4 = bf_lo(u.z); m5 = bf_hi(u.z); m6 = bf_lo(u.w); m7 = bf_hi(u.w);
    }
    uint4 o;
    o.x = (uint32_t)f2bf(fmaf(av0.x, m0, bv0.x))
        | ((uint32_t)f2bf(fmaf(av0.y, m1, bv0.y)) << 16);
    o.y = (uint32_t)f2bf(fmaf(av0.z, m2, bv0.z))
        | ((uint32_t)f2bf(fmaf(av0.w, m3, bv0.w)) << 16);
    o.z = (uint32_t)f2bf(fmaf(av1.x, m4, bv1.x))
        | ((uint32_t)f2bf(fmaf(av1.y, m5, bv1.y)) << 16);
    o.w = (uint32_t)f2bf(fmaf(av1.z, m6, bv1.z))
        | ((uint32_t)f2bf(fmaf(av1.w, m7, bv1.w)) << 16);
    *(uint4*)(aggb + (size_t)r * 128 + c) = o;
}

// ---------------------------------------------------------------------------
// gemm2 standalone (K=256, A = [featb|aggb], 128x128 tile) -> y2 f32 + stats2.
__global__ __launch_bounds__(256) void gemm_bn2(
    const unsigned short* __restrict__ A_lo,
    const unsigned short* __restrict__ A_hi,
    const unsigned short* __restrict__ Bb,
    const float* __restrict__ bias,
    float* __restrict__ Y,
    double* __restrict__ sum, double* __restrict__ sumsq, int N)
{
    constexpr int SA = 72;
    constexpr int K = 256;
    __shared__ unsigned short As[128 * SA];
    __shared__ unsigned short Bs[128 * SA];
    __shared__ float bsum_s[128], bsq_s[128];

    const int tid  = threadIdx.x;
    const int lane = tid & 63;
    const int wv   = tid >> 6;
    const int wr   = wv >> 1;
    const int wc   = wv & 1;
    const int m15  = lane & 15;
    const int quad = lane >> 4;
    const int r0   = (int)blockIdx.x * 128;

    if (tid < 128) { bsum_s[tid] = 0.f; bsq_s[tid] = 0.f; }

    f32x4 acc[4][4];
#pragma unroll
    for (int rt = 0; rt < 4; ++rt)
#pragma unroll
        for (int ct = 0; ct < 4; ++ct)
            acc[rt][ct] = (f32x4){0.f, 0.f, 0.f, 0.f};

    for (int kc = 0; kc < K; kc += 64) {
        const unsigned short* Ap = (kc < 128) ? A_lo : A_hi;
        const int koff = kc & 127;
#pragma unroll
        for (int i = 0; i < 4; ++i) {
            int idx = i * 256 + tid;
            int row = idx >> 3, seg = idx & 7;
            int gr  = r0 + row; if (gr >= N) gr = N - 1;
            uint4 v = *(const uint4*)(Ap + (size_t)gr * 128 + koff + seg * 8);
            *(uint4*)(As + row * SA + seg * 8) = v;
        }
#pragma unroll
        for (int i = 0; i < 4; ++i) {
            int idx = i * 256 + tid;
            int row = idx >> 3, seg = idx & 7;
            uint4 v = *(const uint4*)(Bb + (size_t)row * K + kc + seg * 8);
            *(uint4*)(Bs + row * SA + seg * 8) = v;
        }
        __syncthreads();

#pragma unroll
        for (int ks = 0; ks < 64; ks += 32) {
            bf16x8 af[4], bfr[4];
#pragma unroll
            for (int rt = 0; rt < 4; ++rt)
                af[rt] = *(const bf16x8*)(As + (wr * 64 + rt * 16 + m15) * SA + ks + quad * 8);
#pragma unroll
            for (int ct = 0; ct < 4; ++ct)
                bfr[ct] = *(const bf16x8*)(Bs + (wc * 64 + ct * 16 + m15) * SA + ks + quad * 8);
#pragma unroll
            for (int rt = 0; rt < 4; ++rt)
#pragma unroll
                for (int ct = 0; ct < 4; ++ct)
                    acc[rt][ct] = __builtin_amdgcn_mfma_f32_16x16x32_bf16(
                        af[rt], bfr[ct], acc[rt][ct], 0, 0, 0);
        }
        __syncthreads();
    }

#pragma unroll
    for (int ct = 0; ct < 4; ++ct) {
        int col = wc * 64 + ct * 16 + m15;
        float bz = bias[col];
        float s = 0.f, q = 0.f;
#pragma unroll
        for (int rt = 0; rt < 4; ++rt) {
#pragma unroll
            for (int reg = 0; reg < 4; ++reg) {
                int row = r0 + wr * 64 + rt * 16 + quad * 4 + reg;
                float vv = fmaxf(acc[rt][ct][reg] + bz, 0.f);
                if (row < N) {
                    Y[(size_t)row * 128 + col] = vv;
                } else {
                    vv = 0.f;
                }
                s += vv; q = fmaf(vv, vv, q);
            }
        }
        s += __shfl_xor(s, 16, 64); s += __shfl_xor(s, 32, 64);
        q += __shfl_xor(q, 16, 64); q += __shfl_xor(q, 32, 64);
        if (quad == 0) {
            atomicAdd(&bsum_s[col], s);
            atomicAdd(&bsq_s[col], q);
        }
    }
    __syncthreads();
    if (tid < 128) {
        const int slot = ((int)blockIdx.x & (NSLOT - 1)) * 128;
        atomicAdd(&sum[slot + tid],   (double)bsum_s[tid]);
        atomicAdd(&sumsq[slot + tid], (double)bsq_s[tid]);
    }
}

// ---------------------------------------------------------------------------
// bn2 affine (precomputed coefs) + row L2 normalize.
__global__ __launch_bounds__(256) void finalize(
    const float* __restrict__ Y2,
    const float* __restrict__ a, const float* __restrict__ b,
    float* __restrict__ out, int N)
{
    __shared__ float sa[128], sb[128];
    const int t = threadIdx.x;
    if (t < 128) { sa[t] = a[t]; sb[t] = b[t]; }
    __syncthreads();
    const int row  = (int)((blockIdx.x * 256u + t) >> 6);
    const int lane = t & 63;
    if (row >= N) return;
    const size_t base = (size_t)row * 128;
    float v0 = fmaf(sa[lane],      Y2[base + lane],      sb[lane]);
    float v1 = fmaf(sa[lane + 64], Y2[base + lane + 64], sb[lane + 64]);
    float ss = fmaf(v0, v0, v1 * v1);
#pragma unroll
    for (int o = 32; o; o >>= 1) ss += __shfl_xor(ss, o, 64);
    float nrm = sqrtf(ss);
    float inv = (nrm == 0.f) ? 1.f : 1.f / nrm;
    out[base + lane]      = v0 * inv;
    out[base + lane + 64] = v1 * inv;
}

// ---------------------------------------------------------------------------
extern "C" void kernel_launch(void* const* d_in, const int* in_sizes, int n_in,
                              void* d_out, int out_size, void* d_ws, size_t ws_size,
                              hipStream_t stream)
{
    const float* feat   = (const float*)d_in[0];
    const float* w      = (const float*)d_in[1];
    const float* Q_w    = (const float*)d_in[2];
    const float* Q_b    = (const float*)d_in[3];
    const float* W_w    = (const float*)d_in[4];
    const float* W_b    = (const float*)d_in[5];
    const float* gamma2 = (const float*)d_in[6];
    const float* beta2  = (const float*)d_in[7];
    const int*   src    = (const int*)d_in[8];
    const int*   dst    = (const int*)d_in[9];

    const int N = in_sizes[0] / 128;   // 50000
    const int E = in_sizes[1];         // 800000

    // workspace layout
    float*          y2    = (float*)d_ws;                            // N*128 f32
    unsigned short* featb = (unsigned short*)(y2 + (size_t)N * 128); // N*128 bf16
    unsigned short* aggb  = featb + (size_t)N * 128;                 // N*128 bf16
    unsigned short* y1b   = aggb + (size_t)N * 128;                  // N*128 bf16
    int4*  tmp    = (int4*)(y1b + (size_t)N * 128);                  // E (16B aligned)
    int2*  epack  = (int2*)(tmp + E);                                // E
    int*   offs   = (int*)(epack + E);                               // N+1
    float* coefs  = (float*)(offs + N + 1);                          // 512
    float* a1 = coefs, *b1 = coefs + 128, *a2 = coefs + 256, *b2 = coefs + 384;
    uintptr_t qp = ((uintptr_t)(coefs + 512) + 15) & ~(uintptr_t)15;
    unsigned short* Qwb = (unsigned short*)qp;                       // 128*128 bf16
    unsigned short* Wwb = Qwb + 128 * 128;                           // 128*256 bf16
    uintptr_t sp = ((uintptr_t)(Wwb + 128 * 256) + 15) & ~(uintptr_t)15;
    double* stats = (double*)sp;                                     // 4*NSLOT*128 <- zeroed
    double* sum1   = stats;
    double* sumsq1 = stats + NSLOT * 128;
    double* sum2   = stats + 2 * NSLOT * 128;
    double* sumsq2 = stats + 3 * NSLOT * 128;
    int*   ccnt   = (int*)(stats + 4 * NSLOT * 128);                 // 128 <- zeroed
    int*   gofs   = ccnt + 128;                                      // 128 <- zeroed

    hipMemsetAsync(stats, 0,
                   4 * NSLOT * 128 * sizeof(double) + 256 * sizeof(int),
                   stream);

    const double invN = 1.0 / (double)N;
    const int GB  = (N + 63) / 64;              // gemm1 blocks (782)
    const int GB2 = (N + 127) / 128;            // gemm2 blocks (391)
    const int NB = (N + 511) >> 9;              // coarse buckets (98)
    const int CB = (N * 128 / 4 + 255) / 256;   // feat cast blocks
    const int HB = (E + 2047) / 2048;           // histogram/bin blocks
    const int QB = 16;                          // Q_w cast blocks
    const int WB = 32;                          // W_w cast blocks

    k_pre<<<CB + HB + QB + WB, 256, 0, stream>>>(
        feat, featb, N * 128, dst, ccnt, E, CB, HB,
        Q_w, Qwb, W_w, Wwb, offs, N);

    // fatB: bin || gemm1 -> y1b bf16 + stats1 (bases via in-block ccnt scan)
    k_bin_gemm<<<HB + GB, 256, 0, stream>>>(
        src, dst, w, ccnt, gofs, tmp, E, HB,
        featb, Qwb, Q_b, y1b, sum1, sumsq1, N);

    // fat: bn_coef1 (block 0) || refine (blocks 1..NB)
    k_bnref<<<NB + 1, 256, 0, stream>>>(
        sum1, sumsq1, gamma2, beta2, a1, b1, invN,
        tmp, ccnt, offs, epack, N);

    gather_agg<<<(N * 64 + 255) / 256, 256, 0, stream>>>(
        y1b, offs, epack, a1, b1, aggb, N);

    gemm_bn2<<<GB2, 256, 0, stream>>>(
        featb, aggb, Wwb, W_b, y2, sum2, sumsq2, N);

    bn_coef<<<1, 128, 0, stream>>>(sum2, sumsq2, gamma2, beta2, a2, b2, invN);
    finalize<<<(N * 64 + 255) / 256, 256, 0, stream>>>(
        y2, a2, b2, (float*)d_out, N);
}

// Round 10
// 221.999 us; speedup vs baseline: 1.3540x; 1.0024x over previous
//
#include <hip/hip_runtime.h>
#include <stdint.h>

// PinConv pipeline, round 20 (base = round 19, 222.5us best):
//  - gemm_bn2 staging rewritten with __builtin_amdgcn_global_load_lds
//    (width 16): no VGPR round-trip. Linear LDS (gload_lds writes
//    base+lane*16) + XOR chunk swizzle (rule #21 both-sides-or-neither):
//    source chunk (lane&7)^(lane>>3) per 8-row group, fragment reads at
//    chunk^(row&7). 2-way bank aliasing = free (m136). Bit-identical math.
//  - stats zeroing moved from memset into 32 extra k_pre blocks; memset
//    shrinks 132KB -> 1KB (ccnt/gofs only).
//  - everything else identical to round 19.

#define BN_EPS 1e-5f
#define NSLOT 32

typedef __attribute__((ext_vector_type(8))) short bf16x8;
typedef __attribute__((ext_vector_type(4))) float f32x4;

#define GLDS16(g, l) __builtin_amdgcn_global_load_lds( \
    (__attribute__((address_space(1))) void*)(g), \
    (__attribute__((address_space(3))) void*)(l), 16, 0, 0)

static __device__ __forceinline__ unsigned short f2bf(float f) {
    uint32_t u = __builtin_bit_cast(uint32_t, f);
    u += 0x7fffu + ((u >> 16) & 1u);          // round-to-nearest-even
    return (unsigned short)(u >> 16);
}
static __device__ __forceinline__ float bf_lo(uint32_t u) {
    return __builtin_bit_cast(float, u << 16);
}
static __device__ __forceinline__ float bf_hi(uint32_t u) {
    return __builtin_bit_cast(float, u & 0xffff0000u);
}

static __device__ __forceinline__ void cast_blk(
    const float* __restrict__ src, unsigned short* __restrict__ dst,
    int n, int blk)
{
    int i = (blk * 256 + threadIdx.x) * 4;
    if (i + 3 < n) {
        float4 v = *(const float4*)(src + i);
        ushort4 o;
        o.x = f2bf(v.x); o.y = f2bf(v.y); o.z = f2bf(v.z); o.w = f2bf(v.w);
        *(ushort4*)(dst + i) = o;
    } else {
        for (int j = i; j < n; ++j) dst[j] = f2bf(src[j]);
    }
}

// Redundant per-block exclusive scan of ccnt[128].
static __device__ __forceinline__ void scan_ccnt(
    const int* __restrict__ ccnt, int* excl_out, int* v_out, int* w0s)
{
    const int t = threadIdx.x;
    int v = 0, incl = 0;
    if (t < 128) {
        v = ccnt[t];
        incl = v;
        const int lane = t & 63;
#pragma unroll
        for (int o = 1; o < 64; o <<= 1) {
            int u = __shfl_up(incl, o, 64);
            if (lane >= o) incl += u;
        }
        if (t == 63) *w0s = incl;
    }
    __syncthreads();
    int excl = 0;
    if (t < 128) excl = incl - v + ((t >> 6) ? *w0s : 0);
    *excl_out = excl;
    *v_out = v;
}

// ---------------------------------------------------------------------------
// Fused: blocks [0,CB) cast feat; [CB,CB+HB) coarse-histogram dst;
// [CB+HB, CB+HB+QB+WB) cast Q_w/W_w; remaining ZB blocks zero stats.
__global__ __launch_bounds__(256) void k_pre(
    const float* __restrict__ feat, unsigned short* __restrict__ featb, int nf,
    const int* __restrict__ dst, int* __restrict__ ccnt, int E, int CB, int HB,
    const float* __restrict__ Qw, unsigned short* __restrict__ Qwb,
    const float* __restrict__ Ww, unsigned short* __restrict__ Wwb,
    int* __restrict__ offs, int N, double* __restrict__ stats)
{
    int b = (int)blockIdx.x;
    if (b < CB) {
        if (b == 0 && threadIdx.x == 0) offs[N] = E;
        cast_blk(feat, featb, nf, b);
        return;
    }
    b -= CB;
    if (b >= HB) {
        b -= HB;
        if (b < 16) { cast_blk(Qw, Qwb, 128 * 128, b); return; }
        b -= 16;
        if (b < 32) { cast_blk(Ww, Wwb, 128 * 256, b); return; }
        b -= 32;
        // zero stats: 32 blocks x 256 threads x 16B = 128 KB
        uint4* p = (uint4*)stats;
        p[b * 256 + threadIdx.x] = make_uint4(0u, 0u, 0u, 0u);
        return;
    }
    __shared__ int hcnt[128];
    const int tid = threadIdx.x;
    if (tid < 128) hcnt[tid] = 0;
    __syncthreads();
    const int base_e = b * 2048;
#pragma unroll
    for (int j = 0; j < 8; ++j) {
        int e = base_e + j * 256 + tid;
        if (e < E) atomicAdd(&hcnt[dst[e] >> 9], 1);
    }
    __syncthreads();
    if (tid < 128 && hcnt[tid] > 0) atomicAdd(&ccnt[tid], hcnt[tid]);
}

// ---------------------------------------------------------------------------
// GEMM body (LDS-staged, 64x128 tile): used by gemm1 inside fatB.
template<int K, bool OUT_BF16>
static __device__ __forceinline__ void gemm_body(
    int bid,
    const unsigned short* __restrict__ A_lo,
    const unsigned short* __restrict__ A_hi,
    const unsigned short* __restrict__ Bb,
    const float* __restrict__ bias,
    void* __restrict__ Yv,
    double* __restrict__ sum, double* __restrict__ sumsq, int N)
{
    constexpr int SA = 72;
    __shared__ unsigned short As[64 * SA];
    __shared__ unsigned short Bs[128 * SA];
    __shared__ float bsum_s[128], bsq_s[128];

    const int tid  = threadIdx.x;
    const int lane = tid & 63;
    const int wv   = tid >> 6;
    const int wr   = wv >> 1;
    const int wc   = wv & 1;
    const int m15  = lane & 15;
    const int quad = lane >> 4;
    const int r0   = bid * 64;

    if (tid < 128) { bsum_s[tid] = 0.f; bsq_s[tid] = 0.f; }

    f32x4 acc[2][4];
#pragma unroll
    for (int rt = 0; rt < 2; ++rt)
#pragma unroll
        for (int ct = 0; ct < 4; ++ct)
            acc[rt][ct] = (f32x4){0.f, 0.f, 0.f, 0.f};

    for (int kc = 0; kc < K; kc += 64) {
        const unsigned short* Ap = (kc < 128) ? A_lo : A_hi;
        const int koff = kc & 127;
#pragma unroll
        for (int i = 0; i < 2; ++i) {
            int idx = i * 256 + tid;
            int row = idx >> 3, seg = idx & 7;
            int gr  = r0 + row; if (gr >= N) gr = N - 1;
            uint4 v = *(const uint4*)(Ap + (size_t)gr * 128 + koff + seg * 8);
            *(uint4*)(As + row * SA + seg * 8) = v;
        }
#pragma unroll
        for (int i = 0; i < 4; ++i) {
            int idx = i * 256 + tid;
            int row = idx >> 3, seg = idx & 7;
            uint4 v = *(const uint4*)(Bb + (size_t)row * K + kc + seg * 8);
            *(uint4*)(Bs + row * SA + seg * 8) = v;
        }
        __syncthreads();

#pragma unroll
        for (int ks = 0; ks < 64; ks += 32) {
            bf16x8 af[2], bfr[4];
#pragma unroll
            for (int rt = 0; rt < 2; ++rt)
                af[rt] = *(const bf16x8*)(As + (wr * 32 + rt * 16 + m15) * SA + ks + quad * 8);
#pragma unroll
            for (int ct = 0; ct < 4; ++ct)
                bfr[ct] = *(const bf16x8*)(Bs + (wc * 64 + ct * 16 + m15) * SA + ks + quad * 8);
#pragma unroll
            for (int rt = 0; rt < 2; ++rt)
#pragma unroll
                for (int ct = 0; ct < 4; ++ct)
                    acc[rt][ct] = __builtin_amdgcn_mfma_f32_16x16x32_bf16(
                        af[rt], bfr[ct], acc[rt][ct], 0, 0, 0);
        }
        __syncthreads();
    }

#pragma unroll
    for (int ct = 0; ct < 4; ++ct) {
        int col = wc * 64 + ct * 16 + m15;
        float bz = bias[col];
        float s = 0.f, q = 0.f;
#pragma unroll
        for (int rt = 0; rt < 2; ++rt) {
#pragma unroll
            for (int reg = 0; reg < 4; ++reg) {
                int row = r0 + wr * 32 + rt * 16 + quad * 4 + reg;
                float vv = fmaxf(acc[rt][ct][reg] + bz, 0.f);
                if (row < N) {
                    if constexpr (OUT_BF16)
                        ((unsigned short*)Yv)[(size_t)row * 128 + col] = f2bf(vv);
                    else
                        ((float*)Yv)[(size_t)row * 128 + col] = vv;
                } else {
                    vv = 0.f;
                }
                s += vv; q = fmaf(vv, vv, q);
            }
        }
        s += __shfl_xor(s, 16, 64); s += __shfl_xor(s, 32, 64);
        q += __shfl_xor(q, 16, 64); q += __shfl_xor(q, 32, 64);
        if (quad == 0) {
            atomicAdd(&bsum_s[col], s);
            atomicAdd(&bsq_s[col], q);
        }
    }
    __syncthreads();
    if (tid < 128) {
        const int slot = (bid & (NSLOT - 1)) * 128;
        atomicAdd(&sum[slot + tid],   (double)bsum_s[tid]);
        atomicAdd(&sumsq[slot + tid], (double)bsq_s[tid]);
    }
}

// ---------------------------------------------------------------------------
// bn coef body: reduce 32 slots -> bn affine coefs. t in [0,128).
static __device__ __forceinline__ void bn_coef_body(
    int t, const double* __restrict__ sum, const double* __restrict__ sumsq,
    const float* __restrict__ gamma, const float* __restrict__ beta,
    float* __restrict__ a, float* __restrict__ b, double invN)
{
    double ms = 0.0, qs = 0.0;
#pragma unroll
    for (int s = 0; s < NSLOT; ++s) {
        ms += sum[s * 128 + t];
        qs += sumsq[s * 128 + t];
    }
    float mean = (float)(ms * invN);
    float var  = (float)(qs * invN) - mean * mean;
    float sc = rsqrtf(var + BN_EPS) * gamma[t];
    a[t] = sc;
    b[t] = fmaf(-mean, sc, beta[t]);
}

__global__ __launch_bounds__(128) void bn_coef(
    const double* __restrict__ sum, const double* __restrict__ sumsq,
    const float* __restrict__ gamma, const float* __restrict__ beta,
    float* __restrict__ a, float* __restrict__ b, double invN)
{
    bn_coef_body(threadIdx.x, sum, sumsq, gamma, beta, a, b, invN);
}

// ---------------------------------------------------------------------------
// bin body: bin edges into coarse buckets of 512 dsts (int4 records).
static __device__ __forceinline__ void bin_body(
    int bid,
    const int* __restrict__ src, const int* __restrict__ dst,
    const float* __restrict__ w,
    const int* __restrict__ ccnt, int* __restrict__ gofs,
    int4* __restrict__ tmp, int E)
{
    __shared__ int hcnt[128];
    __shared__ int hbase[128];
    __shared__ int w0s;
    const int tid = threadIdx.x;
    if (tid < 128) hcnt[tid] = 0;
    __syncthreads();

    int d8[8], s8[8], slot8[8];
    float w8[8];
#pragma unroll
    for (int j = 0; j < 8; ++j) {
        int e = bid * 2048 + j * 256 + tid;
        if (e < E) {
            d8[j] = dst[e]; s8[j] = src[e]; w8[j] = w[e];
            slot8[j] = atomicAdd(&hcnt[d8[j] >> 9], 1);
        } else d8[j] = -1;
    }
    __syncthreads();
    int excl, vcnt;
    scan_ccnt(ccnt, &excl, &vcnt, &w0s);
    if (tid < 128 && hcnt[tid] > 0)
        hbase[tid] = excl + atomicAdd(&gofs[tid], hcnt[tid]);
    __syncthreads();
#pragma unroll
    for (int j = 0; j < 8; ++j) {
        if (d8[j] >= 0) {
            int pos = hbase[d8[j] >> 9] + slot8[j];
            tmp[pos] = make_int4(s8[j], __float_as_int(w8[j]), d8[j], 0);
        }
    }
}

// fatB: blocks [0,HB) bin edges; blocks [HB,HB+GB) run gemm1 -> y1b bf16.
__global__ __launch_bounds__(256) void k_bin_gemm(
    const int* __restrict__ src, const int* __restrict__ dst,
    const float* __restrict__ w,
    const int* __restrict__ ccnt, int* __restrict__ gofs,
    int4* __restrict__ tmp, int E, int HB,
    const unsigned short* __restrict__ featb,
    const unsigned short* __restrict__ Qwb, const float* __restrict__ Qb,
    unsigned short* __restrict__ y1b,
    double* __restrict__ sum, double* __restrict__ sumsq, int N)
{
    if ((int)blockIdx.x < HB)
        bin_body(blockIdx.x, src, dst, w, ccnt, gofs, tmp, E);
    else
        gemm_body<128, true>(blockIdx.x - HB, featb, featb, Qwb, Qb, y1b,
                             sum, sumsq, N);
}

// ---------------------------------------------------------------------------
// refine body: per bucket — bases from redundant ccnt scan; count per-dst in
// LDS, scan (+bucket base), write offs slice, scatter to epack in dst order.
static __device__ __forceinline__ void refine_body(
    int b,
    const int4* __restrict__ tmp, const int* __restrict__ ccnt,
    int* __restrict__ offs, int2* __restrict__ epack, int N)
{
    __shared__ int hist[512];
    __shared__ int wpre[4];
    __shared__ int w0s;
    __shared__ int sbounds[2];
    const int d0   = b << 9;
    const int dlim = min(512, N - d0);
    const int tid  = threadIdx.x;
    const int lane = tid & 63, wv = tid >> 6;

    hist[tid] = 0; hist[tid + 256] = 0;
    __syncthreads();
    int excl, vcnt;
    scan_ccnt(ccnt, &excl, &vcnt, &w0s);
    if (tid == b) { sbounds[0] = excl; sbounds[1] = excl + vcnt; }
    __syncthreads();
    const int start = sbounds[0];
    const int end   = sbounds[1];

    for (int p = start + tid; p < end; p += 256)
        atomicAdd(&hist[tmp[p].z - d0], 1);
    __syncthreads();

    int v0 = hist[2 * tid], v1 = hist[2 * tid + 1];
    int s = v0 + v1;
    int incl = s;
#pragma unroll
    for (int o = 1; o < 64; o <<= 1) {
        int t = __shfl_up(incl, o, 64);
        if (lane >= o) incl += t;
    }
    if (lane == 63) wpre[wv] = incl;
    __syncthreads();
    if (tid == 0) {
        int r = 0;
#pragma unroll
        for (int i = 0; i < 4; ++i) { int t = wpre[i]; wpre[i] = r; r += t; }
    }
    __syncthreads();
    int e0 = start + wpre[wv] + incl - s;
    if (2 * tid < dlim)     offs[d0 + 2 * tid]     = e0;
    if (2 * tid + 1 < dlim) offs[d0 + 2 * tid + 1] = e0 + v0;
    hist[2 * tid]     = e0;
    hist[2 * tid + 1] = e0 + v0;
    __syncthreads();

    for (int p = start + tid; p < end; p += 256) {
        int4 rec = tmp[p];
        int pos = atomicAdd(&hist[rec.z - d0], 1);
        epack[pos] = make_int2(rec.x, rec.y);
    }
}

// fat: block 0 = bn_coef1 reduce; blocks [1,NB] = refine buckets.
__global__ __launch_bounds__(256) void k_bnref(
    const double* __restrict__ sum, const double* __restrict__ sumsq,
    const float* __restrict__ gamma, const float* __restrict__ beta,
    float* __restrict__ a, float* __restrict__ b, double invN,
    const int4* __restrict__ tmp, const int* __restrict__ ccnt,
    int* __restrict__ offs, int2* __restrict__ epack, int N)
{
    if (blockIdx.x == 0) {
        if (threadIdx.x < 128)
            bn_coef_body(threadIdx.x, sum, sumsq, gamma, beta, a, b, invN);
        return;
    }
    refine_body((int)blockIdx.x - 1, tmp, ccnt, offs, epack, N);
}

// ---------------------------------------------------------------------------
// One wave per dst row; 16 lanes/edge, uint4 (16B) loads, 4 edges per load
// round (8 with 2-deep unroll). Reads raw relu y1b; applies bn affine (a,b)
// to the weighted mean (or own row when den==0). Writes agg bf16.
__global__ __launch_bounds__(256) void gather_agg(
    const unsigned short* __restrict__ y1b,
    const int* __restrict__ offs, const int2* __restrict__ epack,
    const float* __restrict__ a, const float* __restrict__ b,
    unsigned short* __restrict__ aggb, int N)
{
    const int r    = (int)((blockIdx.x * 256u + threadIdx.x) >> 6);
    const int lane = threadIdx.x & 63;
    const int li   = lane & 15;     // owns columns 8*li .. 8*li+7
    const int hf   = lane >> 4;     // edge slot in quad (0..3)
    if (r >= N) return;
    int p = offs[r];
    const int end = offs[r + 1];
    const int c = 8 * li;
    float ac0 = 0.f, ac1 = 0.f, ac2 = 0.f, ac3 = 0.f;
    float ac4 = 0.f, ac5 = 0.f, ac6 = 0.f, ac7 = 0.f;
    float den = 0.f;
    for (; p + 7 < end; p += 8) {
        int2 e0 = epack[p + hf];
        int2 e1 = epack[p + 4 + hf];
        uint4 u0 = *(const uint4*)(y1b + (size_t)e0.x * 128 + c);
        uint4 u1 = *(const uint4*)(y1b + (size_t)e1.x * 128 + c);
        float w0 = __int_as_float(e0.y), w1 = __int_as_float(e1.y);
        ac0 = fmaf(w0, bf_lo(u0.x), ac0); ac1 = fmaf(w0, bf_hi(u0.x), ac1);
        ac2 = fmaf(w0, bf_lo(u0.y), ac2); ac3 = fmaf(w0, bf_hi(u0.y), ac3);
        ac4 = fmaf(w0, bf_lo(u0.z), ac4); ac5 = fmaf(w0, bf_hi(u0.z), ac5);
        ac6 = fmaf(w0, bf_lo(u0.w), ac6); ac7 = fmaf(w0, bf_hi(u0.w), ac7);
        ac0 = fmaf(w1, bf_lo(u1.x), ac0); ac1 = fmaf(w1, bf_hi(u1.x), ac1);
        ac2 = fmaf(w1, bf_lo(u1.y), ac2); ac3 = fmaf(w1, bf_hi(u1.y), ac3);
        ac4 = fmaf(w1, bf_lo(u1.z), ac4); ac5 = fmaf(w1, bf_hi(u1.z), ac5);
        ac6 = fmaf(w1, bf_lo(u1.w), ac6); ac7 = fmaf(w1, bf_hi(u1.w), ac7);
        den += w0 + w1;
    }
    for (; p < end; p += 4) {
        if (p + hf < end) {
            int2 e0 = epack[p + hf];
            uint4 u0 = *(const uint4*)(y1b + (size_t)e0.x * 128 + c);
            float w0 = __int_as_float(e0.y);
            ac0 = fmaf(w0, bf_lo(u0.x), ac0); ac1 = fmaf(w0, bf_hi(u0.x), ac1);
            ac2 = fmaf(w0, bf_lo(u0.y), ac2); ac3 = fmaf(w0, bf_hi(u0.y), ac3);
            ac4 = fmaf(w0, bf_lo(u0.z), ac4); ac5 = fmaf(w0, bf_hi(u0.z), ac5);
            ac6 = fmaf(w0, bf_lo(u0.w), ac6); ac7 = fmaf(w0, bf_hi(u0.w), ac7);
            den += w0;
        }
    }
    // sum the 4 edge-groups (lane bits 4,5); li (lane&15) invariant
    ac0 += __shfl_xor(ac0, 16, 64); ac0 += __shfl_xor(ac0, 32, 64);
    ac1 += __shfl_xor(ac1, 16, 64); ac1 += __shfl_xor(ac1, 32, 64);
    ac2 += __shfl_xor(ac2, 16, 64); ac2 += __shfl_xor(ac2, 32, 64);
    ac3 += __shfl_xor(ac3, 16, 64); ac3 += __shfl_xor(ac3, 32, 64);
    ac4 += __shfl_xor(ac4, 16, 64); ac4 += __shfl_xor(ac4, 32, 64);
    ac5 += __shfl_xor(ac5, 16, 64); ac5 += __shfl_xor(ac5, 32, 64);
    ac6 += __shfl_xor(ac6, 16, 64); ac6 += __shfl_xor(ac6, 32, 64);
    ac7 += __shfl_xor(ac7, 16, 64); ac7 += __shfl_xor(ac7, 32, 64);
    den += __shfl_xor(den, 16, 64); den += __shfl_xor(den, 32, 64);
    if (hf) return;
    float4 av0 = *(const float4*)(a + c);
    float4 av1 = *(const float4*)(a + c + 4);
    float4 bv0 = *(const float4*)(b + c);
    float4 bv1 = *(const float4*)(b + c + 4);
    float m0, m1, m2, m3, m4, m5, m6, m7;
    if (den != 0.f) {
        float inv = 1.f / den;
        m0 = ac0 * inv; m1 = ac1 * inv; m2 = ac2 * inv; m3 = ac3 * inv;
        m4 = ac4 * inv; m5 = ac5 * inv; m6 = ac6 * inv; m7 = ac7 * inv;
    } else {
        uint4 u = *(const uint4*)(y1b + (size_t)r * 128 + c);
        m0 = bf_lo(u.x); m1 = bf_hi(u.x); m2 = bf_lo(u.y); m3 = bf_hi(u.y);
        m4 = bf_lo(u.z); m5 = bf_hi(u.z); m6 = bf_lo(u.w); m7 = bf_hi(u.w);
    }
    uint4 o;
    o.x = (uint32_t)f2bf(fmaf(av0.x, m0, bv0.x))
        | ((uint32_t)f2bf(fmaf(av0.y, m1, bv0.y)) << 16);
    o.y = (uint32_t)f2bf(fmaf(av0.z, m2, bv0.z))
        | ((uint32_t)f2bf(fmaf(av0.w, m3, bv0.w)) << 16);
    o.z = (uint32_t)f2bf(fmaf(av1.x, m4, bv1.x))
        | ((uint32_t)f2bf(fmaf(av1.y, m5, bv1.y)) << 16);
    o.w = (uint32_t)f2bf(fmaf(av1.z, m6, bv1.z))
        | ((uint32_t)f2bf(fmaf(av1.w, m7, bv1.w)) << 16);
    *(uint4*)(aggb + (size_t)r * 128 + c) = o;
}

// ---------------------------------------------------------------------------
// gemm2 standalone (K=256, A = [featb|aggb], 128x128 tile) -> y2 f32 + stats2.
// Staging via global_load_lds (width 16), linear LDS + XOR chunk swizzle:
// LDS[row][slot] holds global chunk slot^(row&7); reads use chunk^(row&7).
__global__ __launch_bounds__(256) void gemm_bn2(
    const unsigned short* __restrict__ A_lo,
    const unsigned short* __restrict__ A_hi,
    const unsigned short* __restrict__ Bb,
    const float* __restrict__ bias,
    float* __restrict__ Y,
    double* __restrict__ sum, double* __restrict__ sumsq, int N)
{
    constexpr int K = 256;
    __shared__ unsigned short As[128 * 64];   // linear [128][64], swizzled
    __shared__ unsigned short Bs[128 * 64];
    __shared__ float bsum_s[128], bsq_s[128];

    const int tid  = threadIdx.x;
    const int lane = tid & 63;
    const int wv   = tid >> 6;
    const int wr   = wv >> 1;
    const int wc   = wv & 1;
    const int m15  = lane & 15;
    const int quad = lane >> 4;
    const int r0   = (int)blockIdx.x * 128;

    if (tid < 128) { bsum_s[tid] = 0.f; bsq_s[tid] = 0.f; }

    const int lrow8 = lane >> 3;               // row within 8-row group
    const int ch    = (lane & 7) ^ lrow8;      // swizzled source chunk

    f32x4 acc[4][4];
#pragma unroll
    for (int rt = 0; rt < 4; ++rt)
#pragma unroll
        for (int ct = 0; ct < 4; ++ct)
            acc[rt][ct] = (f32x4){0.f, 0.f, 0.f, 0.f};

    for (int kc = 0; kc < K; kc += 64) {
        const unsigned short* Ap = (kc < 128) ? A_lo : A_hi;
        const int koff = kc & 127;
        // A tile: 16 gload_lds of 1KB (8 rows each); wave wv -> groups wv*4..+3
#pragma unroll
        for (int jj = 0; jj < 4; ++jj) {
            int j = wv * 4 + jj;
            int row = j * 8 + lrow8;
            int gr  = r0 + row; if (gr >= N) gr = N - 1;
            GLDS16(Ap + (size_t)gr * 128 + koff + ch * 8, As + j * 512);
        }
        // B tile: same structure, source Bb[row][kc + ch*8]
#pragma unroll
        for (int jj = 0; jj < 4; ++jj) {
            int j = wv * 4 + jj;
            int row = j * 8 + lrow8;
            GLDS16(Bb + (size_t)row * K + kc + ch * 8, Bs + j * 512);
        }
        __syncthreads();

#pragma unroll
        for (int ks = 0; ks < 64; ks += 32) {
            const int chunk = quad + (ks >> 3);      // ks=32 -> +4
            bf16x8 af[4], bfr[4];
#pragma unroll
            for (int rt = 0; rt < 4; ++rt) {
                int arow = wr * 64 + rt * 16 + m15;
                af[rt] = *(const bf16x8*)(As + arow * 64 + ((chunk ^ (arow & 7)) * 8));
            }
#pragma unroll
            for (int ct = 0; ct < 4; ++ct) {
                int brow = wc * 64 + ct * 16 + m15;
                bfr[ct] = *(const bf16x8*)(Bs + brow * 64 + ((chunk ^ (brow & 7)) * 8));
            }
#pragma unroll
            for (int rt = 0; rt < 4; ++rt)
#pragma unroll
                for (int ct = 0; ct < 4; ++ct)
                    acc[rt][ct] = __builtin_amdgcn_mfma_f32_16x16x32_bf16(
                        af[rt], bfr[ct], acc[rt][ct], 0, 0, 0);
        }
        __syncthreads();
    }

#pragma unroll
    for (int ct = 0; ct < 4; ++ct) {
        int col = wc * 64 + ct * 16 + m15;
        float bz = bias[col];
        float s = 0.f, q = 0.f;
#pragma unroll
        for (int rt = 0; rt < 4; ++rt) {
#pragma unroll
            for (int reg = 0; reg < 4; ++reg) {
                int row = r0 + wr * 64 + rt * 16 + quad * 4 + reg;
                float vv = fmaxf(acc[rt][ct][reg] + bz, 0.f);
                if (row < N) {
                    Y[(size_t)row * 128 + col] = vv;
                } else {
                    vv = 0.f;
                }
                s += vv; q = fmaf(vv, vv, q);
            }
        }
        s += __shfl_xor(s, 16, 64); s += __shfl_xor(s, 32, 64);
        q += __shfl_xor(q, 16, 64); q += __shfl_xor(q, 32, 64);
        if (quad == 0) {
            atomicAdd(&bsum_s[col], s);
            atomicAdd(&bsq_s[col], q);
        }
    }
    __syncthreads();
    if (tid < 128) {
        const int slot = ((int)blockIdx.x & (NSLOT - 1)) * 128;
        atomicAdd(&sum[slot + tid],   (double)bsum_s[tid]);
        atomicAdd(&sumsq[slot + tid], (double)bsq_s[tid]);
    }
}

// ---------------------------------------------------------------------------
// bn2 affine (precomputed coefs) + row L2 normalize.
__global__ __launch_bounds__(256) void finalize(
    const float* __restrict__ Y2,
    const float* __restrict__ a, const float* __restrict__ b,
    float* __restrict__ out, int N)
{
    __shared__ float sa[128], sb[128];
    const int t = threadIdx.x;
    if (t < 128) { sa[t] = a[t]; sb[t] = b[t]; }
    __syncthreads();
    const int row  = (int)((blockIdx.x * 256u + t) >> 6);
    const int lane = t & 63;
    if (row >= N) return;
    const size_t base = (size_t)row * 128;
    float v0 = fmaf(sa[lane],      Y2[base + lane],      sb[lane]);
    float v1 = fmaf(sa[lane + 64], Y2[base + lane + 64], sb[lane + 64]);
    float ss = fmaf(v0, v0, v1 * v1);
#pragma unroll
    for (int o = 32; o; o >>= 1) ss += __shfl_xor(ss, o, 64);
    float nrm = sqrtf(ss);
    float inv = (nrm == 0.f) ? 1.f : 1.f / nrm;
    out[base + lane]      = v0 * inv;
    out[base + lane + 64] = v1 * inv;
}

// ---------------------------------------------------------------------------
extern "C" void kernel_launch(void* const* d_in, const int* in_sizes, int n_in,
                              void* d_out, int out_size, void* d_ws, size_t ws_size,
                              hipStream_t stream)
{
    const float* feat   = (const float*)d_in[0];
    const float* w      = (const float*)d_in[1];
    const float* Q_w    = (const float*)d_in[2];
    const float* Q_b    = (const float*)d_in[3];
    const float* W_w    = (const float*)d_in[4];
    const float* W_b    = (const float*)d_in[5];
    const float* gamma2 = (const float*)d_in[6];
    const float* beta2  = (const float*)d_in[7];
    const int*   src    = (const int*)d_in[8];
    const int*   dst    = (const int*)d_in[9];

    const int N = in_sizes[0] / 128;   // 50000
    const int E = in_sizes[1];         // 800000

    // workspace layout
    float*          y2    = (float*)d_ws;                            // N*128 f32
    unsigned short* featb = (unsigned short*)(y2 + (size_t)N * 128); // N*128 bf16
    unsigned short* aggb  = featb + (size_t)N * 128;                 // N*128 bf16
    unsigned short* y1b   = aggb + (size_t)N * 128;                  // N*128 bf16
    int4*  tmp    = (int4*)(y1b + (size_t)N * 128);                  // E (16B aligned)
    int2*  epack  = (int2*)(tmp + E);                                // E
    int*   offs   = (int*)(epack + E);                               // N+1
    float* coefs  = (float*)(offs + N + 1);                          // 512
    float* a1 = coefs, *b1 = coefs + 128, *a2 = coefs + 256, *b2 = coefs + 384;
    uintptr_t qp = ((uintptr_t)(coefs + 512) + 15) & ~(uintptr_t)15;
    unsigned short* Qwb = (unsigned short*)qp;                       // 128*128 bf16
    unsigned short* Wwb = Qwb + 128 * 128;                           // 128*256 bf16
    uintptr_t sp = ((uintptr_t)(Wwb + 128 * 256) + 15) & ~(uintptr_t)15;
    double* stats = (double*)sp;                                     // 4*NSLOT*128 <- zeroed in k_pre
    double* sum1   = stats;
    double* sumsq1 = stats + NSLOT * 128;
    double* sum2   = stats + 2 * NSLOT * 128;
    double* sumsq2 = stats + 3 * NSLOT * 128;
    int*   ccnt   = (int*)(stats + 4 * NSLOT * 128);                 // 128 <- zeroed
    int*   gofs   = ccnt + 128;                                      // 128 <- zeroed

    hipMemsetAsync(ccnt, 0, 256 * sizeof(int), stream);

    const double invN = 1.0 / (double)N;
    const int GB  = (N + 63) / 64;              // gemm1 blocks (782)
    const int GB2 = (N + 127) / 128;            // gemm2 blocks (391)
    const int NB = (N + 511) >> 9;              // coarse buckets (98)
    const int CB = (N * 128 / 4 + 255) / 256;   // feat cast blocks
    const int HB = (E + 2047) / 2048;           // histogram/bin blocks
    const int QB = 16;                          // Q_w cast blocks
    const int WB = 32;                          // W_w cast blocks
    const int ZB = 32;                          // stats-zero blocks (128KB)

    k_pre<<<CB + HB + QB + WB + ZB, 256, 0, stream>>>(
        feat, featb, N * 128, dst, ccnt, E, CB, HB,
        Q_w, Qwb, W_w, Wwb, offs, N, stats);

    // fatB: bin || gemm1 -> y1b bf16 + stats1 (bases via in-block ccnt scan)
    k_bin_gemm<<<HB + GB, 256, 0, stream>>>(
        src, dst, w, ccnt, gofs, tmp, E, HB,
        featb, Qwb, Q_b, y1b, sum1, sumsq1, N);

    // fat: bn_coef1 (block 0) || refine (blocks 1..NB)
    k_bnref<<<NB + 1, 256, 0, stream>>>(
        sum1, sumsq1, gamma2, beta2, a1, b1, invN,
        tmp, ccnt, offs, epack, N);

    gather_agg<<<(N * 64 + 255) / 256, 256, 0, stream>>>(
        y1b, offs, epack, a1, b1, aggb, N);

    gemm_bn2<<<GB2, 256, 0, stream>>>(
        featb, aggb, Wwb, W_b, y2, sum2, sumsq2, N);

    bn_coef<<<1, 128, 0, stream>>>(sum2, sumsq2, gamma2, beta2, a2, b2, invN);
    finalize<<<(N * 64 + 255) / 256, 256, 0, stream>>>(
        y2, a2, b2, (float*)d_out, N);
}

// Round 11
// 220.767 us; speedup vs baseline: 1.3616x; 1.0056x over previous
//
#include <hip/hip_runtime.h>
#include <stdint.h>

// PinConv pipeline, round 21 (base = round 20, 222.0us best):
//  - gemm1 (inside fatB) staging ported to global_load_lds width-16 + XOR
//    chunk swizzle (the round-20-verified pattern), keeping the 64x128 tile.
//    Fat kernel static LDS 30.2KB -> ~25.6KB => both branches 5 -> 6
//    blocks/CU; bin branch (latency-bound) gains TLP. Bit-identical math.
//  - everything else identical to round 20.

#define BN_EPS 1e-5f
#define NSLOT 32

typedef __attribute__((ext_vector_type(8))) short bf16x8;
typedef __attribute__((ext_vector_type(4))) float f32x4;

#define GLDS16(g, l) __builtin_amdgcn_global_load_lds( \
    (__attribute__((address_space(1))) void*)(g), \
    (__attribute__((address_space(3))) void*)(l), 16, 0, 0)

static __device__ __forceinline__ unsigned short f2bf(float f) {
    uint32_t u = __builtin_bit_cast(uint32_t, f);
    u += 0x7fffu + ((u >> 16) & 1u);          // round-to-nearest-even
    return (unsigned short)(u >> 16);
}
static __device__ __forceinline__ float bf_lo(uint32_t u) {
    return __builtin_bit_cast(float, u << 16);
}
static __device__ __forceinline__ float bf_hi(uint32_t u) {
    return __builtin_bit_cast(float, u & 0xffff0000u);
}

static __device__ __forceinline__ void cast_blk(
    const float* __restrict__ src, unsigned short* __restrict__ dst,
    int n, int blk)
{
    int i = (blk * 256 + threadIdx.x) * 4;
    if (i + 3 < n) {
        float4 v = *(const float4*)(src + i);
        ushort4 o;
        o.x = f2bf(v.x); o.y = f2bf(v.y); o.z = f2bf(v.z); o.w = f2bf(v.w);
        *(ushort4*)(dst + i) = o;
    } else {
        for (int j = i; j < n; ++j) dst[j] = f2bf(src[j]);
    }
}

// Redundant per-block exclusive scan of ccnt[128].
static __device__ __forceinline__ void scan_ccnt(
    const int* __restrict__ ccnt, int* excl_out, int* v_out, int* w0s)
{
    const int t = threadIdx.x;
    int v = 0, incl = 0;
    if (t < 128) {
        v = ccnt[t];
        incl = v;
        const int lane = t & 63;
#pragma unroll
        for (int o = 1; o < 64; o <<= 1) {
            int u = __shfl_up(incl, o, 64);
            if (lane >= o) incl += u;
        }
        if (t == 63) *w0s = incl;
    }
    __syncthreads();
    int excl = 0;
    if (t < 128) excl = incl - v + ((t >> 6) ? *w0s : 0);
    *excl_out = excl;
    *v_out = v;
}

// ---------------------------------------------------------------------------
// Fused: blocks [0,CB) cast feat; [CB,CB+HB) coarse-histogram dst;
// [CB+HB, CB+HB+QB+WB) cast Q_w/W_w; remaining ZB blocks zero stats.
__global__ __launch_bounds__(256) void k_pre(
    const float* __restrict__ feat, unsigned short* __restrict__ featb, int nf,
    const int* __restrict__ dst, int* __restrict__ ccnt, int E, int CB, int HB,
    const float* __restrict__ Qw, unsigned short* __restrict__ Qwb,
    const float* __restrict__ Ww, unsigned short* __restrict__ Wwb,
    int* __restrict__ offs, int N, double* __restrict__ stats)
{
    int b = (int)blockIdx.x;
    if (b < CB) {
        if (b == 0 && threadIdx.x == 0) offs[N] = E;
        cast_blk(feat, featb, nf, b);
        return;
    }
    b -= CB;
    if (b >= HB) {
        b -= HB;
        if (b < 16) { cast_blk(Qw, Qwb, 128 * 128, b); return; }
        b -= 16;
        if (b < 32) { cast_blk(Ww, Wwb, 128 * 256, b); return; }
        b -= 32;
        // zero stats: 32 blocks x 256 threads x 16B = 128 KB
        uint4* p = (uint4*)stats;
        p[b * 256 + threadIdx.x] = make_uint4(0u, 0u, 0u, 0u);
        return;
    }
    __shared__ int hcnt[128];
    const int tid = threadIdx.x;
    if (tid < 128) hcnt[tid] = 0;
    __syncthreads();
    const int base_e = b * 2048;
#pragma unroll
    for (int j = 0; j < 8; ++j) {
        int e = base_e + j * 256 + tid;
        if (e < E) atomicAdd(&hcnt[dst[e] >> 9], 1);
    }
    __syncthreads();
    if (tid < 128 && hcnt[tid] > 0) atomicAdd(&ccnt[tid], hcnt[tid]);
}

// ---------------------------------------------------------------------------
// GEMM1 body (64x128 tile, gload_lds staging + XOR chunk swizzle):
// Y = relu(A @ B^T + bias) -> bf16. A = featb (K=128), B = Qwb [128][128].
static __device__ __forceinline__ void gemm1_body(
    int bid,
    const unsigned short* __restrict__ A,
    const unsigned short* __restrict__ Bb,
    const float* __restrict__ bias,
    unsigned short* __restrict__ Y,
    double* __restrict__ sum, double* __restrict__ sumsq, int N)
{
    __shared__ unsigned short As[64 * 64];    // linear [64][64], swizzled
    __shared__ unsigned short Bs[128 * 64];
    __shared__ float bsum_s[128], bsq_s[128];

    const int tid  = threadIdx.x;
    const int lane = tid & 63;
    const int wv   = tid >> 6;
    const int wr   = wv >> 1;
    const int wc   = wv & 1;
    const int m15  = lane & 15;
    const int quad = lane >> 4;
    const int r0   = bid * 64;

    if (tid < 128) { bsum_s[tid] = 0.f; bsq_s[tid] = 0.f; }

    const int lrow8 = lane >> 3;               // row within 8-row group
    const int ch    = (lane & 7) ^ lrow8;      // swizzled source chunk

    f32x4 acc[2][4];
#pragma unroll
    for (int rt = 0; rt < 2; ++rt)
#pragma unroll
        for (int ct = 0; ct < 4; ++ct)
            acc[rt][ct] = (f32x4){0.f, 0.f, 0.f, 0.f};

    for (int kc = 0; kc < 128; kc += 64) {
        // A tile: 8 groups of 8 rows (1KB each); wave wv -> groups wv*2..+1
#pragma unroll
        for (int jj = 0; jj < 2; ++jj) {
            int j = wv * 2 + jj;
            int row = j * 8 + lrow8;
            int gr  = r0 + row; if (gr >= N) gr = N - 1;
            GLDS16(A + (size_t)gr * 128 + kc + ch * 8, As + j * 512);
        }
        // B tile: 16 groups; wave wv -> groups wv*4..+3
#pragma unroll
        for (int jj = 0; jj < 4; ++jj) {
            int j = wv * 4 + jj;
            int row = j * 8 + lrow8;
            GLDS16(Bb + (size_t)row * 128 + kc + ch * 8, Bs + j * 512);
        }
        __syncthreads();

#pragma unroll
        for (int ks = 0; ks < 64; ks += 32) {
            const int chunk = quad + (ks >> 3);      // ks=32 -> +4
            bf16x8 af[2], bfr[4];
#pragma unroll
            for (int rt = 0; rt < 2; ++rt) {
                int arow = wr * 32 + rt * 16 + m15;
                af[rt] = *(const bf16x8*)(As + arow * 64 + ((chunk ^ (arow & 7)) * 8));
            }
#pragma unroll
            for (int ct = 0; ct < 4; ++ct) {
                int brow = wc * 64 + ct * 16 + m15;
                bfr[ct] = *(const bf16x8*)(Bs + brow * 64 + ((chunk ^ (brow & 7)) * 8));
            }
#pragma unroll
            for (int rt = 0; rt < 2; ++rt)
#pragma unroll
                for (int ct = 0; ct < 4; ++ct)
                    acc[rt][ct] = __builtin_amdgcn_mfma_f32_16x16x32_bf16(
                        af[rt], bfr[ct], acc[rt][ct], 0, 0, 0);
        }
        __syncthreads();
    }

#pragma unroll
    for (int ct = 0; ct < 4; ++ct) {
        int col = wc * 64 + ct * 16 + m15;
        float bz = bias[col];
        float s = 0.f, q = 0.f;
#pragma unroll
        for (int rt = 0; rt < 2; ++rt) {
#pragma unroll
            for (int reg = 0; reg < 4; ++reg) {
                int row = r0 + wr * 32 + rt * 16 + quad * 4 + reg;
                float vv = fmaxf(acc[rt][ct][reg] + bz, 0.f);
                if (row < N) {
                    Y[(size_t)row * 128 + col] = f2bf(vv);
                } else {
                    vv = 0.f;
                }
                s += vv; q = fmaf(vv, vv, q);
            }
        }
        s += __shfl_xor(s, 16, 64); s += __shfl_xor(s, 32, 64);
        q += __shfl_xor(q, 16, 64); q += __shfl_xor(q, 32, 64);
        if (quad == 0) {
            atomicAdd(&bsum_s[col], s);
            atomicAdd(&bsq_s[col], q);
        }
    }
    __syncthreads();
    if (tid < 128) {
        const int slot = (bid & (NSLOT - 1)) * 128;
        atomicAdd(&sum[slot + tid],   (double)bsum_s[tid]);
        atomicAdd(&sumsq[slot + tid], (double)bsq_s[tid]);
    }
}

// ---------------------------------------------------------------------------
// bn coef body: reduce 32 slots -> bn affine coefs. t in [0,128).
static __device__ __forceinline__ void bn_coef_body(
    int t, const double* __restrict__ sum, const double* __restrict__ sumsq,
    const float* __restrict__ gamma, const float* __restrict__ beta,
    float* __restrict__ a, float* __restrict__ b, double invN)
{
    double ms = 0.0, qs = 0.0;
#pragma unroll
    for (int s = 0; s < NSLOT; ++s) {
        ms += sum[s * 128 + t];
        qs += sumsq[s * 128 + t];
    }
    float mean = (float)(ms * invN);
    float var  = (float)(qs * invN) - mean * mean;
    float sc = rsqrtf(var + BN_EPS) * gamma[t];
    a[t] = sc;
    b[t] = fmaf(-mean, sc, beta[t]);
}

__global__ __launch_bounds__(128) void bn_coef(
    const double* __restrict__ sum, const double* __restrict__ sumsq,
    const float* __restrict__ gamma, const float* __restrict__ beta,
    float* __restrict__ a, float* __restrict__ b, double invN)
{
    bn_coef_body(threadIdx.x, sum, sumsq, gamma, beta, a, b, invN);
}

// ---------------------------------------------------------------------------
// bin body: bin edges into coarse buckets of 512 dsts (int4 records).
static __device__ __forceinline__ void bin_body(
    int bid,
    const int* __restrict__ src, const int* __restrict__ dst,
    const float* __restrict__ w,
    const int* __restrict__ ccnt, int* __restrict__ gofs,
    int4* __restrict__ tmp, int E)
{
    __shared__ int hcnt[128];
    __shared__ int hbase[128];
    __shared__ int w0s;
    const int tid = threadIdx.x;
    if (tid < 128) hcnt[tid] = 0;
    __syncthreads();

    int d8[8], s8[8], slot8[8];
    float w8[8];
#pragma unroll
    for (int j = 0; j < 8; ++j) {
        int e = bid * 2048 + j * 256 + tid;
        if (e < E) {
            d8[j] = dst[e]; s8[j] = src[e]; w8[j] = w[e];
            slot8[j] = atomicAdd(&hcnt[d8[j] >> 9], 1);
        } else d8[j] = -1;
    }
    __syncthreads();
    int excl, vcnt;
    scan_ccnt(ccnt, &excl, &vcnt, &w0s);
    if (tid < 128 && hcnt[tid] > 0)
        hbase[tid] = excl + atomicAdd(&gofs[tid], hcnt[tid]);
    __syncthreads();
#pragma unroll
    for (int j = 0; j < 8; ++j) {
        if (d8[j] >= 0) {
            int pos = hbase[d8[j] >> 9] + slot8[j];
            tmp[pos] = make_int4(s8[j], __float_as_int(w8[j]), d8[j], 0);
        }
    }
}

// fatB: blocks [0,HB) bin edges; blocks [HB,HB+GB) run gemm1 -> y1b bf16.
__global__ __launch_bounds__(256) void k_bin_gemm(
    const int* __restrict__ src, const int* __restrict__ dst,
    const float* __restrict__ w,
    const int* __restrict__ ccnt, int* __restrict__ gofs,
    int4* __restrict__ tmp, int E, int HB,
    const unsigned short* __restrict__ featb,
    const unsigned short* __restrict__ Qwb, const float* __restrict__ Qb,
    unsigned short* __restrict__ y1b,
    double* __restrict__ sum, double* __restrict__ sumsq, int N)
{
    if ((int)blockIdx.x < HB)
        bin_body(blockIdx.x, src, dst, w, ccnt, gofs, tmp, E);
    else
        gemm1_body(blockIdx.x - HB, featb, Qwb, Qb, y1b, sum, sumsq, N);
}

// ---------------------------------------------------------------------------
// refine body: per bucket — bases from redundant ccnt scan; count per-dst in
// LDS, scan (+bucket base), write offs slice, scatter to epack in dst order.
static __device__ __forceinline__ void refine_body(
    int b,
    const int4* __restrict__ tmp, const int* __restrict__ ccnt,
    int* __restrict__ offs, int2* __restrict__ epack, int N)
{
    __shared__ int hist[512];
    __shared__ int wpre[4];
    __shared__ int w0s;
    __shared__ int sbounds[2];
    const int d0   = b << 9;
    const int dlim = min(512, N - d0);
    const int tid  = threadIdx.x;
    const int lane = tid & 63, wv = tid >> 6;

    hist[tid] = 0; hist[tid + 256] = 0;
    __syncthreads();
    int excl, vcnt;
    scan_ccnt(ccnt, &excl, &vcnt, &w0s);
    if (tid == b) { sbounds[0] = excl; sbounds[1] = excl + vcnt; }
    __syncthreads();
    const int start = sbounds[0];
    const int end   = sbounds[1];

    for (int p = start + tid; p < end; p += 256)
        atomicAdd(&hist[tmp[p].z - d0], 1);
    __syncthreads();

    int v0 = hist[2 * tid], v1 = hist[2 * tid + 1];
    int s = v0 + v1;
    int incl = s;
#pragma unroll
    for (int o = 1; o < 64; o <<= 1) {
        int t = __shfl_up(incl, o, 64);
        if (lane >= o) incl += t;
    }
    if (lane == 63) wpre[wv] = incl;
    __syncthreads();
    if (tid == 0) {
        int r = 0;
#pragma unroll
        for (int i = 0; i < 4; ++i) { int t = wpre[i]; wpre[i] = r; r += t; }
    }
    __syncthreads();
    int e0 = start + wpre[wv] + incl - s;
    if (2 * tid < dlim)     offs[d0 + 2 * tid]     = e0;
    if (2 * tid + 1 < dlim) offs[d0 + 2 * tid + 1] = e0 + v0;
    hist[2 * tid]     = e0;
    hist[2 * tid + 1] = e0 + v0;
    __syncthreads();

    for (int p = start + tid; p < end; p += 256) {
        int4 rec = tmp[p];
        int pos = atomicAdd(&hist[rec.z - d0], 1);
        epack[pos] = make_int2(rec.x, rec.y);
    }
}

// fat: block 0 = bn_coef1 reduce; blocks [1,NB] = refine buckets.
__global__ __launch_bounds__(256) void k_bnref(
    const double* __restrict__ sum, const double* __restrict__ sumsq,
    const float* __restrict__ gamma, const float* __restrict__ beta,
    float* __restrict__ a, float* __restrict__ b, double invN,
    const int4* __restrict__ tmp, const int* __restrict__ ccnt,
    int* __restrict__ offs, int2* __restrict__ epack, int N)
{
    if (blockIdx.x == 0) {
        if (threadIdx.x < 128)
            bn_coef_body(threadIdx.x, sum, sumsq, gamma, beta, a, b, invN);
        return;
    }
    refine_body((int)blockIdx.x - 1, tmp, ccnt, offs, epack, N);
}

// ---------------------------------------------------------------------------
// One wave per dst row; 16 lanes/edge, uint4 (16B) loads, 4 edges per load
// round (8 with 2-deep unroll). Reads raw relu y1b; applies bn affine (a,b)
// to the weighted mean (or own row when den==0). Writes agg bf16.
__global__ __launch_bounds__(256) void gather_agg(
    const unsigned short* __restrict__ y1b,
    const int* __restrict__ offs, const int2* __restrict__ epack,
    const float* __restrict__ a, const float* __restrict__ b,
    unsigned short* __restrict__ aggb, int N)
{
    const int r    = (int)((blockIdx.x * 256u + threadIdx.x) >> 6);
    const int lane = threadIdx.x & 63;
    const int li   = lane & 15;     // owns columns 8*li .. 8*li+7
    const int hf   = lane >> 4;     // edge slot in quad (0..3)
    if (r >= N) return;
    int p = offs[r];
    const int end = offs[r + 1];
    const int c = 8 * li;
    float ac0 = 0.f, ac1 = 0.f, ac2 = 0.f, ac3 = 0.f;
    float ac4 = 0.f, ac5 = 0.f, ac6 = 0.f, ac7 = 0.f;
    float den = 0.f;
    for (; p + 7 < end; p += 8) {
        int2 e0 = epack[p + hf];
        int2 e1 = epack[p + 4 + hf];
        uint4 u0 = *(const uint4*)(y1b + (size_t)e0.x * 128 + c);
        uint4 u1 = *(const uint4*)(y1b + (size_t)e1.x * 128 + c);
        float w0 = __int_as_float(e0.y), w1 = __int_as_float(e1.y);
        ac0 = fmaf(w0, bf_lo(u0.x), ac0); ac1 = fmaf(w0, bf_hi(u0.x), ac1);
        ac2 = fmaf(w0, bf_lo(u0.y), ac2); ac3 = fmaf(w0, bf_hi(u0.y), ac3);
        ac4 = fmaf(w0, bf_lo(u0.z), ac4); ac5 = fmaf(w0, bf_hi(u0.z), ac5);
        ac6 = fmaf(w0, bf_lo(u0.w), ac6); ac7 = fmaf(w0, bf_hi(u0.w), ac7);
        ac0 = fmaf(w1, bf_lo(u1.x), ac0); ac1 = fmaf(w1, bf_hi(u1.x), ac1);
        ac2 = fmaf(w1, bf_lo(u1.y), ac2); ac3 = fmaf(w1, bf_hi(u1.y), ac3);
        ac4 = fmaf(w1, bf_lo(u1.z), ac4); ac5 = fmaf(w1, bf_hi(u1.z), ac5);
        ac6 = fmaf(w1, bf_lo(u1.w), ac6); ac7 = fmaf(w1, bf_hi(u1.w), ac7);
        den += w0 + w1;
    }
    for (; p < end; p += 4) {
        if (p + hf < end) {
            int2 e0 = epack[p + hf];
            uint4 u0 = *(const uint4*)(y1b + (size_t)e0.x * 128 + c);
            float w0 = __int_as_float(e0.y);
            ac0 = fmaf(w0, bf_lo(u0.x), ac0); ac1 = fmaf(w0, bf_hi(u0.x), ac1);
            ac2 = fmaf(w0, bf_lo(u0.y), ac2); ac3 = fmaf(w0, bf_hi(u0.y), ac3);
            ac4 = fmaf(w0, bf_lo(u0.z), ac4); ac5 = fmaf(w0, bf_hi(u0.z), ac5);
            ac6 = fmaf(w0, bf_lo(u0.w), ac6); ac7 = fmaf(w0, bf_hi(u0.w), ac7);
            den += w0;
        }
    }
    // sum the 4 edge-groups (lane bits 4,5); li (lane&15) invariant
    ac0 += __shfl_xor(ac0, 16, 64); ac0 += __shfl_xor(ac0, 32, 64);
    ac1 += __shfl_xor(ac1, 16, 64); ac1 += __shfl_xor(ac1, 32, 64);
    ac2 += __shfl_xor(ac2, 16, 64); ac2 += __shfl_xor(ac2, 32, 64);
    ac3 += __shfl_xor(ac3, 16, 64); ac3 += __shfl_xor(ac3, 32, 64);
    ac4 += __shfl_xor(ac4, 16, 64); ac4 += __shfl_xor(ac4, 32, 64);
    ac5 += __shfl_xor(ac5, 16, 64); ac5 += __shfl_xor(ac5, 32, 64);
    ac6 += __shfl_xor(ac6, 16, 64); ac6 += __shfl_xor(ac6, 32, 64);
    ac7 += __shfl_xor(ac7, 16, 64); ac7 += __shfl_xor(ac7, 32, 64);
    den += __shfl_xor(den, 16, 64); den += __shfl_xor(den, 32, 64);
    if (hf) return;
    float4 av0 = *(const float4*)(a + c);
    float4 av1 = *(const float4*)(a + c + 4);
    float4 bv0 = *(const float4*)(b + c);
    float4 bv1 = *(const float4*)(b + c + 4);
    float m0, m1, m2, m3, m4, m5, m6, m7;
    if (den != 0.f) {
        float inv = 1.f / den;
        m0 = ac0 * inv; m1 = ac1 * inv; m2 = ac2 * inv; m3 = ac3 * inv;
        m4 = ac4 * inv; m5 = ac5 * inv; m6 = ac6 * inv; m7 = ac7 * inv;
    } else {
        uint4 u = *(const uint4*)(y1b + (size_t)r * 128 + c);
        m0 = bf_lo(u.x); m1 = bf_hi(u.x); m2 = bf_lo(u.y); m3 = bf_hi(u.y);
        m4 = bf_lo(u.z); m5 = bf_hi(u.z); m6 = bf_lo(u.w); m7 = bf_hi(u.w);
    }
    uint4 o;
    o.x = (uint32_t)f2bf(fmaf(av0.x, m0, bv0.x))
        | ((uint32_t)f2bf(fmaf(av0.y, m1, bv0.y)) << 16);
    o.y = (uint32_t)f2bf(fmaf(av0.z, m2, bv0.z))
        | ((uint32_t)f2bf(fmaf(av0.w, m3, bv0.w)) << 16);
    o.z = (uint32_t)f2bf(fmaf(av1.x, m4, bv1.x))
        | ((uint32_t)f2bf(fmaf(av1.y, m5, bv1.y)) << 16);
    o.w = (uint32_t)f2bf(fmaf(av1.z, m6, bv1.z))
        | ((uint32_t)f2bf(fmaf(av1.w, m7, bv1.w)) << 16);
    *(uint4*)(aggb + (size_t)r * 128 + c) = o;
}

// ---------------------------------------------------------------------------
// gemm2 standalone (K=256, A = [featb|aggb], 128x128 tile) -> y2 f32 + stats2.
// Staging via global_load_lds (width 16), linear LDS + XOR chunk swizzle.
__global__ __launch_bounds__(256) void gemm_bn2(
    const unsigned short* __restrict__ A_lo,
    const unsigned short* __restrict__ A_hi,
    const unsigned short* __restrict__ Bb,
    const float* __restrict__ bias,
    float* __restrict__ Y,
    double* __restrict__ sum, double* __restrict__ sumsq, int N)
{
    constexpr int K = 256;
    __shared__ unsigned short As[128 * 64];   // linear [128][64], swizzled
    __shared__ unsigned short Bs[128 * 64];
    __shared__ float bsum_s[128], bsq_s[128];

    const int tid  = threadIdx.x;
    const int lane = tid & 63;
    const int wv   = tid >> 6;
    const int wr   = wv >> 1;
    const int wc   = wv & 1;
    const int m15  = lane & 15;
    const int quad = lane >> 4;
    const int r0   = (int)blockIdx.x * 128;

    if (tid < 128) { bsum_s[tid] = 0.f; bsq_s[tid] = 0.f; }

    const int lrow8 = lane >> 3;               // row within 8-row group
    const int ch    = (lane & 7) ^ lrow8;      // swizzled source chunk

    f32x4 acc[4][4];
#pragma unroll
    for (int rt = 0; rt < 4; ++rt)
#pragma unroll
        for (int ct = 0; ct < 4; ++ct)
            acc[rt][ct] = (f32x4){0.f, 0.f, 0.f, 0.f};

    for (int kc = 0; kc < K; kc += 64) {
        const unsigned short* Ap = (kc < 128) ? A_lo : A_hi;
        const int koff = kc & 127;
        // A tile: 16 gload_lds of 1KB (8 rows each); wave wv -> groups wv*4..+3
#pragma unroll
        for (int jj = 0; jj < 4; ++jj) {
            int j = wv * 4 + jj;
            int row = j * 8 + lrow8;
            int gr  = r0 + row; if (gr >= N) gr = N - 1;
            GLDS16(Ap + (size_t)gr * 128 + koff + ch * 8, As + j * 512);
        }
        // B tile: same structure, source Bb[row][kc + ch*8]
#pragma unroll
        for (int jj = 0; jj < 4; ++jj) {
            int j = wv * 4 + jj;
            int row = j * 8 + lrow8;
            GLDS16(Bb + (size_t)row * K + kc + ch * 8, Bs + j * 512);
        }
        __syncthreads();

#pragma unroll
        for (int ks = 0; ks < 64; ks += 32) {
            const int chunk = quad + (ks >> 3);      // ks=32 -> +4
            bf16x8 af[4], bfr[4];
#pragma unroll
            for (int rt = 0; rt < 4; ++rt) {
                int arow = wr * 64 + rt * 16 + m15;
                af[rt] = *(const bf16x8*)(As + arow * 64 + ((chunk ^ (arow & 7)) * 8));
            }
#pragma unroll
            for (int ct = 0; ct < 4; ++ct) {
                int brow = wc * 64 + ct * 16 + m15;
                bfr[ct] = *(const bf16x8*)(Bs + brow * 64 + ((chunk ^ (brow & 7)) * 8));
            }
#pragma unroll
            for (int rt = 0; rt < 4; ++rt)
#pragma unroll
                for (int ct = 0; ct < 4; ++ct)
                    acc[rt][ct] = __builtin_amdgcn_mfma_f32_16x16x32_bf16(
                        af[rt], bfr[ct], acc[rt][ct], 0, 0, 0);
        }
        __syncthreads();
    }

#pragma unroll
    for (int ct = 0; ct < 4; ++ct) {
        int col = wc * 64 + ct * 16 + m15;
        float bz = bias[col];
        float s = 0.f, q = 0.f;
#pragma unroll
        for (int rt = 0; rt < 4; ++rt) {
#pragma unroll
            for (int reg = 0; reg < 4; ++reg) {
                int row = r0 + wr * 64 + rt * 16 + quad * 4 + reg;
                float vv = fmaxf(acc[rt][ct][reg] + bz, 0.f);
                if (row < N) {
                    Y[(size_t)row * 128 + col] = vv;
                } else {
                    vv = 0.f;
                }
                s += vv; q = fmaf(vv, vv, q);
            }
        }
        s += __shfl_xor(s, 16, 64); s += __shfl_xor(s, 32, 64);
        q += __shfl_xor(q, 16, 64); q += __shfl_xor(q, 32, 64);
        if (quad == 0) {
            atomicAdd(&bsum_s[col], s);
            atomicAdd(&bsq_s[col], q);
        }
    }
    __syncthreads();
    if (tid < 128) {
        const int slot = ((int)blockIdx.x & (NSLOT - 1)) * 128;
        atomicAdd(&sum[slot + tid],   (double)bsum_s[tid]);
        atomicAdd(&sumsq[slot + tid], (double)bsq_s[tid]);
    }
}

// ---------------------------------------------------------------------------
// bn2 affine (precomputed coefs) + row L2 normalize.
__global__ __launch_bounds__(256) void finalize(
    const float* __restrict__ Y2,
    const float* __restrict__ a, const float* __restrict__ b,
    float* __restrict__ out, int N)
{
    __shared__ float sa[128], sb[128];
    const int t = threadIdx.x;
    if (t < 128) { sa[t] = a[t]; sb[t] = b[t]; }
    __syncthreads();
    const int row  = (int)((blockIdx.x * 256u + t) >> 6);
    const int lane = t & 63;
    if (row >= N) return;
    const size_t base = (size_t)row * 128;
    float v0 = fmaf(sa[lane],      Y2[base + lane],      sb[lane]);
    float v1 = fmaf(sa[lane + 64], Y2[base + lane + 64], sb[lane + 64]);
    float ss = fmaf(v0, v0, v1 * v1);
#pragma unroll
    for (int o = 32; o; o >>= 1) ss += __shfl_xor(ss, o, 64);
    float nrm = sqrtf(ss);
    float inv = (nrm == 0.f) ? 1.f : 1.f / nrm;
    out[base + lane]      = v0 * inv;
    out[base + lane + 64] = v1 * inv;
}

// ---------------------------------------------------------------------------
extern "C" void kernel_launch(void* const* d_in, const int* in_sizes, int n_in,
                              void* d_out, int out_size, void* d_ws, size_t ws_size,
                              hipStream_t stream)
{
    const float* feat   = (const float*)d_in[0];
    const float* w      = (const float*)d_in[1];
    const float* Q_w    = (const float*)d_in[2];
    const float* Q_b    = (const float*)d_in[3];
    const float* W_w    = (const float*)d_in[4];
    const float* W_b    = (const float*)d_in[5];
    const float* gamma2 = (const float*)d_in[6];
    const float* beta2  = (const float*)d_in[7];
    const int*   src    = (const int*)d_in[8];
    const int*   dst    = (const int*)d_in[9];

    const int N = in_sizes[0] / 128;   // 50000
    const int E = in_sizes[1];         // 800000

    // workspace layout
    float*          y2    = (float*)d_ws;                            // N*128 f32
    unsigned short* featb = (unsigned short*)(y2 + (size_t)N * 128); // N*128 bf16
    unsigned short* aggb  = featb + (size_t)N * 128;                 // N*128 bf16
    unsigned short* y1b   = aggb + (size_t)N * 128;                  // N*128 bf16
    int4*  tmp    = (int4*)(y1b + (size_t)N * 128);                  // E (16B aligned)
    int2*  epack  = (int2*)(tmp + E);                                // E
    int*   offs   = (int*)(epack + E);                               // N+1
    float* coefs  = (float*)(offs + N + 1);                          // 512
    float* a1 = coefs, *b1 = coefs + 128, *a2 = coefs + 256, *b2 = coefs + 384;
    uintptr_t qp = ((uintptr_t)(coefs + 512) + 15) & ~(uintptr_t)15;
    unsigned short* Qwb = (unsigned short*)qp;                       // 128*128 bf16
    unsigned short* Wwb = Qwb + 128 * 128;                           // 128*256 bf16
    uintptr_t sp = ((uintptr_t)(Wwb + 128 * 256) + 15) & ~(uintptr_t)15;
    double* stats = (double*)sp;                                     // 4*NSLOT*128 <- zeroed in k_pre
    double* sum1   = stats;
    double* sumsq1 = stats + NSLOT * 128;
    double* sum2   = stats + 2 * NSLOT * 128;
    double* sumsq2 = stats + 3 * NSLOT * 128;
    int*   ccnt   = (int*)(stats + 4 * NSLOT * 128);                 // 128 <- zeroed
    int*   gofs   = ccnt + 128;                                      // 128 <- zeroed

    hipMemsetAsync(ccnt, 0, 256 * sizeof(int), stream);

    const double invN = 1.0 / (double)N;
    const int GB  = (N + 63) / 64;              // gemm1 blocks (782)
    const int GB2 = (N + 127) / 128;            // gemm2 blocks (391)
    const int NB = (N + 511) >> 9;              // coarse buckets (98)
    const int CB = (N * 128 / 4 + 255) / 256;   // feat cast blocks
    const int HB = (E + 2047) / 2048;           // histogram/bin blocks
    const int QB = 16;                          // Q_w cast blocks
    const int WB = 32;                          // W_w cast blocks
    const int ZB = 32;                          // stats-zero blocks (128KB)

    k_pre<<<CB + HB + QB + WB + ZB, 256, 0, stream>>>(
        feat, featb, N * 128, dst, ccnt, E, CB, HB,
        Q_w, Qwb, W_w, Wwb, offs, N, stats);

    // fatB: bin || gemm1 -> y1b bf16 + stats1 (bases via in-block ccnt scan)
    k_bin_gemm<<<HB + GB, 256, 0, stream>>>(
        src, dst, w, ccnt, gofs, tmp, E, HB,
        featb, Qwb, Q_b, y1b, sum1, sumsq1, N);

    // fat: bn_coef1 (block 0) || refine (blocks 1..NB)
    k_bnref<<<NB + 1, 256, 0, stream>>>(
        sum1, sumsq1, gamma2, beta2, a1, b1, invN,
        tmp, ccnt, offs, epack, N);

    gather_agg<<<(N * 64 + 255) / 256, 256, 0, stream>>>(
        y1b, offs, epack, a1, b1, aggb, N);

    gemm_bn2<<<GB2, 256, 0, stream>>>(
        featb, aggb, Wwb, W_b, y2, sum2, sumsq2, N);

    bn_coef<<<1, 128, 0, stream>>>(sum2, sumsq2, gamma2, beta2, a2, b2, invN);
    finalize<<<(N * 64 + 255) / 256, 256, 0, stream>>>(
        y2, a2, b2, (float*)d_out, N);
}

// Round 12
// 215.449 us; speedup vs baseline: 1.3952x; 1.0247x over previous
//
#include <hip/hip_runtime.h>
#include <stdint.h>

// PinConv pipeline, round 22 (base = round 21, 220.8us best):
//  - edge records tmp[] packed int4 (16B) -> int2 (8B): x = src | (dst&511)<<17
//    (src < 131072 fits 17 bits; in-bucket dst offset fits 9), y = w bits.
//    Halves bin's random scatter-write (12.8->6.4MB) and refine's two read
//    passes (25.6->12.8MB). Bit-exact packing.
//  - everything else identical to round 21 (gload_lds+XOR-swizzle staging in
//    both GEMMs, 128^2 gemm2 tile, no k_coffs, no fences, pre-cast bf16 B).

#define BN_EPS 1e-5f
#define NSLOT 32

typedef __attribute__((ext_vector_type(8))) short bf16x8;
typedef __attribute__((ext_vector_type(4))) float f32x4;

#define GLDS16(g, l) __builtin_amdgcn_global_load_lds( \
    (__attribute__((address_space(1))) void*)(g), \
    (__attribute__((address_space(3))) void*)(l), 16, 0, 0)

static __device__ __forceinline__ unsigned short f2bf(float f) {
    uint32_t u = __builtin_bit_cast(uint32_t, f);
    u += 0x7fffu + ((u >> 16) & 1u);          // round-to-nearest-even
    return (unsigned short)(u >> 16);
}
static __device__ __forceinline__ float bf_lo(uint32_t u) {
    return __builtin_bit_cast(float, u << 16);
}
static __device__ __forceinline__ float bf_hi(uint32_t u) {
    return __builtin_bit_cast(float, u & 0xffff0000u);
}

static __device__ __forceinline__ void cast_blk(
    const float* __restrict__ src, unsigned short* __restrict__ dst,
    int n, int blk)
{
    int i = (blk * 256 + threadIdx.x) * 4;
    if (i + 3 < n) {
        float4 v = *(const float4*)(src + i);
        ushort4 o;
        o.x = f2bf(v.x); o.y = f2bf(v.y); o.z = f2bf(v.z); o.w = f2bf(v.w);
        *(ushort4*)(dst + i) = o;
    } else {
        for (int j = i; j < n; ++j) dst[j] = f2bf(src[j]);
    }
}

// Redundant per-block exclusive scan of ccnt[128].
static __device__ __forceinline__ void scan_ccnt(
    const int* __restrict__ ccnt, int* excl_out, int* v_out, int* w0s)
{
    const int t = threadIdx.x;
    int v = 0, incl = 0;
    if (t < 128) {
        v = ccnt[t];
        incl = v;
        const int lane = t & 63;
#pragma unroll
        for (int o = 1; o < 64; o <<= 1) {
            int u = __shfl_up(incl, o, 64);
            if (lane >= o) incl += u;
        }
        if (t == 63) *w0s = incl;
    }
    __syncthreads();
    int excl = 0;
    if (t < 128) excl = incl - v + ((t >> 6) ? *w0s : 0);
    *excl_out = excl;
    *v_out = v;
}

// ---------------------------------------------------------------------------
// Fused: blocks [0,CB) cast feat; [CB,CB+HB) coarse-histogram dst;
// [CB+HB, CB+HB+QB+WB) cast Q_w/W_w; remaining ZB blocks zero stats.
__global__ __launch_bounds__(256) void k_pre(
    const float* __restrict__ feat, unsigned short* __restrict__ featb, int nf,
    const int* __restrict__ dst, int* __restrict__ ccnt, int E, int CB, int HB,
    const float* __restrict__ Qw, unsigned short* __restrict__ Qwb,
    const float* __restrict__ Ww, unsigned short* __restrict__ Wwb,
    int* __restrict__ offs, int N, double* __restrict__ stats)
{
    int b = (int)blockIdx.x;
    if (b < CB) {
        if (b == 0 && threadIdx.x == 0) offs[N] = E;
        cast_blk(feat, featb, nf, b);
        return;
    }
    b -= CB;
    if (b >= HB) {
        b -= HB;
        if (b < 16) { cast_blk(Qw, Qwb, 128 * 128, b); return; }
        b -= 16;
        if (b < 32) { cast_blk(Ww, Wwb, 128 * 256, b); return; }
        b -= 32;
        // zero stats: 32 blocks x 256 threads x 16B = 128 KB
        uint4* p = (uint4*)stats;
        p[b * 256 + threadIdx.x] = make_uint4(0u, 0u, 0u, 0u);
        return;
    }
    __shared__ int hcnt[128];
    const int tid = threadIdx.x;
    if (tid < 128) hcnt[tid] = 0;
    __syncthreads();
    const int base_e = b * 2048;
#pragma unroll
    for (int j = 0; j < 8; ++j) {
        int e = base_e + j * 256 + tid;
        if (e < E) atomicAdd(&hcnt[dst[e] >> 9], 1);
    }
    __syncthreads();
    if (tid < 128 && hcnt[tid] > 0) atomicAdd(&ccnt[tid], hcnt[tid]);
}

// ---------------------------------------------------------------------------
// GEMM1 body (64x128 tile, gload_lds staging + XOR chunk swizzle):
// Y = relu(A @ B^T + bias) -> bf16. A = featb (K=128), B = Qwb [128][128].
static __device__ __forceinline__ void gemm1_body(
    int bid,
    const unsigned short* __restrict__ A,
    const unsigned short* __restrict__ Bb,
    const float* __restrict__ bias,
    unsigned short* __restrict__ Y,
    double* __restrict__ sum, double* __restrict__ sumsq, int N)
{
    __shared__ unsigned short As[64 * 64];    // linear [64][64], swizzled
    __shared__ unsigned short Bs[128 * 64];
    __shared__ float bsum_s[128], bsq_s[128];

    const int tid  = threadIdx.x;
    const int lane = tid & 63;
    const int wv   = tid >> 6;
    const int wr   = wv >> 1;
    const int wc   = wv & 1;
    const int m15  = lane & 15;
    const int quad = lane >> 4;
    const int r0   = bid * 64;

    if (tid < 128) { bsum_s[tid] = 0.f; bsq_s[tid] = 0.f; }

    const int lrow8 = lane >> 3;               // row within 8-row group
    const int ch    = (lane & 7) ^ lrow8;      // swizzled source chunk

    f32x4 acc[2][4];
#pragma unroll
    for (int rt = 0; rt < 2; ++rt)
#pragma unroll
        for (int ct = 0; ct < 4; ++ct)
            acc[rt][ct] = (f32x4){0.f, 0.f, 0.f, 0.f};

    for (int kc = 0; kc < 128; kc += 64) {
        // A tile: 8 groups of 8 rows (1KB each); wave wv -> groups wv*2..+1
#pragma unroll
        for (int jj = 0; jj < 2; ++jj) {
            int j = wv * 2 + jj;
            int row = j * 8 + lrow8;
            int gr  = r0 + row; if (gr >= N) gr = N - 1;
            GLDS16(A + (size_t)gr * 128 + kc + ch * 8, As + j * 512);
        }
        // B tile: 16 groups; wave wv -> groups wv*4..+3
#pragma unroll
        for (int jj = 0; jj < 4; ++jj) {
            int j = wv * 4 + jj;
            int row = j * 8 + lrow8;
            GLDS16(Bb + (size_t)row * 128 + kc + ch * 8, Bs + j * 512);
        }
        __syncthreads();

#pragma unroll
        for (int ks = 0; ks < 64; ks += 32) {
            const int chunk = quad + (ks >> 3);      // ks=32 -> +4
            bf16x8 af[2], bfr[4];
#pragma unroll
            for (int rt = 0; rt < 2; ++rt) {
                int arow = wr * 32 + rt * 16 + m15;
                af[rt] = *(const bf16x8*)(As + arow * 64 + ((chunk ^ (arow & 7)) * 8));
            }
#pragma unroll
            for (int ct = 0; ct < 4; ++ct) {
                int brow = wc * 64 + ct * 16 + m15;
                bfr[ct] = *(const bf16x8*)(Bs + brow * 64 + ((chunk ^ (brow & 7)) * 8));
            }
#pragma unroll
            for (int rt = 0; rt < 2; ++rt)
#pragma unroll
                for (int ct = 0; ct < 4; ++ct)
                    acc[rt][ct] = __builtin_amdgcn_mfma_f32_16x16x32_bf16(
                        af[rt], bfr[ct], acc[rt][ct], 0, 0, 0);
        }
        __syncthreads();
    }

#pragma unroll
    for (int ct = 0; ct < 4; ++ct) {
        int col = wc * 64 + ct * 16 + m15;
        float bz = bias[col];
        float s = 0.f, q = 0.f;
#pragma unroll
        for (int rt = 0; rt < 2; ++rt) {
#pragma unroll
            for (int reg = 0; reg < 4; ++reg) {
                int row = r0 + wr * 32 + rt * 16 + quad * 4 + reg;
                float vv = fmaxf(acc[rt][ct][reg] + bz, 0.f);
                if (row < N) {
                    Y[(size_t)row * 128 + col] = f2bf(vv);
                } else {
                    vv = 0.f;
                }
                s += vv; q = fmaf(vv, vv, q);
            }
        }
        s += __shfl_xor(s, 16, 64); s += __shfl_xor(s, 32, 64);
        q += __shfl_xor(q, 16, 64); q += __shfl_xor(q, 32, 64);
        if (quad == 0) {
            atomicAdd(&bsum_s[col], s);
            atomicAdd(&bsq_s[col], q);
        }
    }
    __syncthreads();
    if (tid < 128) {
        const int slot = (bid & (NSLOT - 1)) * 128;
        atomicAdd(&sum[slot + tid],   (double)bsum_s[tid]);
        atomicAdd(&sumsq[slot + tid], (double)bsq_s[tid]);
    }
}

// ---------------------------------------------------------------------------
// bn coef body: reduce 32 slots -> bn affine coefs. t in [0,128).
static __device__ __forceinline__ void bn_coef_body(
    int t, const double* __restrict__ sum, const double* __restrict__ sumsq,
    const float* __restrict__ gamma, const float* __restrict__ beta,
    float* __restrict__ a, float* __restrict__ b, double invN)
{
    double ms = 0.0, qs = 0.0;
#pragma unroll
    for (int s = 0; s < NSLOT; ++s) {
        ms += sum[s * 128 + t];
        qs += sumsq[s * 128 + t];
    }
    float mean = (float)(ms * invN);
    float var  = (float)(qs * invN) - mean * mean;
    float sc = rsqrtf(var + BN_EPS) * gamma[t];
    a[t] = sc;
    b[t] = fmaf(-mean, sc, beta[t]);
}

__global__ __launch_bounds__(128) void bn_coef(
    const double* __restrict__ sum, const double* __restrict__ sumsq,
    const float* __restrict__ gamma, const float* __restrict__ beta,
    float* __restrict__ a, float* __restrict__ b, double invN)
{
    bn_coef_body(threadIdx.x, sum, sumsq, gamma, beta, a, b, invN);
}

// ---------------------------------------------------------------------------
// bin body: bin edges into coarse buckets of 512 dsts. Record packed int2:
// x = src | (dst&511)<<17  (src<131072), y = w bits.
static __device__ __forceinline__ void bin_body(
    int bid,
    const int* __restrict__ src, const int* __restrict__ dst,
    const float* __restrict__ w,
    const int* __restrict__ ccnt, int* __restrict__ gofs,
    int2* __restrict__ tmp, int E)
{
    __shared__ int hcnt[128];
    __shared__ int hbase[128];
    __shared__ int w0s;
    const int tid = threadIdx.x;
    if (tid < 128) hcnt[tid] = 0;
    __syncthreads();

    int d8[8], s8[8], slot8[8];
    float w8[8];
#pragma unroll
    for (int j = 0; j < 8; ++j) {
        int e = bid * 2048 + j * 256 + tid;
        if (e < E) {
            d8[j] = dst[e]; s8[j] = src[e]; w8[j] = w[e];
            slot8[j] = atomicAdd(&hcnt[d8[j] >> 9], 1);
        } else d8[j] = -1;
    }
    __syncthreads();
    int excl, vcnt;
    scan_ccnt(ccnt, &excl, &vcnt, &w0s);
    if (tid < 128 && hcnt[tid] > 0)
        hbase[tid] = excl + atomicAdd(&gofs[tid], hcnt[tid]);
    __syncthreads();
#pragma unroll
    for (int j = 0; j < 8; ++j) {
        if (d8[j] >= 0) {
            int pos = hbase[d8[j] >> 9] + slot8[j];
            tmp[pos] = make_int2(s8[j] | ((d8[j] & 511) << 17),
                                 __float_as_int(w8[j]));
        }
    }
}

// fatB: blocks [0,HB) bin edges; blocks [HB,HB+GB) run gemm1 -> y1b bf16.
__global__ __launch_bounds__(256) void k_bin_gemm(
    const int* __restrict__ src, const int* __restrict__ dst,
    const float* __restrict__ w,
    const int* __restrict__ ccnt, int* __restrict__ gofs,
    int2* __restrict__ tmp, int E, int HB,
    const unsigned short* __restrict__ featb,
    const unsigned short* __restrict__ Qwb, const float* __restrict__ Qb,
    unsigned short* __restrict__ y1b,
    double* __restrict__ sum, double* __restrict__ sumsq, int N)
{
    if ((int)blockIdx.x < HB)
        bin_body(blockIdx.x, src, dst, w, ccnt, gofs, tmp, E);
    else
        gemm1_body(blockIdx.x - HB, featb, Qwb, Qb, y1b, sum, sumsq, N);
}

// ---------------------------------------------------------------------------
// refine body: per bucket — bases from redundant ccnt scan; count per-dst in
// LDS, scan (+bucket base), write offs slice, scatter to epack in dst order.
// tmp records packed: dstoff = x>>17, src = x & 0x1FFFF.
static __device__ __forceinline__ void refine_body(
    int b,
    const int2* __restrict__ tmp, const int* __restrict__ ccnt,
    int* __restrict__ offs, int2* __restrict__ epack, int N)
{
    __shared__ int hist[512];
    __shared__ int wpre[4];
    __shared__ int w0s;
    __shared__ int sbounds[2];
    const int d0   = b << 9;
    const int dlim = min(512, N - d0);
    const int tid  = threadIdx.x;
    const int lane = tid & 63, wv = tid >> 6;

    hist[tid] = 0; hist[tid + 256] = 0;
    __syncthreads();
    int excl, vcnt;
    scan_ccnt(ccnt, &excl, &vcnt, &w0s);
    if (tid == b) { sbounds[0] = excl; sbounds[1] = excl + vcnt; }
    __syncthreads();
    const int start = sbounds[0];
    const int end   = sbounds[1];

    for (int p = start + tid; p < end; p += 256)
        atomicAdd(&hist[tmp[p].x >> 17], 1);
    __syncthreads();

    int v0 = hist[2 * tid], v1 = hist[2 * tid + 1];
    int s = v0 + v1;
    int incl = s;
#pragma unroll
    for (int o = 1; o < 64; o <<= 1) {
        int t = __shfl_up(incl, o, 64);
        if (lane >= o) incl += t;
    }
    if (lane == 63) wpre[wv] = incl;
    __syncthreads();
    if (tid == 0) {
        int r = 0;
#pragma unroll
        for (int i = 0; i < 4; ++i) { int t = wpre[i]; wpre[i] = r; r += t; }
    }
    __syncthreads();
    int e0 = start + wpre[wv] + incl - s;
    if (2 * tid < dlim)     offs[d0 + 2 * tid]     = e0;
    if (2 * tid + 1 < dlim) offs[d0 + 2 * tid + 1] = e0 + v0;
    hist[2 * tid]     = e0;
    hist[2 * tid + 1] = e0 + v0;
    __syncthreads();

    for (int p = start + tid; p < end; p += 256) {
        int2 rec = tmp[p];
        int pos = atomicAdd(&hist[rec.x >> 17], 1);
        epack[pos] = make_int2(rec.x & 0x1FFFF, rec.y);
    }
}

// fat: block 0 = bn_coef1 reduce; blocks [1,NB] = refine buckets.
__global__ __launch_bounds__(256) void k_bnref(
    const double* __restrict__ sum, const double* __restrict__ sumsq,
    const float* __restrict__ gamma, const float* __restrict__ beta,
    float* __restrict__ a, float* __restrict__ b, double invN,
    const int2* __restrict__ tmp, const int* __restrict__ ccnt,
    int* __restrict__ offs, int2* __restrict__ epack, int N)
{
    if (blockIdx.x == 0) {
        if (threadIdx.x < 128)
            bn_coef_body(threadIdx.x, sum, sumsq, gamma, beta, a, b, invN);
        return;
    }
    refine_body((int)blockIdx.x - 1, tmp, ccnt, offs, epack, N);
}

// ---------------------------------------------------------------------------
// One wave per dst row; 16 lanes/edge, uint4 (16B) loads, 4 edges per load
// round (8 with 2-deep unroll). Reads raw relu y1b; applies bn affine (a,b)
// to the weighted mean (or own row when den==0). Writes agg bf16.
__global__ __launch_bounds__(256) void gather_agg(
    const unsigned short* __restrict__ y1b,
    const int* __restrict__ offs, const int2* __restrict__ epack,
    const float* __restrict__ a, const float* __restrict__ b,
    unsigned short* __restrict__ aggb, int N)
{
    const int r    = (int)((blockIdx.x * 256u + threadIdx.x) >> 6);
    const int lane = threadIdx.x & 63;
    const int li   = lane & 15;     // owns columns 8*li .. 8*li+7
    const int hf   = lane >> 4;     // edge slot in quad (0..3)
    if (r >= N) return;
    int p = offs[r];
    const int end = offs[r + 1];
    const int c = 8 * li;
    float ac0 = 0.f, ac1 = 0.f, ac2 = 0.f, ac3 = 0.f;
    float ac4 = 0.f, ac5 = 0.f, ac6 = 0.f, ac7 = 0.f;
    float den = 0.f;
    for (; p + 7 < end; p += 8) {
        int2 e0 = epack[p + hf];
        int2 e1 = epack[p + 4 + hf];
        uint4 u0 = *(const uint4*)(y1b + (size_t)e0.x * 128 + c);
        uint4 u1 = *(const uint4*)(y1b + (size_t)e1.x * 128 + c);
        float w0 = __int_as_float(e0.y), w1 = __int_as_float(e1.y);
        ac0 = fmaf(w0, bf_lo(u0.x), ac0); ac1 = fmaf(w0, bf_hi(u0.x), ac1);
        ac2 = fmaf(w0, bf_lo(u0.y), ac2); ac3 = fmaf(w0, bf_hi(u0.y), ac3);
        ac4 = fmaf(w0, bf_lo(u0.z), ac4); ac5 = fmaf(w0, bf_hi(u0.z), ac5);
        ac6 = fmaf(w0, bf_lo(u0.w), ac6); ac7 = fmaf(w0, bf_hi(u0.w), ac7);
        ac0 = fmaf(w1, bf_lo(u1.x), ac0); ac1 = fmaf(w1, bf_hi(u1.x), ac1);
        ac2 = fmaf(w1, bf_lo(u1.y), ac2); ac3 = fmaf(w1, bf_hi(u1.y), ac3);
        ac4 = fmaf(w1, bf_lo(u1.z), ac4); ac5 = fmaf(w1, bf_hi(u1.z), ac5);
        ac6 = fmaf(w1, bf_lo(u1.w), ac6); ac7 = fmaf(w1, bf_hi(u1.w), ac7);
        den += w0 + w1;
    }
    for (; p < end; p += 4) {
        if (p + hf < end) {
            int2 e0 = epack[p + hf];
            uint4 u0 = *(const uint4*)(y1b + (size_t)e0.x * 128 + c);
            float w0 = __int_as_float(e0.y);
            ac0 = fmaf(w0, bf_lo(u0.x), ac0); ac1 = fmaf(w0, bf_hi(u0.x), ac1);
            ac2 = fmaf(w0, bf_lo(u0.y), ac2); ac3 = fmaf(w0, bf_hi(u0.y), ac3);
            ac4 = fmaf(w0, bf_lo(u0.z), ac4); ac5 = fmaf(w0, bf_hi(u0.z), ac5);
            ac6 = fmaf(w0, bf_lo(u0.w), ac6); ac7 = fmaf(w0, bf_hi(u0.w), ac7);
            den += w0;
        }
    }
    // sum the 4 edge-groups (lane bits 4,5); li (lane&15) invariant
    ac0 += __shfl_xor(ac0, 16, 64); ac0 += __shfl_xor(ac0, 32, 64);
    ac1 += __shfl_xor(ac1, 16, 64); ac1 += __shfl_xor(ac1, 32, 64);
    ac2 += __shfl_xor(ac2, 16, 64); ac2 += __shfl_xor(ac2, 32, 64);
    ac3 += __shfl_xor(ac3, 16, 64); ac3 += __shfl_xor(ac3, 32, 64);
    ac4 += __shfl_xor(ac4, 16, 64); ac4 += __shfl_xor(ac4, 32, 64);
    ac5 += __shfl_xor(ac5, 16, 64); ac5 += __shfl_xor(ac5, 32, 64);
    ac6 += __shfl_xor(ac6, 16, 64); ac6 += __shfl_xor(ac6, 32, 64);
    ac7 += __shfl_xor(ac7, 16, 64); ac7 += __shfl_xor(ac7, 32, 64);
    den += __shfl_xor(den, 16, 64); den += __shfl_xor(den, 32, 64);
    if (hf) return;
    float4 av0 = *(const float4*)(a + c);
    float4 av1 = *(const float4*)(a + c + 4);
    float4 bv0 = *(const float4*)(b + c);
    float4 bv1 = *(const float4*)(b + c + 4);
    float m0, m1, m2, m3, m4, m5, m6, m7;
    if (den != 0.f) {
        float inv = 1.f / den;
        m0 = ac0 * inv; m1 = ac1 * inv; m2 = ac2 * inv; m3 = ac3 * inv;
        m4 = ac4 * inv; m5 = ac5 * inv; m6 = ac6 * inv; m7 = ac7 * inv;
    } else {
        uint4 u = *(const uint4*)(y1b + (size_t)r * 128 + c);
        m0 = bf_lo(u.x); m1 = bf_hi(u.x); m2 = bf_lo(u.y); m3 = bf_hi(u.y);
        m4 = bf_lo(u.z); m5 = bf_hi(u.z); m6 = bf_lo(u.w); m7 = bf_hi(u.w);
    }
    uint4 o;
    o.x = (uint32_t)f2bf(fmaf(av0.x, m0, bv0.x))
        | ((uint32_t)f2bf(fmaf(av0.y, m1, bv0.y)) << 16);
    o.y = (uint32_t)f2bf(fmaf(av0.z, m2, bv0.z))
        | ((uint32_t)f2bf(fmaf(av0.w, m3, bv0.w)) << 16);
    o.z = (uint32_t)f2bf(fmaf(av1.x, m4, bv1.x))
        | ((uint32_t)f2bf(fmaf(av1.y, m5, bv1.y)) << 16);
    o.w = (uint32_t)f2bf(fmaf(av1.z, m6, bv1.z))
        | ((uint32_t)f2bf(fmaf(av1.w, m7, bv1.w)) << 16);
    *(uint4*)(aggb + (size_t)r * 128 + c) = o;
}

// ---------------------------------------------------------------------------
// gemm2 standalone (K=256, A = [featb|aggb], 128x128 tile) -> y2 f32 + stats2.
// Staging via global_load_lds (width 16), linear LDS + XOR chunk swizzle.
__global__ __launch_bounds__(256) void gemm_bn2(
    const unsigned short* __restrict__ A_lo,
    const unsigned short* __restrict__ A_hi,
    const unsigned short* __restrict__ Bb,
    const float* __restrict__ bias,
    float* __restrict__ Y,
    double* __restrict__ sum, double* __restrict__ sumsq, int N)
{
    constexpr int K = 256;
    __shared__ unsigned short As[128 * 64];   // linear [128][64], swizzled
    __shared__ unsigned short Bs[128 * 64];
    __shared__ float bsum_s[128], bsq_s[128];

    const int tid  = threadIdx.x;
    const int lane = tid & 63;
    const int wv   = tid >> 6;
    const int wr   = wv >> 1;
    const int wc   = wv & 1;
    const int m15  = lane & 15;
    const int quad = lane >> 4;
    const int r0   = (int)blockIdx.x * 128;

    if (tid < 128) { bsum_s[tid] = 0.f; bsq_s[tid] = 0.f; }

    const int lrow8 = lane >> 3;               // row within 8-row group
    const int ch    = (lane & 7) ^ lrow8;      // swizzled source chunk

    f32x4 acc[4][4];
#pragma unroll
    for (int rt = 0; rt < 4; ++rt)
#pragma unroll
        for (int ct = 0; ct < 4; ++ct)
            acc[rt][ct] = (f32x4){0.f, 0.f, 0.f, 0.f};

    for (int kc = 0; kc < K; kc += 64) {
        const unsigned short* Ap = (kc < 128) ? A_lo : A_hi;
        const int koff = kc & 127;
        // A tile: 16 gload_lds of 1KB (8 rows each); wave wv -> groups wv*4..+3
#pragma unroll
        for (int jj = 0; jj < 4; ++jj) {
            int j = wv * 4 + jj;
            int row = j * 8 + lrow8;
            int gr  = r0 + row; if (gr >= N) gr = N - 1;
            GLDS16(Ap + (size_t)gr * 128 + koff + ch * 8, As + j * 512);
        }
        // B tile: same structure, source Bb[row][kc + ch*8]
#pragma unroll
        for (int jj = 0; jj < 4; ++jj) {
            int j = wv * 4 + jj;
            int row = j * 8 + lrow8;
            GLDS16(Bb + (size_t)row * K + kc + ch * 8, Bs + j * 512);
        }
        __syncthreads();

#pragma unroll
        for (int ks = 0; ks < 64; ks += 32) {
            const int chunk = quad + (ks >> 3);      // ks=32 -> +4
            bf16x8 af[4], bfr[4];
#pragma unroll
            for (int rt = 0; rt < 4; ++rt) {
                int arow = wr * 64 + rt * 16 + m15;
                af[rt] = *(const bf16x8*)(As + arow * 64 + ((chunk ^ (arow & 7)) * 8));
            }
#pragma unroll
            for (int ct = 0; ct < 4; ++ct) {
                int brow = wc * 64 + ct * 16 + m15;
                bfr[ct] = *(const bf16x8*)(Bs + brow * 64 + ((chunk ^ (brow & 7)) * 8));
            }
#pragma unroll
            for (int rt = 0; rt < 4; ++rt)
#pragma unroll
                for (int ct = 0; ct < 4; ++ct)
                    acc[rt][ct] = __builtin_amdgcn_mfma_f32_16x16x32_bf16(
                        af[rt], bfr[ct], acc[rt][ct], 0, 0, 0);
        }
        __syncthreads();
    }

#pragma unroll
    for (int ct = 0; ct < 4; ++ct) {
        int col = wc * 64 + ct * 16 + m15;
        float bz = bias[col];
        float s = 0.f, q = 0.f;
#pragma unroll
        for (int rt = 0; rt < 4; ++rt) {
#pragma unroll
            for (int reg = 0; reg < 4; ++reg) {
                int row = r0 + wr * 64 + rt * 16 + quad * 4 + reg;
                float vv = fmaxf(acc[rt][ct][reg] + bz, 0.f);
                if (row < N) {
                    Y[(size_t)row * 128 + col] = vv;
                } else {
                    vv = 0.f;
                }
                s += vv; q = fmaf(vv, vv, q);
            }
        }
        s += __shfl_xor(s, 16, 64); s += __shfl_xor(s, 32, 64);
        q += __shfl_xor(q, 16, 64); q += __shfl_xor(q, 32, 64);
        if (quad == 0) {
            atomicAdd(&bsum_s[col], s);
            atomicAdd(&bsq_s[col], q);
        }
    }
    __syncthreads();
    if (tid < 128) {
        const int slot = ((int)blockIdx.x & (NSLOT - 1)) * 128;
        atomicAdd(&sum[slot + tid],   (double)bsum_s[tid]);
        atomicAdd(&sumsq[slot + tid], (double)bsq_s[tid]);
    }
}

// ---------------------------------------------------------------------------
// bn2 affine (precomputed coefs) + row L2 normalize.
__global__ __launch_bounds__(256) void finalize(
    const float* __restrict__ Y2,
    const float* __restrict__ a, const float* __restrict__ b,
    float* __restrict__ out, int N)
{
    __shared__ float sa[128], sb[128];
    const int t = threadIdx.x;
    if (t < 128) { sa[t] = a[t]; sb[t] = b[t]; }
    __syncthreads();
    const int row  = (int)((blockIdx.x * 256u + t) >> 6);
    const int lane = t & 63;
    if (row >= N) return;
    const size_t base = (size_t)row * 128;
    float v0 = fmaf(sa[lane],      Y2[base + lane],      sb[lane]);
    float v1 = fmaf(sa[lane + 64], Y2[base + lane + 64], sb[lane + 64]);
    float ss = fmaf(v0, v0, v1 * v1);
#pragma unroll
    for (int o = 32; o; o >>= 1) ss += __shfl_xor(ss, o, 64);
    float nrm = sqrtf(ss);
    float inv = (nrm == 0.f) ? 1.f : 1.f / nrm;
    out[base + lane]      = v0 * inv;
    out[base + lane + 64] = v1 * inv;
}

// ---------------------------------------------------------------------------
extern "C" void kernel_launch(void* const* d_in, const int* in_sizes, int n_in,
                              void* d_out, int out_size, void* d_ws, size_t ws_size,
                              hipStream_t stream)
{
    const float* feat   = (const float*)d_in[0];
    const float* w      = (const float*)d_in[1];
    const float* Q_w    = (const float*)d_in[2];
    const float* Q_b    = (const float*)d_in[3];
    const float* W_w    = (const float*)d_in[4];
    const float* W_b    = (const float*)d_in[5];
    const float* gamma2 = (const float*)d_in[6];
    const float* beta2  = (const float*)d_in[7];
    const int*   src    = (const int*)d_in[8];
    const int*   dst    = (const int*)d_in[9];

    const int N = in_sizes[0] / 128;   // 50000
    const int E = in_sizes[1];         // 800000

    // workspace layout
    float*          y2    = (float*)d_ws;                            // N*128 f32
    unsigned short* featb = (unsigned short*)(y2 + (size_t)N * 128); // N*128 bf16
    unsigned short* aggb  = featb + (size_t)N * 128;                 // N*128 bf16
    unsigned short* y1b   = aggb + (size_t)N * 128;                  // N*128 bf16
    int2*  tmp    = (int2*)(y1b + (size_t)N * 128);                  // E (8B, packed)
    int2*  epack  = (int2*)(tmp + E);                                // E
    int*   offs   = (int*)(epack + E);                               // N+1
    float* coefs  = (float*)(offs + N + 1);                          // 512
    float* a1 = coefs, *b1 = coefs + 128, *a2 = coefs + 256, *b2 = coefs + 384;
    uintptr_t qp = ((uintptr_t)(coefs + 512) + 15) & ~(uintptr_t)15;
    unsigned short* Qwb = (unsigned short*)qp;                       // 128*128 bf16
    unsigned short* Wwb = Qwb + 128 * 128;                           // 128*256 bf16
    uintptr_t sp = ((uintptr_t)(Wwb + 128 * 256) + 15) & ~(uintptr_t)15;
    double* stats = (double*)sp;                                     // 4*NSLOT*128 <- zeroed in k_pre
    double* sum1   = stats;
    double* sumsq1 = stats + NSLOT * 128;
    double* sum2   = stats + 2 * NSLOT * 128;
    double* sumsq2 = stats + 3 * NSLOT * 128;
    int*   ccnt   = (int*)(stats + 4 * NSLOT * 128);                 // 128 <- zeroed
    int*   gofs   = ccnt + 128;                                      // 128 <- zeroed

    hipMemsetAsync(ccnt, 0, 256 * sizeof(int), stream);

    const double invN = 1.0 / (double)N;
    const int GB  = (N + 63) / 64;              // gemm1 blocks (782)
    const int GB2 = (N + 127) / 128;            // gemm2 blocks (391)
    const int NB = (N + 511) >> 9;              // coarse buckets (98)
    const int CB = (N * 128 / 4 + 255) / 256;   // feat cast blocks
    const int HB = (E + 2047) / 2048;           // histogram/bin blocks
    const int QB = 16;                          // Q_w cast blocks
    const int WB = 32;                          // W_w cast blocks
    const int ZB = 32;                          // stats-zero blocks (128KB)

    k_pre<<<CB + HB + QB + WB + ZB, 256, 0, stream>>>(
        feat, featb, N * 128, dst, ccnt, E, CB, HB,
        Q_w, Qwb, W_w, Wwb, offs, N, stats);

    // fatB: bin || gemm1 -> y1b bf16 + stats1 (bases via in-block ccnt scan)
    k_bin_gemm<<<HB + GB, 256, 0, stream>>>(
        src, dst, w, ccnt, gofs, tmp, E, HB,
        featb, Qwb, Q_b, y1b, sum1, sumsq1, N);

    // fat: bn_coef1 (block 0) || refine (blocks 1..NB)
    k_bnref<<<NB + 1, 256, 0, stream>>>(
        sum1, sumsq1, gamma2, beta2, a1, b1, invN,
        tmp, ccnt, offs, epack, N);

    gather_agg<<<(N * 64 + 255) / 256, 256, 0, stream>>>(
        y1b, offs, epack, a1, b1, aggb, N);

    gemm_bn2<<<GB2, 256, 0, stream>>>(
        featb, aggb, Wwb, W_b, y2, sum2, sumsq2, N);

    bn_coef<<<1, 128, 0, stream>>>(sum2, sumsq2, gamma2, beta2, a2, b2, invN);
    finalize<<<(N * 64 + 255) / 256, 256, 0, stream>>>(
        y2, a2, b2, (float*)d_out, N);
}